// Round 10
// baseline (841.929 us; speedup 1.0000x reference)
//
#include <hip/hip_runtime.h>
#include <hip/hip_bf16.h>

#define DEVI __device__ __forceinline__

typedef float f32x4 __attribute__((ext_vector_type(4)));
typedef _Float16 f16x8 __attribute__((ext_vector_type(8)));
typedef short s16x8 __attribute__((ext_vector_type(8)));
typedef unsigned int u32;

constexpr int Bc = 2, Sc = 2048, Dc = 1024, Hc = 16, KVc = 4, HDc = 64, Fc = 2816, Ec = 8;
constexpr int Tc = Bc * Sc;                 // 4096 tokens
constexpr int QKVN = Hc * HDc + 2 * KVc * HDc; // 1536
constexpr int CAP = Tc * 2 + Ec * 128;      // 9216 padded expert-token slots
constexpr float LO_SCALE = 1024.0f;
constexpr float LO_INV = 1.0f / 1024.0f;

DEVI f32x4 mfma16(f16x8 a, f16x8 b, f32x4 c) {
    return __builtin_amdgcn_mfma_f32_16x16x32_f16(a, b, c, 0, 0, 0);
}
DEVI f32x4 mfma16(s16x8 a, s16x8 b, f32x4 c) {
    return __builtin_amdgcn_mfma_f32_16x16x32_bf16(a, b, c, 0, 0, 0);
}

DEVI void gll16(const void *g, void *l) {
    __builtin_amdgcn_global_load_lds(
        (const __attribute__((address_space(1))) u32 *)g,
        (__attribute__((address_space(3))) u32 *)l, 16, 0, 0);
}

DEVI u32 pack2(_Float16 a, _Float16 b) {
    union { _Float16 h[2]; u32 u; } t;
    t.h[0] = a; t.h[1] = b;
    return t.u;
}

template <int N> DEVI void wait_vm() {
    if constexpr (N == 0) asm volatile("s_waitcnt vmcnt(0)" ::: "memory");
    else if constexpr (N == 3) asm volatile("s_waitcnt vmcnt(3)" ::: "memory");
    else if constexpr (N == 4) asm volatile("s_waitcnt vmcnt(4)" ::: "memory");
    else if constexpr (N == 6) asm volatile("s_waitcnt vmcnt(6)" ::: "memory");
    else if constexpr (N == 8) asm volatile("s_waitcnt vmcnt(8)" ::: "memory");
    else if constexpr (N == 12) asm volatile("s_waitcnt vmcnt(12)" ::: "memory");
}

template <typename VT> struct FragT;
template <> struct FragT<_Float16> { using type = f16x8; };
template <> struct FragT<__hip_bfloat16> { using type = s16x8; };

// occupancy target from LDS footprint (blocks/CU; 256-thr blocks -> arg = blocks)
template <bool SPLIT, bool GU, int BN>
constexpr int lbBlocks() {
    int tot = (SPLIT ? 1024 : 512) + ((SPLIT || GU) ? 2 : 1) * BN * 4; // 16B chunks
    int ldsB = tot * 32;                                              // dbuf bytes
    int blocks = (160 * 1024) / ldsB;
    return blocks > 4 ? 4 : blocks;
}

// ---------------------------------------------------------------- GEMM ----
// C[M,N] = A[M,K] * B^T (B stored [N,K], k-contiguous). BK=32 (CK=4 chunks).
// global_load_lds (16B) staging, double-buffered, depth-2 counted-vmcnt
// pipeline. XOR chunk-swizzle cs = c ^ ((r>>1)&3) on BOTH source and read.
// SPLIT: (hi, lo*1024) f16 pairs, cross terms in acc2, v = acc1+acc2/1024.
// GU: dual-B (gate/up), epilogue silu(g)*u -> bf16.  BN: 64 or 128.
// XSWZ: XCD-chunked M-ordering (A-panel slice stays L2-resident per XCD).
struct GemmP {
    const void *Ah, *Al;
    const void *Bh, *Bl, *Bh2;
    long lda, ldb, bExp, K;
    const int *poff, *gidx;
    const float *bias, *resid, *bw;
    float *outF, *outF2;
    __hip_bfloat16 *outBF;
    long ldc;
    int epi; // 0:+bias->f32  2:+resid->f32(dual)  5:plain scaled scatter-store (outF=scat)
};

template <typename VT, bool SPLIT, bool GATHER, bool GU, int BN, bool XSWZ = false>
__global__ __launch_bounds__(256, (lbBlocks<SPLIT, GU, BN>())) void gemm_k(GemmP p) {
    constexpr int BM = 128;
    constexpr int NJ = BN / 32;
    constexpr bool HAS2 = SPLIT || GU;
    constexpr int ACH = SPLIT ? 1024 : 512;   // A-region chunks (16B)
    constexpr int BCH = BN * 4;               // chunks per B matrix
    constexpr int NB = HAS2 ? 2 : 1;
    constexpr int TOT = ACH + NB * BCH;
    constexpr int NCH = TOT / 256;            // chunks staged per thread
    constexpr int BUFVT = TOT * 8;
    constexpr int AOFF2 = 4096;               // Al (SPLIT)
    constexpr int BOFF = ACH * 8;
    constexpr int B2OFF = (ACH + BCH) * 8;
    __shared__ __align__(16) VT s[2][BUFVT];
    const int tid = threadIdx.x, lane = tid & 63;
    const int wid = tid >> 6, wm = wid >> 1, wn = wid & 1;
    const int x = lane & 15, hi = lane >> 4;
    int mb = (int)blockIdx.x;
    if constexpr (XSWZ) mb = (mb & 7) * ((int)gridDim.x >> 3) + (mb >> 3);
    long m0 = (long)mb * BM, n0 = (long)blockIdx.y * BN;
    int e = 0;
    if (p.poff) {
        int tot = p.poff[Ec];
        if (m0 >= tot) return;
        while (m0 >= p.poff[e + 1]) ++e;
    }

    const VT *gs[NCH];
    int chd[NCH];
#pragma unroll
    for (int i = 0; i < NCH; ++i) {
        int ch = tid + i * 256;
        chd[i] = ch;
        if (ch < ACH) {
            int slab = ch >> 9, local = ch & 511;
            int r = local >> 2, c = local & 3;
            int cs = c ^ ((r >> 1) & 3);
            long ar = m0 + r;
            if (GATHER) ar = p.gidx[ar];
            const VT *mat = (SPLIT && slab == 1) ? (const VT *)p.Al : (const VT *)p.Ah;
            gs[i] = mat + ar * p.lda + cs * 8;
        } else {
            int idx = ch - ACH;
            int which = idx / BCH, local = idx % BCH;
            int r = local >> 2, c = local & 3;
            int cs = c ^ ((r >> 1) & 3);
            const VT *bmat = (which == 0) ? (const VT *)p.Bh
                           : (SPLIT ? (const VT *)p.Bl : (const VT *)p.Bh2);
            gs[i] = bmat + (long)e * p.bExp + (n0 + r) * p.ldb + cs * 8;
        }
    }

    f32x4 acc[4][NJ];
    f32x4 acc2[HAS2 ? 4 : 1][HAS2 ? NJ : 1];
#pragma unroll
    for (int i = 0; i < 4; ++i)
#pragma unroll
        for (int j = 0; j < NJ; ++j) {
            acc[i][j] = (f32x4){0.f, 0.f, 0.f, 0.f};
            if constexpr (HAS2) acc2[i][j] = (f32x4){0.f, 0.f, 0.f, 0.f};
        }

    using F8 = typename FragT<VT>::type;
    const int KT = (int)(p.K / 32);
    auto stageTo = [&](int kt, int b) {
#pragma unroll
        for (int i = 0; i < NCH; ++i)
            gll16(gs[i] + (long)kt * 32, &s[b][(size_t)chd[i] * 8]);
    };

    stageTo(0, 0);
    if (KT > 1) stageTo(1, 1);

    for (int kt = 0; kt < KT; ++kt) {
        if (kt + 1 < KT) wait_vm<NCH>();
        else wait_vm<0>();
        __builtin_amdgcn_sched_barrier(0);
        __builtin_amdgcn_s_barrier();
        __builtin_amdgcn_sched_barrier(0);
        const int cur = kt & 1;

        F8 afh[4], afl[SPLIT ? 4 : 1];
#pragma unroll
        for (int mi = 0; mi < 4; ++mi) {
            int ar = wm * 64 + mi * 16 + x;
            int ad = (ar * 4 + (hi ^ ((ar >> 1) & 3))) * 8;
            afh[mi] = *(const F8 *)&s[cur][ad];
            if constexpr (SPLIT) afl[mi] = *(const F8 *)&s[cur][AOFF2 + ad];
        }
        __builtin_amdgcn_s_setprio(1);
#pragma unroll
        for (int nj = 0; nj < NJ; ++nj) {
            int br = wn * (BN / 2) + nj * 16 + x;
            int bd = (br * 4 + (hi ^ ((br >> 1) & 3))) * 8;
            F8 bfh = *(const F8 *)&s[cur][BOFF + bd];
            F8 bf2;
            if constexpr (HAS2) bf2 = *(const F8 *)&s[cur][B2OFF + bd];
#pragma unroll
            for (int mi = 0; mi < 4; ++mi) {
                acc[mi][nj] = mfma16(afh[mi], bfh, acc[mi][nj]);
                if constexpr (SPLIT) {
                    acc2[mi][nj] = mfma16(afh[mi], bf2, acc2[mi][nj]);
                    acc2[mi][nj] = mfma16(afl[mi], bfh, acc2[mi][nj]);
                }
                if constexpr (GU) acc2[mi][nj] = mfma16(afh[mi], bf2, acc2[mi][nj]);
            }
        }
        __builtin_amdgcn_s_setprio(0);

        asm volatile("s_waitcnt lgkmcnt(0)" ::: "memory");
        __builtin_amdgcn_sched_barrier(0);
        __builtin_amdgcn_s_barrier();
        __builtin_amdgcn_sched_barrier(0);
        if (kt + 2 < KT) stageTo(kt + 2, cur);
    }

#pragma unroll
    for (int mi = 0; mi < 4; ++mi)
#pragma unroll
        for (int nj = 0; nj < NJ; ++nj)
#pragma unroll
            for (int r = 0; r < 4; ++r) {
                long row = m0 + wm * 64 + mi * 16 + hi * 4 + r;
                long col = n0 + wn * (BN / 2) + nj * 16 + x;
                float v = acc[mi][nj][r];
                if constexpr (GU) {
                    float u = acc2[mi][nj][r];
                    float he = v / (1.f + __expf(-v)) * u;
                    p.outBF[row * p.ldc + col] = __float2bfloat16(he);
                } else {
                    if constexpr (SPLIT) v = fmaf(acc2[mi][nj][r], LO_INV, v);
                    switch (p.epi) {
                    case 0: p.outF[row * p.ldc + col] = v + p.bias[col]; break;
                    case 2: {
                        float o = v + p.resid[row * p.ldc + col];
                        p.outF[row * p.ldc + col] = o;
                        p.outF2[row * p.ldc + col] = o;
                    } break;
                    case 5: // plain store to per-slot scratch, weight folded
                        p.outF[row * p.ldc + col] = v * p.bw[row];
                        break;
                    }
                }
            }
}

// combine: out[tok] += scat[slot0(tok)] + scat[slot1(tok)]  (coalesced f32x4)
__global__ __launch_bounds__(256) void combine_k(const float *__restrict__ scat,
        const int *__restrict__ tok_slot, float *__restrict__ out) {
    const long tok = blockIdx.x;
    const int c = threadIdx.x * 4;
    const long s0 = tok_slot[tok * 2], s1 = tok_slot[tok * 2 + 1];
    f32x4 a = *(const f32x4 *)(scat + s0 * Dc + c);
    f32x4 b = *(const f32x4 *)(scat + s1 * Dc + c);
    f32x4 o = *(const f32x4 *)(out + tok * Dc + c);
#pragma unroll
    for (int j = 0; j < 4; ++j) o[j] += a[j] + b[j];
    *(f32x4 *)(out + tok * Dc + c) = o;
}

// ----------------------------------------------------- flash attention ----
// 4-wave blocks, 64 q-rows (16/wave), diagonal-paired: block (pairI, bh)
// processes 64-row q-tiles pairI and 31-pairI sequentially -> uniform
// (2p+2)+(2(31-p)+2) = 66 kv-tiles per block. K/V staged ONCE per kv-tile
// for all 64 q-rows (wave roles: K-hi/K-lo/V-hi/V-lo, 4 gll16 each),
// depth-2 counted-vmcnt pipeline. Swapped QK^T, in-register softmax,
// defer-max (THR=8). Waves 0,1 skip their fully-masked last tile (myNT).
__global__ __launch_bounds__(256, 4) void attn_k(
    const _Float16 *__restrict__ qh, const _Float16 *__restrict__ ql,
    const _Float16 *__restrict__ kh, const _Float16 *__restrict__ kl,
    const _Float16 *__restrict__ vTh, const _Float16 *__restrict__ vTl,
    _Float16 *__restrict__ ctxh, _Float16 *__restrict__ ctxl) {
    __shared__ __align__(16) _Float16 kbuf[2][2][32 * 64]; // [dbuf][hi/lo][kv][d]
    __shared__ __align__(16) _Float16 vbuf[2][2][64 * 32]; // [dbuf][hi/lo][d][kv]
    const int tid = threadIdx.x, lane = tid & 63, wid = tid >> 6;
    const int x = lane & 15, hi = lane >> 4;
    const int pairI = blockIdx.x;        // [0,16)
    const int bh = blockIdx.y;
    const int b = bh >> 4, h = bh & 15, kvh = h >> 2;
    const long kRow0 = (long)b * Sc * 256;
    const long vRow0 = (long)(b * 4 + kvh) * 64 * (long)Sc;

    auto stage = [&](int kt, int bufI) {
        if (wid < 2) {           // K: [kv32][d64] CK=8, swizzle c^=(kv&7)
            const _Float16 *src = (wid == 1) ? kl : kh;
#pragma unroll
            for (int i = 0; i < 4; ++i) {
                int kv = 8 * i + (lane >> 3);
                int cd = (lane & 7) ^ (kv & 7);
                const _Float16 *g = src + kRow0 + ((long)kt * 32 + kv) * 256 + kvh * 64 + cd * 8;
                gll16(g, &kbuf[bufI][wid][i * 512]);
            }
        } else {                 // V^T: [d64][kv32] CK=4, swizzle c^=((d>>1)&3)
            const _Float16 *src = (wid == 3) ? vTl : vTh;
#pragma unroll
            for (int i = 0; i < 4; ++i) {
                int d = 16 * i + (lane >> 2);
                int ckv = (lane & 3) ^ ((d >> 1) & 3);
                const _Float16 *g = src + vRow0 + (long)d * Sc + (long)kt * 32 + ckv * 8;
                gll16(g, &vbuf[bufI][wid - 2][i * 512]);
            }
        }
    };

    for (int seg = 0; seg < 2; ++seg) {
        const int qt = seg ? (31 - pairI) : pairI;   // 64-row q-tile index
        const int q0 = qt * 64;
        const long qtokW = (long)b * Sc + q0 + wid * 16;  // wave's 16 q-rows

        // Q B-frags for this segment
        f16x8 qfh[2], qfl[2];
#pragma unroll
        for (int ks = 0; ks < 2; ++ks) {
            long off = (qtokW + x) * (long)Dc + h * 64 + ks * 32 + hi * 8;
            qfh[ks] = *(const f16x8 *)(qh + off);
            qfl[ks] = *(const f16x8 *)(ql + off);
        }
        asm volatile("s_waitcnt vmcnt(0)" ::: "memory"); // retire Q loads pre-pipeline
        __builtin_amdgcn_sched_barrier(0);

        f32x4 o1[4], o2[4];
        float mrow = -3.0e38f, lrow = 0.f;
#pragma unroll
        for (int dj = 0; dj < 4; ++dj) {
            o1[dj] = (f32x4){0.f, 0.f, 0.f, 0.f};
            o2[dj] = (f32x4){0.f, 0.f, 0.f, 0.f};
        }

        const int NT = 2 * qt + 2;
        const int myNT = NT - (wid < 2 ? 1 : 0); // waves 0,1: last tile fully masked

        stage(0, 0);
        stage(1, 1);             // NT >= 2 always

        for (int kt = 0; kt < NT; ++kt) {
            if (kt + 1 < NT) asm volatile("s_waitcnt vmcnt(4)" ::: "memory");
            else asm volatile("s_waitcnt vmcnt(0)" ::: "memory");
            __builtin_amdgcn_sched_barrier(0);
            __builtin_amdgcn_s_barrier();
            __builtin_amdgcn_sched_barrier(0);
            const int cur = kt & 1;

            if (kt < myNT) {
                // --- QK^T (A=K, B=Q) -> S[kv][q] ---
                f32x4 s1[2], s2[2]; // [kvsub]
#pragma unroll
                for (int kvs = 0; kvs < 2; ++kvs) {
                    s1[kvs] = (f32x4){0.f, 0.f, 0.f, 0.f};
                    s2[kvs] = (f32x4){0.f, 0.f, 0.f, 0.f};
                }
                __builtin_amdgcn_s_setprio(1);
#pragma unroll
                for (int ks = 0; ks < 2; ++ks)
#pragma unroll
                    for (int kvs = 0; kvs < 2; ++kvs) {
                        int row = kvs * 16 + x;
                        int addr = row * 64 + (((ks * 4 + hi) ^ (row & 7)) << 3);
                        f16x8 kfh = *(const f16x8 *)&kbuf[cur][0][addr];
                        f16x8 kfl = *(const f16x8 *)&kbuf[cur][1][addr];
                        s1[kvs] = mfma16(kfh, qfh[ks], s1[kvs]);
                        s2[kvs] = mfma16(kfl, qfh[ks], s2[kvs]);
                        s2[kvs] = mfma16(kfh, qfl[ks], s2[kvs]);
                    }
                __builtin_amdgcn_s_setprio(0);

                const bool diag = (kt == myNT - 1);
                const int qpos = q0 + wid * 16 + x;
                float sv[2][4];
#pragma unroll
                for (int kvs = 0; kvs < 2; ++kvs)
#pragma unroll
                    for (int r = 0; r < 4; ++r) {
                        float v = fmaf(s2[kvs][r], LO_INV, s1[kvs][r]) * 0.125f;
                        if (diag) {
                            int kvpos = kt * 32 + kvs * 16 + 4 * hi + r;
                            if (kvpos > qpos) v = -3.0e38f;
                        }
                        sv[kvs][r] = v;
                    }
                float mx = sv[0][0];
#pragma unroll
                for (int kvs = 0; kvs < 2; ++kvs)
#pragma unroll
                    for (int r = 0; r < 4; ++r) mx = fmaxf(mx, sv[kvs][r]);
                mx = fmaxf(mx, __shfl_xor(mx, 16));
                mx = fmaxf(mx, __shfl_xor(mx, 32));
                // defer-max: rescale only when some row grew by > 8
                if (!__all(mx - mrow <= 8.0f)) {
                    float mnew = fmaxf(mrow, mx);
                    float scl = __expf(mrow - mnew);
                    mrow = mnew;
                    lrow *= scl;
                    float sclr[4];
#pragma unroll
                    for (int r = 0; r < 4; ++r) sclr[r] = __shfl(scl, 4 * hi + r);
#pragma unroll
                    for (int dj = 0; dj < 4; ++dj)
#pragma unroll
                        for (int r = 0; r < 4; ++r) {
                            o1[dj][r] *= sclr[r];
                            o2[dj][r] *= sclr[r];
                        }
                }
                float pv[2][4];
                float ls = 0.f;
#pragma unroll
                for (int kvs = 0; kvs < 2; ++kvs)
#pragma unroll
                    for (int r = 0; r < 4; ++r) {
                        pv[kvs][r] = __expf(sv[kvs][r] - mrow);
                        ls += pv[kvs][r];
                    }
                ls += __shfl_xor(ls, 16);
                ls += __shfl_xor(ls, 32);
                lrow += ls;
                // pack P (hi/lo split) and shuffle into PV A-frag layout
                u32 Bh0[2], Bh1[2], Bl0[2], Bl1[2];
#pragma unroll
                for (int pr = 0; pr < 2; ++pr) {
                    _Float16 a0 = (_Float16)pv[0][2 * pr], a1 = (_Float16)pv[0][2 * pr + 1];
                    _Float16 b0 = (_Float16)pv[1][2 * pr], b1 = (_Float16)pv[1][2 * pr + 1];
                    Bh0[pr] = pack2(a0, a1);
                    Bh1[pr] = pack2(b0, b1);
                    _Float16 la0 = (_Float16)((pv[0][2 * pr] - (float)a0) * LO_SCALE);
                    _Float16 la1 = (_Float16)((pv[0][2 * pr + 1] - (float)a1) * LO_SCALE);
                    _Float16 lb0 = (_Float16)((pv[1][2 * pr] - (float)b0) * LO_SCALE);
                    _Float16 lb1 = (_Float16)((pv[1][2 * pr + 1] - (float)b1) * LO_SCALE);
                    Bl0[pr] = pack2(la0, la1);
                    Bl1[pr] = pack2(lb0, lb1);
                }
                const int srcLow = x + ((lane & 16) ? 32 : 0);
                const int srcHigh = srcLow + 16;
                const bool useB1 = lane >= 32;
                union { u32 u[4]; f16x8 v; } fh, fl;
#pragma unroll
                for (int pr = 0; pr < 2; ++pr) {
                    u32 t0 = (u32)__shfl((int)Bh0[pr], srcLow);
                    u32 t1 = (u32)__shfl((int)Bh1[pr], srcLow);
                    fh.u[pr] = useB1 ? t1 : t0;
                    u32 u0 = (u32)__shfl((int)Bh0[pr], srcHigh);
                    u32 u1 = (u32)__shfl((int)Bh1[pr], srcHigh);
                    fh.u[2 + pr] = useB1 ? u1 : u0;
                    u32 s0 = (u32)__shfl((int)Bl0[pr], srcLow);
                    u32 s1v = (u32)__shfl((int)Bl1[pr], srcLow);
                    fl.u[pr] = useB1 ? s1v : s0;
                    u32 w0 = (u32)__shfl((int)Bl0[pr], srcHigh);
                    u32 w1 = (u32)__shfl((int)Bl1[pr], srcHigh);
                    fl.u[2 + pr] = useB1 ? w1 : w0;
                }
                f16x8 pah = fh.v, pal = fl.v;

                // --- PV: A=P[q16][kv32], B=V^T[d][kv] ---
                __builtin_amdgcn_s_setprio(1);
#pragma unroll
                for (int dj = 0; dj < 4; ++dj) {
                    int d = dj * 16 + x;
                    int addr = d * 32 + ((hi ^ ((d >> 1) & 3)) << 3);
                    f16x8 vhf = *(const f16x8 *)&vbuf[cur][0][addr];
                    f16x8 vlf = *(const f16x8 *)&vbuf[cur][1][addr];
                    o1[dj] = mfma16(pah, vhf, o1[dj]);
                    o2[dj] = mfma16(pah, vlf, o2[dj]);
                    o2[dj] = mfma16(pal, vhf, o2[dj]);
                }
                __builtin_amdgcn_s_setprio(0);
            }

            asm volatile("s_waitcnt lgkmcnt(0)" ::: "memory");
            __builtin_amdgcn_sched_barrier(0);
            __builtin_amdgcn_s_barrier();
            __builtin_amdgcn_sched_barrier(0);
            if (kt + 2 < NT) stage(kt + 2, cur);
        }

        // epilogue: normalize + hi/lo split store
        float linv = 1.0f / lrow;
        float lr[4];
#pragma unroll
        for (int r = 0; r < 4; ++r) lr[r] = __shfl(linv, 4 * hi + r);
#pragma unroll
        for (int dj = 0; dj < 4; ++dj)
#pragma unroll
            for (int r = 0; r < 4; ++r) {
                long tok = qtokW + 4 * hi + r;
                float ov = fmaf(o2[dj][r], LO_INV, o1[dj][r]) * lr[r];
                _Float16 hv = (_Float16)ov;
                long off = tok * Dc + h * 64 + dj * 16 + x;
                ctxh[off] = hv;
                ctxl[off] = (_Float16)((ov - (float)hv) * LO_SCALE);
            }
    }
}

// ------------------------------------------------------- small kernels ----
__global__ __launch_bounds__(256) void rmsnorm_split_k(const float *__restrict__ x,
        const float *__restrict__ w, _Float16 *__restrict__ oh, _Float16 *__restrict__ ol) {
    const long row = blockIdx.x;
    const int tid = threadIdx.x, lane = tid & 63, wid = tid >> 6;
    f32x4 v = *(const f32x4 *)(x + row * Dc + tid * 4);
    float ss = v[0] * v[0] + v[1] * v[1] + v[2] * v[2] + v[3] * v[3];
#pragma unroll
    for (int off = 1; off < 64; off <<= 1) ss += __shfl_xor(ss, off);
    __shared__ float sw[4];
    if (lane == 0) sw[wid] = ss;
    __syncthreads();
    float inv = 1.0f / sqrtf((sw[0] + sw[1] + sw[2] + sw[3]) * (1.f / Dc) + 1e-6f);
#pragma unroll
    for (int j = 0; j < 4; ++j) {
        float y = v[j] * inv * w[tid * 4 + j];
        _Float16 hv = (_Float16)y;
        oh[row * Dc + tid * 4 + j] = hv;
        ol[row * Dc + tid * 4 + j] = (_Float16)((y - (float)hv) * LO_SCALE);
    }
}

__global__ __launch_bounds__(256) void rmsnorm2_k(const float *__restrict__ x,
        const float *__restrict__ w, float *__restrict__ tf, __hip_bfloat16 *__restrict__ tb) {
    const long row = blockIdx.x;
    const int tid = threadIdx.x, lane = tid & 63, wid = tid >> 6;
    f32x4 v = *(const f32x4 *)(x + row * Dc + tid * 4);
    float ss = v[0] * v[0] + v[1] * v[1] + v[2] * v[2] + v[3] * v[3];
#pragma unroll
    for (int off = 1; off < 64; off <<= 1) ss += __shfl_xor(ss, off);
    __shared__ float sw[4];
    if (lane == 0) sw[wid] = ss;
    __syncthreads();
    float inv = 1.0f / sqrtf((sw[0] + sw[1] + sw[2] + sw[3]) * (1.f / Dc) + 1e-6f);
#pragma unroll
    for (int j = 0; j < 4; ++j) {
        float y = v[j] * inv * w[tid * 4 + j];
        tf[row * Dc + tid * 4 + j] = y;
        tb[row * Dc + tid * 4 + j] = __float2bfloat16(y);
    }
}

__global__ void split_f16_k(const float *__restrict__ x, _Float16 *hi, _Float16 *lo, long n) {
    for (long i = (long)blockIdx.x * 256 + threadIdx.x; i < n; i += (long)gridDim.x * 256) {
        float v = x[i];
        _Float16 h = (_Float16)v;
        hi[i] = h;
        lo[i] = (_Float16)((v - (float)h) * LO_SCALE);
    }
}

__global__ void pack_qkvw_k(const float *__restrict__ qw, const float *__restrict__ kw,
        const float *__restrict__ vw, _Float16 *wh, _Float16 *wl) {
    const long n = (long)QKVN * Dc;
    for (long i = (long)blockIdx.x * 256 + threadIdx.x; i < n; i += (long)gridDim.x * 256) {
        long o = i >> 10;
        int d = (int)(i & 1023);
        float v;
        if (o < 1024) v = qw[o * 1024 + d];
        else if (o < 1280) v = kw[(o - 1024) * 1024 + d];
        else v = vw[(o - 1280) * 1024 + d];
        _Float16 h = (_Float16)v;
        wh[i] = h;
        wl[i] = (_Float16)((v - (float)h) * LO_SCALE);
    }
}

__global__ void pack_bias_k(const float *qb, const float *kb, const float *vb, float *out) {
    int i = blockIdx.x * 256 + threadIdx.x;
    if (i >= QKVN) return;
    out[i] = (i < 1024) ? qb[i] : (i < 1280) ? kb[i - 1024] : vb[i - 1280];
}

__global__ __launch_bounds__(256) void transpose_bf16_k(const float *__restrict__ in,
        __hip_bfloat16 *__restrict__ out, int R, int C) {
    __shared__ float tile[64 * 65];
    const long eo = (long)blockIdx.z * R * C;
    const int r0 = blockIdx.y * 64, c0 = blockIdx.x * 64;
#pragma unroll
    for (int i = 0; i < 16; ++i) {
        int idx = threadIdx.x + i * 256;
        int r = idx >> 6, c = idx & 63;
        tile[r * 65 + c] = in[eo + (long)(r0 + r) * C + (c0 + c)];
    }
    __syncthreads();
#pragma unroll
    for (int i = 0; i < 16; ++i) {
        int idx = threadIdx.x + i * 256;
        int cc = idx >> 6, rr = idx & 63;
        out[eo + (long)(c0 + cc) * R + (r0 + rr)] = __float2bfloat16(tile[rr * 65 + cc]);
    }
}

// V needs no RoPE: transpose V section of qkvf to [B*KV*64][S] with hi/lo split
__global__ __launch_bounds__(256) void vtrans_k(const float *__restrict__ qkvf,
        _Float16 *__restrict__ vTh, _Float16 *__restrict__ vTl) {
    __shared__ float tile[64][65];
    const int tok0 = blockIdx.x * 64;
    const int bk = blockIdx.y;
    const int b = bk >> 2, kvh = bk & 3;
#pragma unroll
    for (int it = 0; it < 16; ++it) {
        int idx = it * 256 + threadIdx.x;
        int r = idx >> 6, c = idx & 63;
        tile[r][c] = qkvf[((long)b * Sc + tok0 + r) * QKVN + 1280 + kvh * 64 + c];
    }
    __syncthreads();
    const int d = threadIdx.x & 63, ch = threadIdx.x >> 6;
    long orow = ((long)bk * 64 + d) * (long)Sc + tok0 + ch * 16;
    f16x8 oh[2], ol[2];
#pragma unroll
    for (int j = 0; j < 16; ++j) {
        float v = tile[ch * 16 + j][d];
        _Float16 hv = (_Float16)v;
        oh[j >> 3][j & 7] = hv;
        ol[j >> 3][j & 7] = (_Float16)((v - (float)hv) * LO_SCALE);
    }
    *(f16x8 *)(vTh + orow) = oh[0];
    *(f16x8 *)(vTh + orow + 8) = oh[1];
    *(f16x8 *)(vTl + orow) = ol[0];
    *(f16x8 *)(vTl + orow + 8) = ol[1];
}

__global__ __launch_bounds__(256) void rope_k(const float *__restrict__ qkv,
        const float *__restrict__ cosb, const float *__restrict__ sinb,
        _Float16 *qh, _Float16 *ql, _Float16 *kh2, _Float16 *kl2) {
    const long tok = blockIdx.x;
    const int s = (int)(tok % Sc);
    const float *row = qkv + tok * QKVN;
    for (int p = threadIdx.x; p < 640; p += 256) {
        int u = p >> 5, d = p & 31;
        float x1 = row[u * 64 + d], x2 = row[u * 64 + d + 32];
        float cs = cosb[(long)s * 64 + d], sn = sinb[(long)s * 64 + d];
        float o1v = x1 * cs - x2 * sn;
        float o2v = x2 * cs + x1 * sn;
        _Float16 h1 = (_Float16)o1v, h2 = (_Float16)o2v;
        _Float16 l1 = (_Float16)((o1v - (float)h1) * LO_SCALE);
        _Float16 l2 = (_Float16)((o2v - (float)h2) * LO_SCALE);
        if (u < 16) {
            long off = tok * 1024 + u * 64 + d;
            qh[off] = h1; ql[off] = l1; qh[off + 32] = h2; ql[off + 32] = l2;
        } else {
            long off = tok * 256 + (u - 16) * 64 + d;
            kh2[off] = h1; kl2[off] = l1; kh2[off + 32] = h2; kl2[off + 32] = l2;
        }
    }
}

__global__ __launch_bounds__(256) void router_p1_k(const float *__restrict__ t,
        const float *__restrict__ rw, float *probs, int *tok_e, float *tok_w, int *cnt) {
    const int tid = threadIdx.x, lane = tid & 63, wid = tid >> 6;
    const long tok = (long)blockIdx.x * 4 + wid;
    const float *row = t + tok * Dc;
    const int d0 = lane * 16;
    f32x4 xv[4];
#pragma unroll
    for (int i = 0; i < 4; ++i) xv[i] = *(const f32x4 *)(row + d0 + i * 4);
    float acc[8];
#pragma unroll
    for (int e = 0; e < 8; ++e) {
        const float *wr = rw + (long)e * Dc + d0;
        float a = 0.f;
#pragma unroll
        for (int i = 0; i < 4; ++i) {
            f32x4 wv = *(const f32x4 *)(wr + i * 4);
            a += xv[i][0] * wv[0] + xv[i][1] * wv[1] + xv[i][2] * wv[2] + xv[i][3] * wv[3];
        }
        acc[e] = a;
    }
#pragma unroll
    for (int off = 1; off < 64; off <<= 1)
#pragma unroll
        for (int e = 0; e < 8; ++e) acc[e] += __shfl_xor(acc[e], off);
    if (lane == 0) {
        float mx = acc[0];
#pragma unroll
        for (int e = 1; e < 8; ++e) mx = fmaxf(mx, acc[e]);
        float ex[8], s = 0.f;
#pragma unroll
        for (int e = 0; e < 8; ++e) { ex[e] = expf(acc[e] - mx); s += ex[e]; }
        float inv = 1.f / s;
        int i1 = -1, i2 = -1;
        float p1v = -1.f, p2v = -1.f;
#pragma unroll
        for (int e = 0; e < 8; ++e) {
            float pe = ex[e] * inv;
            probs[tok * 8 + e] = pe;
            if (pe > p1v) { i2 = i1; p2v = p1v; i1 = e; p1v = pe; }
            else if (pe > p2v) { i2 = e; p2v = pe; }
        }
        float wsum = p1v + p2v;
        tok_e[tok * 2] = i1; tok_e[tok * 2 + 1] = i2;
        tok_w[tok * 2] = p1v / wsum; tok_w[tok * 2 + 1] = p2v / wsum;
        atomicAdd(&cnt[i1], 1);
        atomicAdd(&cnt[i2], 1);
    }
}

__global__ __launch_bounds__(1024) void router_p2_k(const int *cnt, const float *probs,
        int *poff, float *aux_out) {
    __shared__ float sd[1024];
    const int tid = threadIdx.x;
    const int e = tid & 7, rs = tid >> 3;
    float s = 0.f;
    for (int r = rs; r < Tc; r += 128) s += probs[(long)r * 8 + e];
    sd[tid] = s;
    __syncthreads();
    for (int st = 64; st >= 1; st >>= 1) {
        if (rs < st) sd[tid] += sd[tid + st * 8];
        __syncthreads();
    }
    if (tid == 0) {
        float a = 0.f;
        for (int ee = 0; ee < 8; ++ee) {
            float m = sd[ee] * (1.f / Tc);
            a += m * m;
        }
        aux_out[0] = a;
        int o = 0;
        poff[0] = 0;
        for (int ee = 0; ee < 8; ++ee) { o += (cnt[ee] + 127) & ~127; poff[ee + 1] = o; }
    }
}

__global__ void router_p3_k(const int *tok_e, const float *tok_w, const int *poff,
        int *cursor, int *btok, float *bw, int *tok_slot) {
    long tok = (long)blockIdx.x * 256 + threadIdx.x;
    if (tok >= Tc) return;
#pragma unroll
    for (int j = 0; j < 2; ++j) {
        int e = tok_e[tok * 2 + j];
        int slot = atomicAdd(&cursor[e], 1);
        btok[poff[e] + slot] = (int)tok;
        bw[poff[e] + slot] = tok_w[tok * 2 + j];
        tok_slot[tok * 2 + j] = poff[e] + slot;
    }
}

__global__ void router_p4_k(const int *poff, const int *cnt, int *btok, float *bw) {
    int s = blockIdx.x * 256 + threadIdx.x;
    if (s >= poff[8]) return;
    int e = 0;
    while (s >= poff[e + 1]) ++e;
    if (s - poff[e] >= cnt[e]) { btok[s] = 0; bw[s] = 0.f; }
}

// -------------------------------------------------------------- launch ----
extern "C" void kernel_launch(void *const *d_in, const int *in_sizes, int n_in,
                              void *d_out, int out_size, void *d_ws, size_t ws_size,
                              hipStream_t stream) {
    (void)in_sizes; (void)n_in;
    const float *hidden = (const float *)d_in[0];
    const float *ln1 = (const float *)d_in[1];
    const float *ln2 = (const float *)d_in[2];
    const float *qw = (const float *)d_in[3];
    const float *qb = (const float *)d_in[4];
    const float *kw = (const float *)d_in[5];
    const float *kb = (const float *)d_in[6];
    const float *vw = (const float *)d_in[7];
    const float *vb = (const float *)d_in[8];
    const float *ow = (const float *)d_in[9];
    const float *rw = (const float *)d_in[10];
    const float *gw = (const float *)d_in[11];
    const float *uw = (const float *)d_in[12];
    const float *dwn = (const float *)d_in[13];
    const float *cosb = (const float *)d_in[14];
    const float *sinb = (const float *)d_in[15];
    float *outx = (float *)d_out;

    char *base = (char *)d_ws;
    size_t off = 0;
    auto alloc = [&](size_t bytes) -> char * {
        char *p = base + off;
        off += (bytes + 255) & ~(size_t)255;
        return p;
    };
    _Float16 *qkvwh = (_Float16 *)alloc((size_t)QKVN * Dc * 2);
    _Float16 *qkvwl = (_Float16 *)alloc((size_t)QKVN * Dc * 2);
    float *qkvb = (float *)alloc(QKVN * 4);
    _Float16 *owh = (_Float16 *)alloc((size_t)Dc * Dc * 2);
    _Float16 *owl = (_Float16 *)alloc((size_t)Dc * Dc * 2);
    __hip_bfloat16 *gateT = (__hip_bfloat16 *)alloc((size_t)Ec * Fc * Dc * 2);
    __hip_bfloat16 *upT = (__hip_bfloat16 *)alloc((size_t)Ec * Fc * Dc * 2);
    __hip_bfloat16 *downT = (__hip_bfloat16 *)alloc((size_t)Ec * Dc * Fc * 2);
    // U2..vTl span (~40 MB) is dead by down-GEMM time; scat (36 MB) aliases it
    char *U2 = alloc((size_t)Tc * Dc * 4);
    _Float16 *hh = (_Float16 *)U2;
    _Float16 *hl = hh + (size_t)Tc * Dc;
    float *tf = (float *)U2;
    char *U3 = alloc((size_t)Tc * Dc * 4);
    _Float16 *qhb = (_Float16 *)U3;
    _Float16 *qlb = qhb + (size_t)Tc * Dc;
    float *x1 = (float *)U3;
    _Float16 *khb = (_Float16 *)alloc((size_t)Tc * 256 * 2);
    _Float16 *klb = (_Float16 *)alloc((size_t)Tc * 256 * 2);
    _Float16 *vTh = (_Float16 *)alloc((size_t)Tc * 256 * 2);
    _Float16 *vTl = (_Float16 *)alloc((size_t)Tc * 256 * 2);
    float *scat = (float *)U2;   // CAP*Dc*4 = 36 MB <= U2..vTl span (~40 MB)
    _Float16 *ctxh = (_Float16 *)alloc((size_t)Tc * Dc * 2);
    _Float16 *ctxl = (_Float16 *)alloc((size_t)Tc * Dc * 2);
    __hip_bfloat16 *tbf = (__hip_bfloat16 *)alloc((size_t)Tc * Dc * 2);
    float *probs = (float *)alloc((size_t)Tc * 8 * 4);
    int *tok_e = (int *)alloc((size_t)Tc * 2 * 4);
    float *tok_w = (float *)alloc((size_t)Tc * 2 * 4);
    int *tok_slot = (int *)alloc((size_t)Tc * 2 * 4);
    int *cnt = (int *)alloc(256);
    int *cursor = cnt + 8;
    int *poff = (int *)alloc(256);
    int *btok = (int *)alloc((size_t)CAP * 4);
    float *bwgt = (float *)alloc((size_t)CAP * 4);
    size_t qkvfB = (size_t)Tc * QKVN * 4;
    size_t gbufB = (size_t)CAP * Fc * 2;
    size_t u1B = qkvfB > gbufB ? qkvfB : gbufB;
    char *U1 = alloc(u1B);
    float *qkvf = (float *)U1;
    __hip_bfloat16 *gbuf = (__hip_bfloat16 *)U1;

    if (off > ws_size) {
        hipMemsetAsync(d_out, 0, (size_t)out_size * 4, stream);
        return;
    }

    hipMemsetAsync(cnt, 0, 64, stream);
    pack_qkvw_k<<<1024, 256, 0, stream>>>(qw, kw, vw, qkvwh, qkvwl);
    pack_bias_k<<<(QKVN + 255) / 256, 256, 0, stream>>>(qb, kb, vb, qkvb);
    split_f16_k<<<1024, 256, 0, stream>>>(ow, owh, owl, (long)Dc * Dc);
    transpose_bf16_k<<<dim3(Fc / 64, Dc / 64, Ec), 256, 0, stream>>>(gw, gateT, Dc, Fc);
    transpose_bf16_k<<<dim3(Fc / 64, Dc / 64, Ec), 256, 0, stream>>>(uw, upT, Dc, Fc);
    transpose_bf16_k<<<dim3(Dc / 64, Fc / 64, Ec), 256, 0, stream>>>(dwn, downT, Fc, Dc);
    rmsnorm_split_k<<<Tc, 256, 0, stream>>>(hidden, ln1, hh, hl);

    GemmP g{};
    g.Ah = hh; g.Al = hl; g.Bh = qkvwh; g.Bl = qkvwl;
    g.lda = Dc; g.ldb = Dc; g.bExp = 0; g.K = Dc;
    g.bias = qkvb; g.outF = qkvf; g.ldc = QKVN; g.epi = 0;
    gemm_k<_Float16, true, false, false, 128><<<dim3(Tc / 128, QKVN / 128), 256, 0, stream>>>(g);

    rope_k<<<Tc, 256, 0, stream>>>(qkvf, cosb, sinb, qhb, qlb, khb, klb);
    vtrans_k<<<dim3(Sc / 64, Bc * KVc), 256, 0, stream>>>(qkvf, vTh, vTl);
    attn_k<<<dim3(16, Bc * Hc), 256, 0, stream>>>(qhb, qlb, khb, klb, vTh, vTl, ctxh, ctxl);

    GemmP go{};
    go.Ah = ctxh; go.Al = ctxl; go.Bh = owh; go.Bl = owl;
    go.lda = Dc; go.ldb = Dc; go.bExp = 0; go.K = Dc;
    go.resid = hidden; go.outF = x1; go.outF2 = outx; go.ldc = Dc; go.epi = 2;
    gemm_k<_Float16, true, false, false, 128><<<dim3(Tc / 128, Dc / 128), 256, 0, stream>>>(go);

    rmsnorm2_k<<<Tc, 256, 0, stream>>>(x1, ln2, tf, tbf);
    router_p1_k<<<Tc / 4, 256, 0, stream>>>(tf, rw, probs, tok_e, tok_w, cnt);
    router_p2_k<<<1, 1024, 0, stream>>>(cnt, probs, poff, outx + (long)Tc * Dc);
    router_p3_k<<<Tc / 256, 256, 0, stream>>>(tok_e, tok_w, poff, cursor, btok, bwgt, tok_slot);
    router_p4_k<<<CAP / 256, 256, 0, stream>>>(poff, cnt, btok, bwgt);

    // fused gate+up: he = silu(t@gate) * (t@up) -> gbuf (bf16), XCD-chunked M
    GemmP gg{};
    gg.Ah = tbf; gg.Bh = gateT; gg.Bh2 = upT;
    gg.lda = Dc; gg.ldb = Dc; gg.bExp = (long)Fc * Dc; gg.K = Dc;
    gg.poff = poff; gg.gidx = btok; gg.outBF = gbuf; gg.ldc = Fc;
    gemm_k<__hip_bfloat16, false, true, true, 128, true><<<dim3(CAP / 128, Fc / 128), 256, 0, stream>>>(gg);

    // down: BN=128, plain weighted store to per-slot scratch, XCD-chunked M
    GemmP gd{};
    gd.Ah = gbuf; gd.Bh = downT;
    gd.lda = Fc; gd.ldb = Fc; gd.bExp = (long)Dc * Fc; gd.K = Fc;
    gd.poff = poff; gd.bw = bwgt;
    gd.outF = scat; gd.ldc = Dc; gd.epi = 5;
    gemm_k<__hip_bfloat16, false, false, false, 128, true><<<dim3(CAP / 128, Dc / 128), 256, 0, stream>>>(gd);

    // combine: outx[tok] += scat[slot0] + scat[slot1]
    combine_k<<<Tc, 256, 0, stream>>>(scat, tok_slot, outx);
}

// Round 11
// 712.261 us; speedup vs baseline: 1.1821x; 1.1821x over previous
//
#include <hip/hip_runtime.h>
#include <hip/hip_bf16.h>

#define DEVI __device__ __forceinline__

typedef float f32x4 __attribute__((ext_vector_type(4)));
typedef _Float16 f16x8 __attribute__((ext_vector_type(8)));
typedef short s16x8 __attribute__((ext_vector_type(8)));
typedef unsigned int u32;

constexpr int Bc = 2, Sc = 2048, Dc = 1024, Hc = 16, KVc = 4, HDc = 64, Fc = 2816, Ec = 8;
constexpr int Tc = Bc * Sc;                 // 4096 tokens
constexpr int QKVN = Hc * HDc + 2 * KVc * HDc; // 1536
constexpr int CAP = Tc * 2 + Ec * 128;      // 9216 padded expert-token slots
constexpr float LO_SCALE = 1024.0f;
constexpr float LO_INV = 1.0f / 1024.0f;

DEVI f32x4 mfma16(f16x8 a, f16x8 b, f32x4 c) {
    return __builtin_amdgcn_mfma_f32_16x16x32_f16(a, b, c, 0, 0, 0);
}
DEVI f32x4 mfma16(s16x8 a, s16x8 b, f32x4 c) {
    return __builtin_amdgcn_mfma_f32_16x16x32_bf16(a, b, c, 0, 0, 0);
}

DEVI void gll16(const void *g, void *l) {
    __builtin_amdgcn_global_load_lds(
        (const __attribute__((address_space(1))) u32 *)g,
        (__attribute__((address_space(3))) u32 *)l, 16, 0, 0);
}

DEVI u32 pack2(_Float16 a, _Float16 b) {
    union { _Float16 h[2]; u32 u; } t;
    t.h[0] = a; t.h[1] = b;
    return t.u;
}

template <int N> DEVI void wait_vm() {
    if constexpr (N == 0) asm volatile("s_waitcnt vmcnt(0)" ::: "memory");
    else if constexpr (N == 3) asm volatile("s_waitcnt vmcnt(3)" ::: "memory");
    else if constexpr (N == 4) asm volatile("s_waitcnt vmcnt(4)" ::: "memory");
    else if constexpr (N == 6) asm volatile("s_waitcnt vmcnt(6)" ::: "memory");
    else if constexpr (N == 8) asm volatile("s_waitcnt vmcnt(8)" ::: "memory");
    else if constexpr (N == 12) asm volatile("s_waitcnt vmcnt(12)" ::: "memory");
}

template <typename VT> struct FragT;
template <> struct FragT<_Float16> { using type = f16x8; };
template <> struct FragT<__hip_bfloat16> { using type = s16x8; };

// ---------------------------------------------------------------- GEMM ----
// C[M,N] = A[M,K] * B^T (B stored [N,K], k-contiguous). BK=32 (CK=4 chunks).
// global_load_lds (16B) staging, double-buffered, depth-2 counted-vmcnt
// pipeline. XOR chunk-swizzle cs = c ^ ((r>>1)&3) on BOTH source and read.
// SPLIT: (hi, lo*1024) f16 pairs, cross terms in acc2, v = acc1+acc2/1024.
// GU: dual-B (gate/up), epilogue silu(g)*u -> bf16.  BN: 64 or 128.
// XSWZ: XCD-chunked M-ordering (A-panel slice stays L2-resident per XCD).
// Launch bounds are REGISTER-AWARE (R10 lesson): unified VGPR+AGPR file means
// dual-accumulator variants (SPLIT / GU) need ~224 regs -> min-waves/EU = 2
// (cap 256). Forcing 3 (cap ~170) makes the compiler spill accumulators to
// scratch: R10 measured WRITE_SIZE 48->213 MB and 2x duration on GU.
struct GemmP {
    const void *Ah, *Al;
    const void *Bh, *Bl, *Bh2;
    long lda, ldb, bExp, K;
    const int *poff, *gidx;
    const float *bias, *resid, *bw;
    float *outF, *outF2;
    __hip_bfloat16 *outBF;
    long ldc;
    int epi; // 0:+bias->f32  2:+resid->f32(dual)  5:plain scaled scatter-store (outF=scat)
};

template <typename VT, bool SPLIT, bool GATHER, bool GU, int BN, bool XSWZ = false>
__global__ __launch_bounds__(256, (SPLIT || GU) ? 2 : 4) void gemm_k(GemmP p) {
    constexpr int BM = 128;
    constexpr int NJ = BN / 32;
    constexpr bool HAS2 = SPLIT || GU;
    constexpr int ACH = SPLIT ? 1024 : 512;   // A-region chunks (16B)
    constexpr int BCH = BN * 4;               // chunks per B matrix
    constexpr int NB = HAS2 ? 2 : 1;
    constexpr int TOT = ACH + NB * BCH;
    constexpr int NCH = TOT / 256;            // chunks staged per thread
    constexpr int BUFVT = TOT * 8;
    constexpr int AOFF2 = 4096;               // Al (SPLIT)
    constexpr int BOFF = ACH * 8;
    constexpr int B2OFF = (ACH + BCH) * 8;
    __shared__ __align__(16) VT s[2][BUFVT];
    const int tid = threadIdx.x, lane = tid & 63;
    const int wid = tid >> 6, wm = wid >> 1, wn = wid & 1;
    const int x = lane & 15, hi = lane >> 4;
    int mb = (int)blockIdx.x;
    if constexpr (XSWZ) mb = (mb & 7) * ((int)gridDim.x >> 3) + (mb >> 3);
    long m0 = (long)mb * BM, n0 = (long)blockIdx.y * BN;
    int e = 0;
    if (p.poff) {
        int tot = p.poff[Ec];
        if (m0 >= tot) return;
        while (m0 >= p.poff[e + 1]) ++e;
    }

    const VT *gs[NCH];
    int chd[NCH];
#pragma unroll
    for (int i = 0; i < NCH; ++i) {
        int ch = tid + i * 256;
        chd[i] = ch;
        if (ch < ACH) {
            int slab = ch >> 9, local = ch & 511;
            int r = local >> 2, c = local & 3;
            int cs = c ^ ((r >> 1) & 3);
            long ar = m0 + r;
            if (GATHER) ar = p.gidx[ar];
            const VT *mat = (SPLIT && slab == 1) ? (const VT *)p.Al : (const VT *)p.Ah;
            gs[i] = mat + ar * p.lda + cs * 8;
        } else {
            int idx = ch - ACH;
            int which = idx / BCH, local = idx % BCH;
            int r = local >> 2, c = local & 3;
            int cs = c ^ ((r >> 1) & 3);
            const VT *bmat = (which == 0) ? (const VT *)p.Bh
                           : (SPLIT ? (const VT *)p.Bl : (const VT *)p.Bh2);
            gs[i] = bmat + (long)e * p.bExp + (n0 + r) * p.ldb + cs * 8;
        }
    }

    f32x4 acc[4][NJ];
    f32x4 acc2[HAS2 ? 4 : 1][HAS2 ? NJ : 1];
#pragma unroll
    for (int i = 0; i < 4; ++i)
#pragma unroll
        for (int j = 0; j < NJ; ++j) {
            acc[i][j] = (f32x4){0.f, 0.f, 0.f, 0.f};
            if constexpr (HAS2) acc2[i][j] = (f32x4){0.f, 0.f, 0.f, 0.f};
        }

    using F8 = typename FragT<VT>::type;
    const int KT = (int)(p.K / 32);
    auto stageTo = [&](int kt, int b) {
#pragma unroll
        for (int i = 0; i < NCH; ++i)
            gll16(gs[i] + (long)kt * 32, &s[b][(size_t)chd[i] * 8]);
    };

    stageTo(0, 0);
    if (KT > 1) stageTo(1, 1);

    for (int kt = 0; kt < KT; ++kt) {
        if (kt + 1 < KT) wait_vm<NCH>();
        else wait_vm<0>();
        __builtin_amdgcn_sched_barrier(0);
        __builtin_amdgcn_s_barrier();
        __builtin_amdgcn_sched_barrier(0);
        const int cur = kt & 1;

        F8 afh[4], afl[SPLIT ? 4 : 1];
#pragma unroll
        for (int mi = 0; mi < 4; ++mi) {
            int ar = wm * 64 + mi * 16 + x;
            int ad = (ar * 4 + (hi ^ ((ar >> 1) & 3))) * 8;
            afh[mi] = *(const F8 *)&s[cur][ad];
            if constexpr (SPLIT) afl[mi] = *(const F8 *)&s[cur][AOFF2 + ad];
        }
        __builtin_amdgcn_s_setprio(1);
#pragma unroll
        for (int nj = 0; nj < NJ; ++nj) {
            int br = wn * (BN / 2) + nj * 16 + x;
            int bd = (br * 4 + (hi ^ ((br >> 1) & 3))) * 8;
            F8 bfh = *(const F8 *)&s[cur][BOFF + bd];
            F8 bf2;
            if constexpr (HAS2) bf2 = *(const F8 *)&s[cur][B2OFF + bd];
#pragma unroll
            for (int mi = 0; mi < 4; ++mi) {
                acc[mi][nj] = mfma16(afh[mi], bfh, acc[mi][nj]);
                if constexpr (SPLIT) {
                    acc2[mi][nj] = mfma16(afh[mi], bf2, acc2[mi][nj]);
                    acc2[mi][nj] = mfma16(afl[mi], bfh, acc2[mi][nj]);
                }
                if constexpr (GU) acc2[mi][nj] = mfma16(afh[mi], bf2, acc2[mi][nj]);
            }
        }
        __builtin_amdgcn_s_setprio(0);

        asm volatile("s_waitcnt lgkmcnt(0)" ::: "memory");
        __builtin_amdgcn_sched_barrier(0);
        __builtin_amdgcn_s_barrier();
        __builtin_amdgcn_sched_barrier(0);
        if (kt + 2 < KT) stageTo(kt + 2, cur);
    }

#pragma unroll
    for (int mi = 0; mi < 4; ++mi)
#pragma unroll
        for (int nj = 0; nj < NJ; ++nj)
#pragma unroll
            for (int r = 0; r < 4; ++r) {
                long row = m0 + wm * 64 + mi * 16 + hi * 4 + r;
                long col = n0 + wn * (BN / 2) + nj * 16 + x;
                float v = acc[mi][nj][r];
                if constexpr (GU) {
                    float u = acc2[mi][nj][r];
                    float he = v / (1.f + __expf(-v)) * u;
                    p.outBF[row * p.ldc + col] = __float2bfloat16(he);
                } else {
                    if constexpr (SPLIT) v = fmaf(acc2[mi][nj][r], LO_INV, v);
                    switch (p.epi) {
                    case 0: p.outF[row * p.ldc + col] = v + p.bias[col]; break;
                    case 2: {
                        float o = v + p.resid[row * p.ldc + col];
                        p.outF[row * p.ldc + col] = o;
                        p.outF2[row * p.ldc + col] = o;
                    } break;
                    case 5: // plain store to per-slot scratch, weight folded
                        p.outF[row * p.ldc + col] = v * p.bw[row];
                        break;
                    }
                }
            }
}

// combine: out[tok] += scat[slot0(tok)] + scat[slot1(tok)]  (coalesced f32x4)
__global__ __launch_bounds__(256) void combine_k(const float *__restrict__ scat,
        const int *__restrict__ tok_slot, float *__restrict__ out) {
    const long tok = blockIdx.x;
    const int c = threadIdx.x * 4;
    const long s0 = tok_slot[tok * 2], s1 = tok_slot[tok * 2 + 1];
    f32x4 a = *(const f32x4 *)(scat + s0 * Dc + c);
    f32x4 b = *(const f32x4 *)(scat + s1 * Dc + c);
    f32x4 o = *(const f32x4 *)(out + tok * Dc + c);
#pragma unroll
    for (int j = 0; j < 4; ++j) o[j] += a[j] + b[j];
    *(f32x4 *)(out + tok * Dc + c) = o;
}

// ----------------------------------------------------- flash attention ----
// 4-wave blocks, 64 q-rows (16/wave), diagonal-paired: block (pairI, bh)
// processes 64-row q-tiles pairI and 31-pairI sequentially -> uniform
// (2p+2)+(2(31-p)+2) = 66 kv-tiles per block. K/V staged ONCE per kv-tile
// for all 64 q-rows (wave roles: K-hi/K-lo/V-hi/V-lo, 4 gll16 each),
// depth-2 counted-vmcnt pipeline. Swapped QK^T, in-register softmax,
// defer-max (THR=8). Waves 0,1 skip their fully-masked last tile (myNT).
__global__ __launch_bounds__(256, 4) void attn_k(
    const _Float16 *__restrict__ qh, const _Float16 *__restrict__ ql,
    const _Float16 *__restrict__ kh, const _Float16 *__restrict__ kl,
    const _Float16 *__restrict__ vTh, const _Float16 *__restrict__ vTl,
    _Float16 *__restrict__ ctxh, _Float16 *__restrict__ ctxl) {
    __shared__ __align__(16) _Float16 kbuf[2][2][32 * 64]; // [dbuf][hi/lo][kv][d]
    __shared__ __align__(16) _Float16 vbuf[2][2][64 * 32]; // [dbuf][hi/lo][d][kv]
    const int tid = threadIdx.x, lane = tid & 63, wid = tid >> 6;
    const int x = lane & 15, hi = lane >> 4;
    const int pairI = blockIdx.x;        // [0,16)
    const int bh = blockIdx.y;
    const int b = bh >> 4, h = bh & 15, kvh = h >> 2;
    const long kRow0 = (long)b * Sc * 256;
    const long vRow0 = (long)(b * 4 + kvh) * 64 * (long)Sc;

    auto stage = [&](int kt, int bufI) {
        if (wid < 2) {           // K: [kv32][d64] CK=8, swizzle c^=(kv&7)
            const _Float16 *src = (wid == 1) ? kl : kh;
#pragma unroll
            for (int i = 0; i < 4; ++i) {
                int kv = 8 * i + (lane >> 3);
                int cd = (lane & 7) ^ (kv & 7);
                const _Float16 *g = src + kRow0 + ((long)kt * 32 + kv) * 256 + kvh * 64 + cd * 8;
                gll16(g, &kbuf[bufI][wid][i * 512]);
            }
        } else {                 // V^T: [d64][kv32] CK=4, swizzle c^=((d>>1)&3)
            const _Float16 *src = (wid == 3) ? vTl : vTh;
#pragma unroll
            for (int i = 0; i < 4; ++i) {
                int d = 16 * i + (lane >> 2);
                int ckv = (lane & 3) ^ ((d >> 1) & 3);
                const _Float16 *g = src + vRow0 + (long)d * Sc + (long)kt * 32 + ckv * 8;
                gll16(g, &vbuf[bufI][wid - 2][i * 512]);
            }
        }
    };

    for (int seg = 0; seg < 2; ++seg) {
        const int qt = seg ? (31 - pairI) : pairI;   // 64-row q-tile index
        const int q0 = qt * 64;
        const long qtokW = (long)b * Sc + q0 + wid * 16;  // wave's 16 q-rows

        // Q B-frags for this segment
        f16x8 qfh[2], qfl[2];
#pragma unroll
        for (int ks = 0; ks < 2; ++ks) {
            long off = (qtokW + x) * (long)Dc + h * 64 + ks * 32 + hi * 8;
            qfh[ks] = *(const f16x8 *)(qh + off);
            qfl[ks] = *(const f16x8 *)(ql + off);
        }
        asm volatile("s_waitcnt vmcnt(0)" ::: "memory"); // retire Q loads pre-pipeline
        __builtin_amdgcn_sched_barrier(0);

        f32x4 o1[4], o2[4];
        float mrow = -3.0e38f, lrow = 0.f;
#pragma unroll
        for (int dj = 0; dj < 4; ++dj) {
            o1[dj] = (f32x4){0.f, 0.f, 0.f, 0.f};
            o2[dj] = (f32x4){0.f, 0.f, 0.f, 0.f};
        }

        const int NT = 2 * qt + 2;
        const int myNT = NT - (wid < 2 ? 1 : 0); // waves 0,1: last tile fully masked

        stage(0, 0);
        stage(1, 1);             // NT >= 2 always

        for (int kt = 0; kt < NT; ++kt) {
            if (kt + 1 < NT) asm volatile("s_waitcnt vmcnt(4)" ::: "memory");
            else asm volatile("s_waitcnt vmcnt(0)" ::: "memory");
            __builtin_amdgcn_sched_barrier(0);
            __builtin_amdgcn_s_barrier();
            __builtin_amdgcn_sched_barrier(0);
            const int cur = kt & 1;

            if (kt < myNT) {
                // --- QK^T (A=K, B=Q) -> S[kv][q] ---
                f32x4 s1[2], s2[2]; // [kvsub]
#pragma unroll
                for (int kvs = 0; kvs < 2; ++kvs) {
                    s1[kvs] = (f32x4){0.f, 0.f, 0.f, 0.f};
                    s2[kvs] = (f32x4){0.f, 0.f, 0.f, 0.f};
                }
                __builtin_amdgcn_s_setprio(1);
#pragma unroll
                for (int ks = 0; ks < 2; ++ks)
#pragma unroll
                    for (int kvs = 0; kvs < 2; ++kvs) {
                        int row = kvs * 16 + x;
                        int addr = row * 64 + (((ks * 4 + hi) ^ (row & 7)) << 3);
                        f16x8 kfh = *(const f16x8 *)&kbuf[cur][0][addr];
                        f16x8 kfl = *(const f16x8 *)&kbuf[cur][1][addr];
                        s1[kvs] = mfma16(kfh, qfh[ks], s1[kvs]);
                        s2[kvs] = mfma16(kfl, qfh[ks], s2[kvs]);
                        s2[kvs] = mfma16(kfh, qfl[ks], s2[kvs]);
                    }
                __builtin_amdgcn_s_setprio(0);

                const bool diag = (kt == myNT - 1);
                const int qpos = q0 + wid * 16 + x;
                float sv[2][4];
#pragma unroll
                for (int kvs = 0; kvs < 2; ++kvs)
#pragma unroll
                    for (int r = 0; r < 4; ++r) {
                        float v = fmaf(s2[kvs][r], LO_INV, s1[kvs][r]) * 0.125f;
                        if (diag) {
                            int kvpos = kt * 32 + kvs * 16 + 4 * hi + r;
                            if (kvpos > qpos) v = -3.0e38f;
                        }
                        sv[kvs][r] = v;
                    }
                float mx = sv[0][0];
#pragma unroll
                for (int kvs = 0; kvs < 2; ++kvs)
#pragma unroll
                    for (int r = 0; r < 4; ++r) mx = fmaxf(mx, sv[kvs][r]);
                mx = fmaxf(mx, __shfl_xor(mx, 16));
                mx = fmaxf(mx, __shfl_xor(mx, 32));
                // defer-max: rescale only when some row grew by > 8
                if (!__all(mx - mrow <= 8.0f)) {
                    float mnew = fmaxf(mrow, mx);
                    float scl = __expf(mrow - mnew);
                    mrow = mnew;
                    lrow *= scl;
                    float sclr[4];
#pragma unroll
                    for (int r = 0; r < 4; ++r) sclr[r] = __shfl(scl, 4 * hi + r);
#pragma unroll
                    for (int dj = 0; dj < 4; ++dj)
#pragma unroll
                        for (int r = 0; r < 4; ++r) {
                            o1[dj][r] *= sclr[r];
                            o2[dj][r] *= sclr[r];
                        }
                }
                float pv[2][4];
                float ls = 0.f;
#pragma unroll
                for (int kvs = 0; kvs < 2; ++kvs)
#pragma unroll
                    for (int r = 0; r < 4; ++r) {
                        pv[kvs][r] = __expf(sv[kvs][r] - mrow);
                        ls += pv[kvs][r];
                    }
                ls += __shfl_xor(ls, 16);
                ls += __shfl_xor(ls, 32);
                lrow += ls;
                // pack P (hi/lo split) and shuffle into PV A-frag layout
                u32 Bh0[2], Bh1[2], Bl0[2], Bl1[2];
#pragma unroll
                for (int pr = 0; pr < 2; ++pr) {
                    _Float16 a0 = (_Float16)pv[0][2 * pr], a1 = (_Float16)pv[0][2 * pr + 1];
                    _Float16 b0 = (_Float16)pv[1][2 * pr], b1 = (_Float16)pv[1][2 * pr + 1];
                    Bh0[pr] = pack2(a0, a1);
                    Bh1[pr] = pack2(b0, b1);
                    _Float16 la0 = (_Float16)((pv[0][2 * pr] - (float)a0) * LO_SCALE);
                    _Float16 la1 = (_Float16)((pv[0][2 * pr + 1] - (float)a1) * LO_SCALE);
                    _Float16 lb0 = (_Float16)((pv[1][2 * pr] - (float)b0) * LO_SCALE);
                    _Float16 lb1 = (_Float16)((pv[1][2 * pr + 1] - (float)b1) * LO_SCALE);
                    Bl0[pr] = pack2(la0, la1);
                    Bl1[pr] = pack2(lb0, lb1);
                }
                const int srcLow = x + ((lane & 16) ? 32 : 0);
                const int srcHigh = srcLow + 16;
                const bool useB1 = lane >= 32;
                union { u32 u[4]; f16x8 v; } fh, fl;
#pragma unroll
                for (int pr = 0; pr < 2; ++pr) {
                    u32 t0 = (u32)__shfl((int)Bh0[pr], srcLow);
                    u32 t1 = (u32)__shfl((int)Bh1[pr], srcLow);
                    fh.u[pr] = useB1 ? t1 : t0;
                    u32 u0 = (u32)__shfl((int)Bh0[pr], srcHigh);
                    u32 u1 = (u32)__shfl((int)Bh1[pr], srcHigh);
                    fh.u[2 + pr] = useB1 ? u1 : u0;
                    u32 s0 = (u32)__shfl((int)Bl0[pr], srcLow);
                    u32 s1v = (u32)__shfl((int)Bl1[pr], srcLow);
                    fl.u[pr] = useB1 ? s1v : s0;
                    u32 w0 = (u32)__shfl((int)Bl0[pr], srcHigh);
                    u32 w1 = (u32)__shfl((int)Bl1[pr], srcHigh);
                    fl.u[2 + pr] = useB1 ? w1 : w0;
                }
                f16x8 pah = fh.v, pal = fl.v;

                // --- PV: A=P[q16][kv32], B=V^T[d][kv] ---
                __builtin_amdgcn_s_setprio(1);
#pragma unroll
                for (int dj = 0; dj < 4; ++dj) {
                    int d = dj * 16 + x;
                    int addr = d * 32 + ((hi ^ ((d >> 1) & 3)) << 3);
                    f16x8 vhf = *(const f16x8 *)&vbuf[cur][0][addr];
                    f16x8 vlf = *(const f16x8 *)&vbuf[cur][1][addr];
                    o1[dj] = mfma16(pah, vhf, o1[dj]);
                    o2[dj] = mfma16(pah, vlf, o2[dj]);
                    o2[dj] = mfma16(pal, vhf, o2[dj]);
                }
                __builtin_amdgcn_s_setprio(0);
            }

            asm volatile("s_waitcnt lgkmcnt(0)" ::: "memory");
            __builtin_amdgcn_sched_barrier(0);
            __builtin_amdgcn_s_barrier();
            __builtin_amdgcn_sched_barrier(0);
            if (kt + 2 < NT) stage(kt + 2, cur);
        }

        // epilogue: normalize + hi/lo split store
        float linv = 1.0f / lrow;
        float lr[4];
#pragma unroll
        for (int r = 0; r < 4; ++r) lr[r] = __shfl(linv, 4 * hi + r);
#pragma unroll
        for (int dj = 0; dj < 4; ++dj)
#pragma unroll
            for (int r = 0; r < 4; ++r) {
                long tok = qtokW + 4 * hi + r;
                float ov = fmaf(o2[dj][r], LO_INV, o1[dj][r]) * lr[r];
                _Float16 hv = (_Float16)ov;
                long off = tok * Dc + h * 64 + dj * 16 + x;
                ctxh[off] = hv;
                ctxl[off] = (_Float16)((ov - (float)hv) * LO_SCALE);
            }
    }
}

// ------------------------------------------------------- small kernels ----
__global__ __launch_bounds__(256) void rmsnorm_split_k(const float *__restrict__ x,
        const float *__restrict__ w, _Float16 *__restrict__ oh, _Float16 *__restrict__ ol) {
    const long row = blockIdx.x;
    const int tid = threadIdx.x, lane = tid & 63, wid = tid >> 6;
    f32x4 v = *(const f32x4 *)(x + row * Dc + tid * 4);
    float ss = v[0] * v[0] + v[1] * v[1] + v[2] * v[2] + v[3] * v[3];
#pragma unroll
    for (int off = 1; off < 64; off <<= 1) ss += __shfl_xor(ss, off);
    __shared__ float sw[4];
    if (lane == 0) sw[wid] = ss;
    __syncthreads();
    float inv = 1.0f / sqrtf((sw[0] + sw[1] + sw[2] + sw[3]) * (1.f / Dc) + 1e-6f);
#pragma unroll
    for (int j = 0; j < 4; ++j) {
        float y = v[j] * inv * w[tid * 4 + j];
        _Float16 hv = (_Float16)y;
        oh[row * Dc + tid * 4 + j] = hv;
        ol[row * Dc + tid * 4 + j] = (_Float16)((y - (float)hv) * LO_SCALE);
    }
}

__global__ __launch_bounds__(256) void rmsnorm2_k(const float *__restrict__ x,
        const float *__restrict__ w, float *__restrict__ tf, __hip_bfloat16 *__restrict__ tb) {
    const long row = blockIdx.x;
    const int tid = threadIdx.x, lane = tid & 63, wid = tid >> 6;
    f32x4 v = *(const f32x4 *)(x + row * Dc + tid * 4);
    float ss = v[0] * v[0] + v[1] * v[1] + v[2] * v[2] + v[3] * v[3];
#pragma unroll
    for (int off = 1; off < 64; off <<= 1) ss += __shfl_xor(ss, off);
    __shared__ float sw[4];
    if (lane == 0) sw[wid] = ss;
    __syncthreads();
    float inv = 1.0f / sqrtf((sw[0] + sw[1] + sw[2] + sw[3]) * (1.f / Dc) + 1e-6f);
#pragma unroll
    for (int j = 0; j < 4; ++j) {
        float y = v[j] * inv * w[tid * 4 + j];
        tf[row * Dc + tid * 4 + j] = y;
        tb[row * Dc + tid * 4 + j] = __float2bfloat16(y);
    }
}

__global__ void split_f16_k(const float *__restrict__ x, _Float16 *hi, _Float16 *lo, long n) {
    for (long i = (long)blockIdx.x * 256 + threadIdx.x; i < n; i += (long)gridDim.x * 256) {
        float v = x[i];
        _Float16 h = (_Float16)v;
        hi[i] = h;
        lo[i] = (_Float16)((v - (float)h) * LO_SCALE);
    }
}

__global__ void pack_qkvw_k(const float *__restrict__ qw, const float *__restrict__ kw,
        const float *__restrict__ vw, _Float16 *wh, _Float16 *wl) {
    const long n = (long)QKVN * Dc;
    for (long i = (long)blockIdx.x * 256 + threadIdx.x; i < n; i += (long)gridDim.x * 256) {
        long o = i >> 10;
        int d = (int)(i & 1023);
        float v;
        if (o < 1024) v = qw[o * 1024 + d];
        else if (o < 1280) v = kw[(o - 1024) * 1024 + d];
        else v = vw[(o - 1280) * 1024 + d];
        _Float16 h = (_Float16)v;
        wh[i] = h;
        wl[i] = (_Float16)((v - (float)h) * LO_SCALE);
    }
}

__global__ void pack_bias_k(const float *qb, const float *kb, const float *vb, float *out) {
    int i = blockIdx.x * 256 + threadIdx.x;
    if (i >= QKVN) return;
    out[i] = (i < 1024) ? qb[i] : (i < 1280) ? kb[i - 1024] : vb[i - 1280];
}

__global__ __launch_bounds__(256) void transpose_bf16_k(const float *__restrict__ in,
        __hip_bfloat16 *__restrict__ out, int R, int C) {
    __shared__ float tile[64 * 65];
    const long eo = (long)blockIdx.z * R * C;
    const int r0 = blockIdx.y * 64, c0 = blockIdx.x * 64;
#pragma unroll
    for (int i = 0; i < 16; ++i) {
        int idx = threadIdx.x + i * 256;
        int r = idx >> 6, c = idx & 63;
        tile[r * 65 + c] = in[eo + (long)(r0 + r) * C + (c0 + c)];
    }
    __syncthreads();
#pragma unroll
    for (int i = 0; i < 16; ++i) {
        int idx = threadIdx.x + i * 256;
        int cc = idx >> 6, rr = idx & 63;
        out[eo + (long)(c0 + cc) * R + (r0 + rr)] = __float2bfloat16(tile[rr * 65 + cc]);
    }
}

// V needs no RoPE: transpose V section of qkvf to [B*KV*64][S] with hi/lo split
__global__ __launch_bounds__(256) void vtrans_k(const float *__restrict__ qkvf,
        _Float16 *__restrict__ vTh, _Float16 *__restrict__ vTl) {
    __shared__ float tile[64][65];
    const int tok0 = blockIdx.x * 64;
    const int bk = blockIdx.y;
    const int b = bk >> 2, kvh = bk & 3;
#pragma unroll
    for (int it = 0; it < 16; ++it) {
        int idx = it * 256 + threadIdx.x;
        int r = idx >> 6, c = idx & 63;
        tile[r][c] = qkvf[((long)b * Sc + tok0 + r) * QKVN + 1280 + kvh * 64 + c];
    }
    __syncthreads();
    const int d = threadIdx.x & 63, ch = threadIdx.x >> 6;
    long orow = ((long)bk * 64 + d) * (long)Sc + tok0 + ch * 16;
    f16x8 oh[2], ol[2];
#pragma unroll
    for (int j = 0; j < 16; ++j) {
        float v = tile[ch * 16 + j][d];
        _Float16 hv = (_Float16)v;
        oh[j >> 3][j & 7] = hv;
        ol[j >> 3][j & 7] = (_Float16)((v - (float)hv) * LO_SCALE);
    }
    *(f16x8 *)(vTh + orow) = oh[0];
    *(f16x8 *)(vTh + orow + 8) = oh[1];
    *(f16x8 *)(vTl + orow) = ol[0];
    *(f16x8 *)(vTl + orow + 8) = ol[1];
}

__global__ __launch_bounds__(256) void rope_k(const float *__restrict__ qkv,
        const float *__restrict__ cosb, const float *__restrict__ sinb,
        _Float16 *qh, _Float16 *ql, _Float16 *kh2, _Float16 *kl2) {
    const long tok = blockIdx.x;
    const int s = (int)(tok % Sc);
    const float *row = qkv + tok * QKVN;
    for (int p = threadIdx.x; p < 640; p += 256) {
        int u = p >> 5, d = p & 31;
        float x1 = row[u * 64 + d], x2 = row[u * 64 + d + 32];
        float cs = cosb[(long)s * 64 + d], sn = sinb[(long)s * 64 + d];
        float o1v = x1 * cs - x2 * sn;
        float o2v = x2 * cs + x1 * sn;
        _Float16 h1 = (_Float16)o1v, h2 = (_Float16)o2v;
        _Float16 l1 = (_Float16)((o1v - (float)h1) * LO_SCALE);
        _Float16 l2 = (_Float16)((o2v - (float)h2) * LO_SCALE);
        if (u < 16) {
            long off = tok * 1024 + u * 64 + d;
            qh[off] = h1; ql[off] = l1; qh[off + 32] = h2; ql[off + 32] = l2;
        } else {
            long off = tok * 256 + (u - 16) * 64 + d;
            kh2[off] = h1; kl2[off] = l1; kh2[off + 32] = h2; kl2[off + 32] = l2;
        }
    }
}

__global__ __launch_bounds__(256) void router_p1_k(const float *__restrict__ t,
        const float *__restrict__ rw, float *probs, int *tok_e, float *tok_w, int *cnt) {
    const int tid = threadIdx.x, lane = tid & 63, wid = tid >> 6;
    const long tok = (long)blockIdx.x * 4 + wid;
    const float *row = t + tok * Dc;
    const int d0 = lane * 16;
    f32x4 xv[4];
#pragma unroll
    for (int i = 0; i < 4; ++i) xv[i] = *(const f32x4 *)(row + d0 + i * 4);
    float acc[8];
#pragma unroll
    for (int e = 0; e < 8; ++e) {
        const float *wr = rw + (long)e * Dc + d0;
        float a = 0.f;
#pragma unroll
        for (int i = 0; i < 4; ++i) {
            f32x4 wv = *(const f32x4 *)(wr + i * 4);
            a += xv[i][0] * wv[0] + xv[i][1] * wv[1] + xv[i][2] * wv[2] + xv[i][3] * wv[3];
        }
        acc[e] = a;
    }
#pragma unroll
    for (int off = 1; off < 64; off <<= 1)
#pragma unroll
        for (int e = 0; e < 8; ++e) acc[e] += __shfl_xor(acc[e], off);
    if (lane == 0) {
        float mx = acc[0];
#pragma unroll
        for (int e = 1; e < 8; ++e) mx = fmaxf(mx, acc[e]);
        float ex[8], s = 0.f;
#pragma unroll
        for (int e = 0; e < 8; ++e) { ex[e] = expf(acc[e] - mx); s += ex[e]; }
        float inv = 1.f / s;
        int i1 = -1, i2 = -1;
        float p1v = -1.f, p2v = -1.f;
#pragma unroll
        for (int e = 0; e < 8; ++e) {
            float pe = ex[e] * inv;
            probs[tok * 8 + e] = pe;
            if (pe > p1v) { i2 = i1; p2v = p1v; i1 = e; p1v = pe; }
            else if (pe > p2v) { i2 = e; p2v = pe; }
        }
        float wsum = p1v + p2v;
        tok_e[tok * 2] = i1; tok_e[tok * 2 + 1] = i2;
        tok_w[tok * 2] = p1v / wsum; tok_w[tok * 2 + 1] = p2v / wsum;
        atomicAdd(&cnt[i1], 1);
        atomicAdd(&cnt[i2], 1);
    }
}

__global__ __launch_bounds__(1024) void router_p2_k(const int *cnt, const float *probs,
        int *poff, float *aux_out) {
    __shared__ float sd[1024];
    const int tid = threadIdx.x;
    const int e = tid & 7, rs = tid >> 3;
    float s = 0.f;
    for (int r = rs; r < Tc; r += 128) s += probs[(long)r * 8 + e];
    sd[tid] = s;
    __syncthreads();
    for (int st = 64; st >= 1; st >>= 1) {
        if (rs < st) sd[tid] += sd[tid + st * 8];
        __syncthreads();
    }
    if (tid == 0) {
        float a = 0.f;
        for (int ee = 0; ee < 8; ++ee) {
            float m = sd[ee] * (1.f / Tc);
            a += m * m;
        }
        aux_out[0] = a;
        int o = 0;
        poff[0] = 0;
        for (int ee = 0; ee < 8; ++ee) { o += (cnt[ee] + 127) & ~127; poff[ee + 1] = o; }
    }
}

__global__ void router_p3_k(const int *tok_e, const float *tok_w, const int *poff,
        int *cursor, int *btok, float *bw, int *tok_slot) {
    long tok = (long)blockIdx.x * 256 + threadIdx.x;
    if (tok >= Tc) return;
#pragma unroll
    for (int j = 0; j < 2; ++j) {
        int e = tok_e[tok * 2 + j];
        int slot = atomicAdd(&cursor[e], 1);
        btok[poff[e] + slot] = (int)tok;
        bw[poff[e] + slot] = tok_w[tok * 2 + j];
        tok_slot[tok * 2 + j] = poff[e] + slot;
    }
}

__global__ void router_p4_k(const int *poff, const int *cnt, int *btok, float *bw) {
    int s = blockIdx.x * 256 + threadIdx.x;
    if (s >= poff[8]) return;
    int e = 0;
    while (s >= poff[e + 1]) ++e;
    if (s - poff[e] >= cnt[e]) { btok[s] = 0; bw[s] = 0.f; }
}

// -------------------------------------------------------------- launch ----
extern "C" void kernel_launch(void *const *d_in, const int *in_sizes, int n_in,
                              void *d_out, int out_size, void *d_ws, size_t ws_size,
                              hipStream_t stream) {
    (void)in_sizes; (void)n_in;
    const float *hidden = (const float *)d_in[0];
    const float *ln1 = (const float *)d_in[1];
    const float *ln2 = (const float *)d_in[2];
    const float *qw = (const float *)d_in[3];
    const float *qb = (const float *)d_in[4];
    const float *kw = (const float *)d_in[5];
    const float *kb = (const float *)d_in[6];
    const float *vw = (const float *)d_in[7];
    const float *vb = (const float *)d_in[8];
    const float *ow = (const float *)d_in[9];
    const float *rw = (const float *)d_in[10];
    const float *gw = (const float *)d_in[11];
    const float *uw = (const float *)d_in[12];
    const float *dwn = (const float *)d_in[13];
    const float *cosb = (const float *)d_in[14];
    const float *sinb = (const float *)d_in[15];
    float *outx = (float *)d_out;

    char *base = (char *)d_ws;
    size_t off = 0;
    auto alloc = [&](size_t bytes) -> char * {
        char *p = base + off;
        off += (bytes + 255) & ~(size_t)255;
        return p;
    };
    _Float16 *qkvwh = (_Float16 *)alloc((size_t)QKVN * Dc * 2);
    _Float16 *qkvwl = (_Float16 *)alloc((size_t)QKVN * Dc * 2);
    float *qkvb = (float *)alloc(QKVN * 4);
    _Float16 *owh = (_Float16 *)alloc((size_t)Dc * Dc * 2);
    _Float16 *owl = (_Float16 *)alloc((size_t)Dc * Dc * 2);
    __hip_bfloat16 *gateT = (__hip_bfloat16 *)alloc((size_t)Ec * Fc * Dc * 2);
    __hip_bfloat16 *upT = (__hip_bfloat16 *)alloc((size_t)Ec * Fc * Dc * 2);
    __hip_bfloat16 *downT = (__hip_bfloat16 *)alloc((size_t)Ec * Dc * Fc * 2);
    // U2..vTl span (~40 MB) is dead by down-GEMM time; scat (36 MB) aliases it
    char *U2 = alloc((size_t)Tc * Dc * 4);
    _Float16 *hh = (_Float16 *)U2;
    _Float16 *hl = hh + (size_t)Tc * Dc;
    float *tf = (float *)U2;
    char *U3 = alloc((size_t)Tc * Dc * 4);
    _Float16 *qhb = (_Float16 *)U3;
    _Float16 *qlb = qhb + (size_t)Tc * Dc;
    float *x1 = (float *)U3;
    _Float16 *khb = (_Float16 *)alloc((size_t)Tc * 256 * 2);
    _Float16 *klb = (_Float16 *)alloc((size_t)Tc * 256 * 2);
    _Float16 *vTh = (_Float16 *)alloc((size_t)Tc * 256 * 2);
    _Float16 *vTl = (_Float16 *)alloc((size_t)Tc * 256 * 2);
    float *scat = (float *)U2;   // CAP*Dc*4 = 36 MB <= U2..vTl span (~40 MB)
    _Float16 *ctxh = (_Float16 *)alloc((size_t)Tc * Dc * 2);
    _Float16 *ctxl = (_Float16 *)alloc((size_t)Tc * Dc * 2);
    __hip_bfloat16 *tbf = (__hip_bfloat16 *)alloc((size_t)Tc * Dc * 2);
    float *probs = (float *)alloc((size_t)Tc * 8 * 4);
    int *tok_e = (int *)alloc((size_t)Tc * 2 * 4);
    float *tok_w = (float *)alloc((size_t)Tc * 2 * 4);
    int *tok_slot = (int *)alloc((size_t)Tc * 2 * 4);
    int *cnt = (int *)alloc(256);
    int *cursor = cnt + 8;
    int *poff = (int *)alloc(256);
    int *btok = (int *)alloc((size_t)CAP * 4);
    float *bwgt = (float *)alloc((size_t)CAP * 4);
    size_t qkvfB = (size_t)Tc * QKVN * 4;
    size_t gbufB = (size_t)CAP * Fc * 2;
    size_t u1B = qkvfB > gbufB ? qkvfB : gbufB;
    char *U1 = alloc(u1B);
    float *qkvf = (float *)U1;
    __hip_bfloat16 *gbuf = (__hip_bfloat16 *)U1;

    if (off > ws_size) {
        hipMemsetAsync(d_out, 0, (size_t)out_size * 4, stream);
        return;
    }

    hipMemsetAsync(cnt, 0, 64, stream);
    pack_qkvw_k<<<1024, 256, 0, stream>>>(qw, kw, vw, qkvwh, qkvwl);
    pack_bias_k<<<(QKVN + 255) / 256, 256, 0, stream>>>(qb, kb, vb, qkvb);
    split_f16_k<<<1024, 256, 0, stream>>>(ow, owh, owl, (long)Dc * Dc);
    transpose_bf16_k<<<dim3(Fc / 64, Dc / 64, Ec), 256, 0, stream>>>(gw, gateT, Dc, Fc);
    transpose_bf16_k<<<dim3(Fc / 64, Dc / 64, Ec), 256, 0, stream>>>(uw, upT, Dc, Fc);
    transpose_bf16_k<<<dim3(Dc / 64, Fc / 64, Ec), 256, 0, stream>>>(dwn, downT, Fc, Dc);
    rmsnorm_split_k<<<Tc, 256, 0, stream>>>(hidden, ln1, hh, hl);

    GemmP g{};
    g.Ah = hh; g.Al = hl; g.Bh = qkvwh; g.Bl = qkvwl;
    g.lda = Dc; g.ldb = Dc; g.bExp = 0; g.K = Dc;
    g.bias = qkvb; g.outF = qkvf; g.ldc = QKVN; g.epi = 0;
    gemm_k<_Float16, true, false, false, 128><<<dim3(Tc / 128, QKVN / 128), 256, 0, stream>>>(g);

    rope_k<<<Tc, 256, 0, stream>>>(qkvf, cosb, sinb, qhb, qlb, khb, klb);
    vtrans_k<<<dim3(Sc / 64, Bc * KVc), 256, 0, stream>>>(qkvf, vTh, vTl);
    attn_k<<<dim3(16, Bc * Hc), 256, 0, stream>>>(qhb, qlb, khb, klb, vTh, vTl, ctxh, ctxl);

    GemmP go{};
    go.Ah = ctxh; go.Al = ctxl; go.Bh = owh; go.Bl = owl;
    go.lda = Dc; go.ldb = Dc; go.bExp = 0; go.K = Dc;
    go.resid = hidden; go.outF = x1; go.outF2 = outx; go.ldc = Dc; go.epi = 2;
    gemm_k<_Float16, true, false, false, 128><<<dim3(Tc / 128, Dc / 128), 256, 0, stream>>>(go);

    rmsnorm2_k<<<Tc, 256, 0, stream>>>(x1, ln2, tf, tbf);
    router_p1_k<<<Tc / 4, 256, 0, stream>>>(tf, rw, probs, tok_e, tok_w, cnt);
    router_p2_k<<<1, 1024, 0, stream>>>(cnt, probs, poff, outx + (long)Tc * Dc);
    router_p3_k<<<Tc / 256, 256, 0, stream>>>(tok_e, tok_w, poff, cursor, btok, bwgt, tok_slot);
    router_p4_k<<<CAP / 256, 256, 0, stream>>>(poff, cnt, btok, bwgt);

    // fused gate+up: he = silu(t@gate) * (t@up) -> gbuf (bf16), XCD-chunked M
    GemmP gg{};
    gg.Ah = tbf; gg.Bh = gateT; gg.Bh2 = upT;
    gg.lda = Dc; gg.ldb = Dc; gg.bExp = (long)Fc * Dc; gg.K = Dc;
    gg.poff = poff; gg.gidx = btok; gg.outBF = gbuf; gg.ldc = Fc;
    gemm_k<__hip_bfloat16, false, true, true, 128, true><<<dim3(CAP / 128, Fc / 128), 256, 0, stream>>>(gg);

    // down: BN=128, plain weighted store to per-slot scratch, XCD-chunked M
    GemmP gd{};
    gd.Ah = gbuf; gd.Bh = downT;
    gd.lda = Fc; gd.ldb = Fc; gd.bExp = (long)Dc * Fc; gd.K = Fc;
    gd.poff = poff; gd.bw = bwgt;
    gd.outF = scat; gd.ldc = Dc; gd.epi = 5;
    gemm_k<__hip_bfloat16, false, false, false, 128, true><<<dim3(CAP / 128, Dc / 128), 256, 0, stream>>>(gd);

    // combine: outx[tok] += scat[slot0] + scat[slot1]
    combine_k<<<Tc, 256, 0, stream>>>(scat, tok_slot, outx);
}

// Round 12
// 693.270 us; speedup vs baseline: 1.2144x; 1.0274x over previous
//
#include <hip/hip_runtime.h>
#include <hip/hip_bf16.h>

#define DEVI __device__ __forceinline__

typedef float f32x4 __attribute__((ext_vector_type(4)));
typedef _Float16 f16x8 __attribute__((ext_vector_type(8)));
typedef short s16x8 __attribute__((ext_vector_type(8)));
typedef unsigned int u32;

constexpr int Bc = 2, Sc = 2048, Dc = 1024, Hc = 16, KVc = 4, HDc = 64, Fc = 2816, Ec = 8;
constexpr int Tc = Bc * Sc;                 // 4096 tokens
constexpr int QKVN = Hc * HDc + 2 * KVc * HDc; // 1536
constexpr int CAP = Tc * 2 + Ec * 128;      // 9216 padded expert-token slots
constexpr float LO_SCALE = 1024.0f;
constexpr float LO_INV = 1.0f / 1024.0f;

DEVI f32x4 mfma16(f16x8 a, f16x8 b, f32x4 c) {
    return __builtin_amdgcn_mfma_f32_16x16x32_f16(a, b, c, 0, 0, 0);
}
DEVI f32x4 mfma16(s16x8 a, s16x8 b, f32x4 c) {
    return __builtin_amdgcn_mfma_f32_16x16x32_bf16(a, b, c, 0, 0, 0);
}

DEVI void gll16(const void *g, void *l) {
    __builtin_amdgcn_global_load_lds(
        (const __attribute__((address_space(1))) u32 *)g,
        (__attribute__((address_space(3))) u32 *)l, 16, 0, 0);
}

DEVI u32 pack2(_Float16 a, _Float16 b) {
    union { _Float16 h[2]; u32 u; } t;
    t.h[0] = a; t.h[1] = b;
    return t.u;
}

template <int N> DEVI void wait_vm() {
    if constexpr (N == 0) asm volatile("s_waitcnt vmcnt(0)" ::: "memory");
    else if constexpr (N == 4) asm volatile("s_waitcnt vmcnt(4)" ::: "memory");
    else if constexpr (N == 6) asm volatile("s_waitcnt vmcnt(6)" ::: "memory");
    else if constexpr (N == 8) asm volatile("s_waitcnt vmcnt(8)" ::: "memory");
}

template <typename VT> struct FragT;
template <> struct FragT<_Float16> { using type = f16x8; };
template <> struct FragT<__hip_bfloat16> { using type = s16x8; };

// ---------------------------------------------------------------- GEMM ----
// C[M,N] = A[M,K] * B^T (B stored [N,K], k-contiguous). BK=32 (CK=4 chunks).
// global_load_lds (16B) staging, double-buffered, depth-2 counted-vmcnt
// pipeline. XOR chunk-swizzle cs = c ^ ((r>>1)&3) on BOTH source and read.
// SPLIT: (hi, lo*1024) f16 pairs, cross terms in acc2, v = acc1+acc2/1024.
// GU: dual-B (gate/up), epilogue silu(g)*u -> bf16.  BN: 64 or 128.
// XSWZ: XCD-chunked M-ordering (A-panel slice stays L2-resident per XCD).
// Launch bounds REGISTER-AWARE (R10 lesson: forcing 3 waves/EU on the
// ~224-reg dual-accumulator GU spilled accumulators -> WRITE 48->213 MB, 2x).
// epi=6 (QKV+RoPE fusion): block tile -> LDS, __syncthreads, each thread
// reads its rotate-half partner (cl^32, same 64-aligned head), applies
// cos/sin, splits hi/lo f16 to q/k; V stored fp32 to vqf.
struct GemmP {
    const void *Ah, *Al;
    const void *Bh, *Bl, *Bh2;
    long lda, ldb, bExp, K;
    const int *poff, *gidx;
    const float *bias, *resid, *bw;   // epi6: resid=cos table, bw=sin table
    float *outF, *outF2;              // epi6: outF=vqf
    __hip_bfloat16 *outBF;
    _Float16 *rQh, *rQl, *rKh, *rKl;  // epi6 outputs
    long ldc;
    int epi; // 0:+bias->f32  2:+resid->f32(dual)  5:scaled scatter-store  6:rope-split
};

template <typename VT, bool SPLIT, bool GATHER, bool GU, int BN, bool XSWZ = false>
__global__ __launch_bounds__(256, SPLIT ? 3 : ((GU && BN == 128) ? 2 : 4)) void gemm_k(GemmP p) {
    constexpr int BM = 128;
    constexpr int NJ = BN / 32;
    constexpr bool HAS2 = SPLIT || GU;
    constexpr int ACH = SPLIT ? 1024 : 512;   // A-region chunks (16B)
    constexpr int BCH = BN * 4;               // chunks per B matrix
    constexpr int NB = HAS2 ? 2 : 1;
    constexpr int TOT = ACH + NB * BCH;
    constexpr int NCH = TOT / 256;            // chunks staged per thread
    constexpr int BUFVT = TOT * 8;
    constexpr int AOFF2 = 4096;               // Al (SPLIT)
    constexpr int BOFF = ACH * 8;
    constexpr int B2OFF = (ACH + BCH) * 8;
    __shared__ __align__(16) VT s[2][BUFVT];
    const int tid = threadIdx.x, lane = tid & 63;
    const int wid = tid >> 6, wm = wid >> 1, wn = wid & 1;
    const int x = lane & 15, hi = lane >> 4;
    int mb = (int)blockIdx.x;
    if constexpr (XSWZ) mb = (mb & 7) * ((int)gridDim.x >> 3) + (mb >> 3);
    long m0 = (long)mb * BM, n0 = (long)blockIdx.y * BN;
    int e = 0;
    if (p.poff) {
        int tot = p.poff[Ec];
        if (m0 >= tot) return;
        while (m0 >= p.poff[e + 1]) ++e;
    }

    const VT *gs[NCH];
    int chd[NCH];
#pragma unroll
    for (int i = 0; i < NCH; ++i) {
        int ch = tid + i * 256;
        chd[i] = ch;
        if (ch < ACH) {
            int slab = ch >> 9, local = ch & 511;
            int r = local >> 2, c = local & 3;
            int cs = c ^ ((r >> 1) & 3);
            long ar = m0 + r;
            if (GATHER) ar = p.gidx[ar];
            const VT *mat = (SPLIT && slab == 1) ? (const VT *)p.Al : (const VT *)p.Ah;
            gs[i] = mat + ar * p.lda + cs * 8;
        } else {
            int idx = ch - ACH;
            int which = idx / BCH, local = idx % BCH;
            int r = local >> 2, c = local & 3;
            int cs = c ^ ((r >> 1) & 3);
            const VT *bmat = (which == 0) ? (const VT *)p.Bh
                           : (SPLIT ? (const VT *)p.Bl : (const VT *)p.Bh2);
            gs[i] = bmat + (long)e * p.bExp + (n0 + r) * p.ldb + cs * 8;
        }
    }

    f32x4 acc[4][NJ];
    f32x4 acc2[HAS2 ? 4 : 1][HAS2 ? NJ : 1];
#pragma unroll
    for (int i = 0; i < 4; ++i)
#pragma unroll
        for (int j = 0; j < NJ; ++j) {
            acc[i][j] = (f32x4){0.f, 0.f, 0.f, 0.f};
            if constexpr (HAS2) acc2[i][j] = (f32x4){0.f, 0.f, 0.f, 0.f};
        }

    using F8 = typename FragT<VT>::type;
    const int KT = (int)(p.K / 32);
    auto stageTo = [&](int kt, int b) {
#pragma unroll
        for (int i = 0; i < NCH; ++i)
            gll16(gs[i] + (long)kt * 32, &s[b][(size_t)chd[i] * 8]);
    };

    stageTo(0, 0);
    if (KT > 1) stageTo(1, 1);

    for (int kt = 0; kt < KT; ++kt) {
        if (kt + 1 < KT) wait_vm<NCH>();
        else wait_vm<0>();
        __builtin_amdgcn_sched_barrier(0);
        __builtin_amdgcn_s_barrier();
        __builtin_amdgcn_sched_barrier(0);
        const int cur = kt & 1;

        F8 afh[4], afl[SPLIT ? 4 : 1];
#pragma unroll
        for (int mi = 0; mi < 4; ++mi) {
            int ar = wm * 64 + mi * 16 + x;
            int ad = (ar * 4 + (hi ^ ((ar >> 1) & 3))) * 8;
            afh[mi] = *(const F8 *)&s[cur][ad];
            if constexpr (SPLIT) afl[mi] = *(const F8 *)&s[cur][AOFF2 + ad];
        }
        __builtin_amdgcn_s_setprio(1);
#pragma unroll
        for (int nj = 0; nj < NJ; ++nj) {
            int br = wn * (BN / 2) + nj * 16 + x;
            int bd = (br * 4 + (hi ^ ((br >> 1) & 3))) * 8;
            F8 bfh = *(const F8 *)&s[cur][BOFF + bd];
            F8 bf2;
            if constexpr (HAS2) bf2 = *(const F8 *)&s[cur][B2OFF + bd];
#pragma unroll
            for (int mi = 0; mi < 4; ++mi) {
                acc[mi][nj] = mfma16(afh[mi], bfh, acc[mi][nj]);
                if constexpr (SPLIT) {
                    acc2[mi][nj] = mfma16(afh[mi], bf2, acc2[mi][nj]);
                    acc2[mi][nj] = mfma16(afl[mi], bfh, acc2[mi][nj]);
                }
                if constexpr (GU) acc2[mi][nj] = mfma16(afh[mi], bf2, acc2[mi][nj]);
            }
        }
        __builtin_amdgcn_s_setprio(0);

        asm volatile("s_waitcnt lgkmcnt(0)" ::: "memory");
        __builtin_amdgcn_sched_barrier(0);
        __builtin_amdgcn_s_barrier();
        __builtin_amdgcn_sched_barrier(0);
        if (kt + 2 < KT) stageTo(kt + 2, cur);
    }

    if (SPLIT && p.epi == 6) {
        // fused RoPE epilogue: combine+bias -> LDS, exchange rotate-half pair
        float *sEpi = (float *)&s[0][0];   // 128x64 f32 = 32KB (staging dead)
#pragma unroll
        for (int mi = 0; mi < 4; ++mi)
#pragma unroll
            for (int nj = 0; nj < NJ; ++nj)
#pragma unroll
                for (int r = 0; r < 4; ++r) {
                    int rl = wm * 64 + mi * 16 + hi * 4 + r;
                    int cl = wn * (BN / 2) + nj * 16 + x;
                    float v = fmaf(acc2[mi][nj][r], LO_INV, acc[mi][nj][r]) + p.bias[n0 + cl];
                    sEpi[rl * 64 + cl] = v;
                }
        __syncthreads();
        const bool isV = (n0 >= 1280);
        const bool isK = (n0 >= 1024) && !isV;
#pragma unroll
        for (int mi = 0; mi < 4; ++mi)
#pragma unroll
            for (int nj = 0; nj < NJ; ++nj)
#pragma unroll
                for (int r = 0; r < 4; ++r) {
                    int rl = wm * 64 + mi * 16 + hi * 4 + r;
                    int cl = wn * (BN / 2) + nj * 16 + x;
                    long row = m0 + rl;
                    float xv = sEpi[rl * 64 + cl];
                    if (isV) {
                        p.outF[row * 256 + (n0 - 1280) + cl] = xv;
                    } else {
                        int spos = (int)(row & (Sc - 1));
                        float xp = sEpi[rl * 64 + (cl ^ 32)];
                        float cs = p.resid[spos * 64 + cl];
                        float sn = p.bw[spos * 64 + cl];
                        float o = xv * cs + ((cl < 32) ? -xp : xp) * sn;
                        _Float16 hv = (_Float16)o;
                        _Float16 lo = (_Float16)((o - (float)hv) * LO_SCALE);
                        if (isK) {
                            long off = row * 256 + (n0 - 1024) + cl;
                            p.rKh[off] = hv; p.rKl[off] = lo;
                        } else {
                            long off = row * 1024 + n0 + cl;
                            p.rQh[off] = hv; p.rQl[off] = lo;
                        }
                    }
                }
        return;
    }

#pragma unroll
    for (int mi = 0; mi < 4; ++mi)
#pragma unroll
        for (int nj = 0; nj < NJ; ++nj)
#pragma unroll
            for (int r = 0; r < 4; ++r) {
                long row = m0 + wm * 64 + mi * 16 + hi * 4 + r;
                long col = n0 + wn * (BN / 2) + nj * 16 + x;
                float v = acc[mi][nj][r];
                if constexpr (GU) {
                    float u = acc2[mi][nj][r];
                    float he = v / (1.f + __expf(-v)) * u;
                    p.outBF[row * p.ldc + col] = __float2bfloat16(he);
                } else {
                    if constexpr (SPLIT) v = fmaf(acc2[mi][nj][r], LO_INV, v);
                    switch (p.epi) {
                    case 0: p.outF[row * p.ldc + col] = v + p.bias[col]; break;
                    case 2: {
                        float o = v + p.resid[row * p.ldc + col];
                        p.outF[row * p.ldc + col] = o;
                        p.outF2[row * p.ldc + col] = o;
                    } break;
                    case 5: // plain store to per-slot scratch, weight folded
                        p.outF[row * p.ldc + col] = v * p.bw[row];
                        break;
                    }
                }
            }
}

// combine: out[tok] += scat[slot0(tok)] + scat[slot1(tok)]  (coalesced f32x4)
__global__ __launch_bounds__(256) void combine_k(const float *__restrict__ scat,
        const int *__restrict__ tok_slot, float *__restrict__ out) {
    const long tok = blockIdx.x;
    const int c = threadIdx.x * 4;
    const long s0 = tok_slot[tok * 2], s1 = tok_slot[tok * 2 + 1];
    f32x4 a = *(const f32x4 *)(scat + s0 * Dc + c);
    f32x4 b = *(const f32x4 *)(scat + s1 * Dc + c);
    f32x4 o = *(const f32x4 *)(out + tok * Dc + c);
#pragma unroll
    for (int j = 0; j < 4; ++j) o[j] += a[j] + b[j];
    *(f32x4 *)(out + tok * Dc + c) = o;
}

// ----------------------------------------------------- flash attention ----
// Diagonal-paired blocks: block (pairI, bh) processes q-tiles pairI and
// 63-pairI sequentially -> uniform 65 kv-tiles per block (no straggler tail).
// Per segment: 2 waves x 16 q-rows, swapped QK^T (mfma(K,Q)), in-register
// softmax (2 shfl_xor), P to PV A-frag via packed shuffles, K/V staged via
// global_load_lds into swizzled LDS, depth-2 counted-vmcnt pipeline,
// defer-max (THR=8). Outputs ctx hi/lo f16.  (R9 config: independent 2-wave
// blocks beat lockstep 4-wave blocks - cross-block phase mixing, m114.)
__global__ __launch_bounds__(128, 2) void attn_k(
    const _Float16 *__restrict__ qh, const _Float16 *__restrict__ ql,
    const _Float16 *__restrict__ kh, const _Float16 *__restrict__ kl,
    const _Float16 *__restrict__ vTh, const _Float16 *__restrict__ vTl,
    _Float16 *__restrict__ ctxh, _Float16 *__restrict__ ctxl) {
    __shared__ __align__(16) _Float16 kbuf[2][2][32 * 64]; // [dbuf][hi/lo][kv][d]
    __shared__ __align__(16) _Float16 vbuf[2][2][64 * 32]; // [dbuf][hi/lo][d][kv]
    const int tid = threadIdx.x, lane = tid & 63, wid = tid >> 6;
    const int x = lane & 15, hi = lane >> 4;
    const int pairI = blockIdx.x;
    const int bh = blockIdx.y;
    const int b = bh >> 4, h = bh & 15, kvh = h >> 2;
    const long kRow0 = (long)b * Sc * 256;
    const long vRow0 = (long)(b * 4 + kvh) * 64 * (long)Sc;

    auto stage = [&](int kt, int bufI) {
        if (wid == 0) {          // K: [kv32][d64] CK=8, swizzle c^=(kv&7)
#pragma unroll
            for (int ss = 0; ss < 2; ++ss) {
                const _Float16 *src = ss ? kl : kh;
#pragma unroll
                for (int i = 0; i < 4; ++i) {
                    int kv = 8 * i + (lane >> 3);
                    int cd = (lane & 7) ^ (kv & 7);
                    const _Float16 *g = src + kRow0 + ((long)kt * 32 + kv) * 256 + kvh * 64 + cd * 8;
                    gll16(g, &kbuf[bufI][ss][i * 512]);
                }
            }
        } else {                 // V^T: [d64][kv32] CK=4, swizzle c^=((d>>1)&3)
#pragma unroll
            for (int ss = 0; ss < 2; ++ss) {
                const _Float16 *src = ss ? vTl : vTh;
#pragma unroll
                for (int i = 0; i < 4; ++i) {
                    int d = 16 * i + (lane >> 2);
                    int ckv = (lane & 3) ^ ((d >> 1) & 3);
                    const _Float16 *g = src + vRow0 + (long)d * Sc + (long)kt * 32 + ckv * 8;
                    gll16(g, &vbuf[bufI][ss][i * 512]);
                }
            }
        }
    };

    for (int seg = 0; seg < 2; ++seg) {
        const int qt = seg ? (63 - pairI) : pairI;
        const int q0 = qt * 32;
        const long qtokW = (long)b * Sc + q0 + wid * 16;    // wave's 16 q-rows

        f16x8 qfh[2], qfl[2];
#pragma unroll
        for (int ks = 0; ks < 2; ++ks) {
            long off = (qtokW + x) * (long)Dc + h * 64 + ks * 32 + hi * 8;
            qfh[ks] = *(const f16x8 *)(qh + off);
            qfl[ks] = *(const f16x8 *)(ql + off);
        }
        asm volatile("s_waitcnt vmcnt(0)" ::: "memory");
        __builtin_amdgcn_sched_barrier(0);

        f32x4 o1[4], o2[4];
        float mrow = -3.0e38f, lrow = 0.f;
#pragma unroll
        for (int dj = 0; dj < 4; ++dj) {
            o1[dj] = (f32x4){0.f, 0.f, 0.f, 0.f};
            o2[dj] = (f32x4){0.f, 0.f, 0.f, 0.f};
        }

        const int NT = qt + 1;

        stage(0, 0);
        stage(1, 1);

        for (int kt = 0; kt < NT; ++kt) {
            if (kt + 1 < NT) asm volatile("s_waitcnt vmcnt(8)" ::: "memory");
            else asm volatile("s_waitcnt vmcnt(0)" ::: "memory");
            __builtin_amdgcn_sched_barrier(0);
            __builtin_amdgcn_s_barrier();
            __builtin_amdgcn_sched_barrier(0);
            const int cur = kt & 1;

            f32x4 s1[2], s2[2];
#pragma unroll
            for (int kvs = 0; kvs < 2; ++kvs) {
                s1[kvs] = (f32x4){0.f, 0.f, 0.f, 0.f};
                s2[kvs] = (f32x4){0.f, 0.f, 0.f, 0.f};
            }
            __builtin_amdgcn_s_setprio(1);
#pragma unroll
            for (int ks = 0; ks < 2; ++ks)
#pragma unroll
                for (int kvs = 0; kvs < 2; ++kvs) {
                    int row = kvs * 16 + x;
                    int addr = row * 64 + (((ks * 4 + hi) ^ (row & 7)) << 3);
                    f16x8 kfh = *(const f16x8 *)&kbuf[cur][0][addr];
                    f16x8 kfl = *(const f16x8 *)&kbuf[cur][1][addr];
                    s1[kvs] = mfma16(kfh, qfh[ks], s1[kvs]);
                    s2[kvs] = mfma16(kfl, qfh[ks], s2[kvs]);
                    s2[kvs] = mfma16(kfh, qfl[ks], s2[kvs]);
                }
            __builtin_amdgcn_s_setprio(0);

            const bool diag = (kt == NT - 1);
            const int qpos = q0 + wid * 16 + x;
            float sv[2][4];
#pragma unroll
            for (int kvs = 0; kvs < 2; ++kvs)
#pragma unroll
                for (int r = 0; r < 4; ++r) {
                    float v = fmaf(s2[kvs][r], LO_INV, s1[kvs][r]) * 0.125f;
                    if (diag) {
                        int kvpos = kt * 32 + kvs * 16 + 4 * hi + r;
                        if (kvpos > qpos) v = -3.0e38f;
                    }
                    sv[kvs][r] = v;
                }
            float mx = sv[0][0];
#pragma unroll
            for (int kvs = 0; kvs < 2; ++kvs)
#pragma unroll
                for (int r = 0; r < 4; ++r) mx = fmaxf(mx, sv[kvs][r]);
            mx = fmaxf(mx, __shfl_xor(mx, 16));
            mx = fmaxf(mx, __shfl_xor(mx, 32));
            if (!__all(mx - mrow <= 8.0f)) {
                float mnew = fmaxf(mrow, mx);
                float scl = __expf(mrow - mnew);
                mrow = mnew;
                lrow *= scl;
                float sclr[4];
#pragma unroll
                for (int r = 0; r < 4; ++r) sclr[r] = __shfl(scl, 4 * hi + r);
#pragma unroll
                for (int dj = 0; dj < 4; ++dj)
#pragma unroll
                    for (int r = 0; r < 4; ++r) {
                        o1[dj][r] *= sclr[r];
                        o2[dj][r] *= sclr[r];
                    }
            }
            float pv[2][4];
            float ls = 0.f;
#pragma unroll
            for (int kvs = 0; kvs < 2; ++kvs)
#pragma unroll
                for (int r = 0; r < 4; ++r) {
                    pv[kvs][r] = __expf(sv[kvs][r] - mrow);
                    ls += pv[kvs][r];
                }
            ls += __shfl_xor(ls, 16);
            ls += __shfl_xor(ls, 32);
            lrow += ls;
            u32 Bh0[2], Bh1[2], Bl0[2], Bl1[2];
#pragma unroll
            for (int pr = 0; pr < 2; ++pr) {
                _Float16 a0 = (_Float16)pv[0][2 * pr], a1 = (_Float16)pv[0][2 * pr + 1];
                _Float16 b0 = (_Float16)pv[1][2 * pr], b1 = (_Float16)pv[1][2 * pr + 1];
                Bh0[pr] = pack2(a0, a1);
                Bh1[pr] = pack2(b0, b1);
                _Float16 la0 = (_Float16)((pv[0][2 * pr] - (float)a0) * LO_SCALE);
                _Float16 la1 = (_Float16)((pv[0][2 * pr + 1] - (float)a1) * LO_SCALE);
                _Float16 lb0 = (_Float16)((pv[1][2 * pr] - (float)b0) * LO_SCALE);
                _Float16 lb1 = (_Float16)((pv[1][2 * pr + 1] - (float)b1) * LO_SCALE);
                Bl0[pr] = pack2(la0, la1);
                Bl1[pr] = pack2(lb0, lb1);
            }
            const int srcLow = x + ((lane & 16) ? 32 : 0);
            const int srcHigh = srcLow + 16;
            const bool useB1 = lane >= 32;
            union { u32 u[4]; f16x8 v; } fh, fl;
#pragma unroll
            for (int pr = 0; pr < 2; ++pr) {
                u32 t0 = (u32)__shfl((int)Bh0[pr], srcLow);
                u32 t1 = (u32)__shfl((int)Bh1[pr], srcLow);
                fh.u[pr] = useB1 ? t1 : t0;
                u32 u0 = (u32)__shfl((int)Bh0[pr], srcHigh);
                u32 u1 = (u32)__shfl((int)Bh1[pr], srcHigh);
                fh.u[2 + pr] = useB1 ? u1 : u0;
                u32 s0 = (u32)__shfl((int)Bl0[pr], srcLow);
                u32 s1v = (u32)__shfl((int)Bl1[pr], srcLow);
                fl.u[pr] = useB1 ? s1v : s0;
                u32 w0 = (u32)__shfl((int)Bl0[pr], srcHigh);
                u32 w1 = (u32)__shfl((int)Bl1[pr], srcHigh);
                fl.u[2 + pr] = useB1 ? w1 : w0;
            }
            f16x8 pah = fh.v, pal = fl.v;

            __builtin_amdgcn_s_setprio(1);
#pragma unroll
            for (int dj = 0; dj < 4; ++dj) {
                int d = dj * 16 + x;
                int addr = d * 32 + ((hi ^ ((d >> 1) & 3)) << 3);
                f16x8 vhf = *(const f16x8 *)&vbuf[cur][0][addr];
                f16x8 vlf = *(const f16x8 *)&vbuf[cur][1][addr];
                o1[dj] = mfma16(pah, vhf, o1[dj]);
                o2[dj] = mfma16(pah, vlf, o2[dj]);
                o2[dj] = mfma16(pal, vhf, o2[dj]);
            }
            __builtin_amdgcn_s_setprio(0);

            asm volatile("s_waitcnt lgkmcnt(0)" ::: "memory");
            __builtin_amdgcn_sched_barrier(0);
            __builtin_amdgcn_s_barrier();
            __builtin_amdgcn_sched_barrier(0);
            if (kt + 2 < NT) stage(kt + 2, cur);
        }

        float linv = 1.0f / lrow;
        float lr[4];
#pragma unroll
        for (int r = 0; r < 4; ++r) lr[r] = __shfl(linv, 4 * hi + r);
#pragma unroll
        for (int dj = 0; dj < 4; ++dj)
#pragma unroll
            for (int r = 0; r < 4; ++r) {
                long tok = qtokW + 4 * hi + r;
                float ov = fmaf(o2[dj][r], LO_INV, o1[dj][r]) * lr[r];
                _Float16 hv = (_Float16)ov;
                long off = tok * Dc + h * 64 + dj * 16 + x;
                ctxh[off] = hv;
                ctxl[off] = (_Float16)((ov - (float)hv) * LO_SCALE);
            }
    }
}

// ------------------------------------------------------- small kernels ----
__global__ __launch_bounds__(256) void rmsnorm_split_k(const float *__restrict__ x,
        const float *__restrict__ w, _Float16 *__restrict__ oh, _Float16 *__restrict__ ol) {
    const long row = blockIdx.x;
    const int tid = threadIdx.x, lane = tid & 63, wid = tid >> 6;
    f32x4 v = *(const f32x4 *)(x + row * Dc + tid * 4);
    float ss = v[0] * v[0] + v[1] * v[1] + v[2] * v[2] + v[3] * v[3];
#pragma unroll
    for (int off = 1; off < 64; off <<= 1) ss += __shfl_xor(ss, off);
    __shared__ float sw[4];
    if (lane == 0) sw[wid] = ss;
    __syncthreads();
    float inv = 1.0f / sqrtf((sw[0] + sw[1] + sw[2] + sw[3]) * (1.f / Dc) + 1e-6f);
#pragma unroll
    for (int j = 0; j < 4; ++j) {
        float y = v[j] * inv * w[tid * 4 + j];
        _Float16 hv = (_Float16)y;
        oh[row * Dc + tid * 4 + j] = hv;
        ol[row * Dc + tid * 4 + j] = (_Float16)((y - (float)hv) * LO_SCALE);
    }
}

__global__ __launch_bounds__(256) void rmsnorm2_k(const float *__restrict__ x,
        const float *__restrict__ w, float *__restrict__ tf, __hip_bfloat16 *__restrict__ tb) {
    const long row = blockIdx.x;
    const int tid = threadIdx.x, lane = tid & 63, wid = tid >> 6;
    f32x4 v = *(const f32x4 *)(x + row * Dc + tid * 4);
    float ss = v[0] * v[0] + v[1] * v[1] + v[2] * v[2] + v[3] * v[3];
#pragma unroll
    for (int off = 1; off < 64; off <<= 1) ss += __shfl_xor(ss, off);
    __shared__ float sw[4];
    if (lane == 0) sw[wid] = ss;
    __syncthreads();
    float inv = 1.0f / sqrtf((sw[0] + sw[1] + sw[2] + sw[3]) * (1.f / Dc) + 1e-6f);
#pragma unroll
    for (int j = 0; j < 4; ++j) {
        float y = v[j] * inv * w[tid * 4 + j];
        tf[row * Dc + tid * 4 + j] = y;
        tb[row * Dc + tid * 4 + j] = __float2bfloat16(y);
    }
}

__global__ void split_f16_k(const float *__restrict__ x, _Float16 *hi, _Float16 *lo, long n) {
    for (long i = (long)blockIdx.x * 256 + threadIdx.x; i < n; i += (long)gridDim.x * 256) {
        float v = x[i];
        _Float16 h = (_Float16)v;
        hi[i] = h;
        lo[i] = (_Float16)((v - (float)h) * LO_SCALE);
    }
}

__global__ void pack_qkvw_k(const float *__restrict__ qw, const float *__restrict__ kw,
        const float *__restrict__ vw, _Float16 *wh, _Float16 *wl) {
    const long n = (long)QKVN * Dc;
    for (long i = (long)blockIdx.x * 256 + threadIdx.x; i < n; i += (long)gridDim.x * 256) {
        long o = i >> 10;
        int d = (int)(i & 1023);
        float v;
        if (o < 1024) v = qw[o * 1024 + d];
        else if (o < 1280) v = kw[(o - 1024) * 1024 + d];
        else v = vw[(o - 1280) * 1024 + d];
        _Float16 h = (_Float16)v;
        wh[i] = h;
        wl[i] = (_Float16)((v - (float)h) * LO_SCALE);
    }
}

__global__ void pack_bias_k(const float *qb, const float *kb, const float *vb, float *out) {
    int i = blockIdx.x * 256 + threadIdx.x;
    if (i >= QKVN) return;
    out[i] = (i < 1024) ? qb[i] : (i < 1280) ? kb[i - 1024] : vb[i - 1280];
}

__global__ __launch_bounds__(256) void transpose_bf16_k(const float *__restrict__ in,
        __hip_bfloat16 *__restrict__ out, int R, int C) {
    __shared__ float tile[64 * 65];
    const long eo = (long)blockIdx.z * R * C;
    const int r0 = blockIdx.y * 64, c0 = blockIdx.x * 64;
#pragma unroll
    for (int i = 0; i < 16; ++i) {
        int idx = threadIdx.x + i * 256;
        int r = idx >> 6, c = idx & 63;
        tile[r * 65 + c] = in[eo + (long)(r0 + r) * C + (c0 + c)];
    }
    __syncthreads();
#pragma unroll
    for (int i = 0; i < 16; ++i) {
        int idx = threadIdx.x + i * 256;
        int cc = idx >> 6, rr = idx & 63;
        out[eo + (long)(c0 + cc) * R + (r0 + rr)] = __float2bfloat16(tile[rr * 65 + cc]);
    }
}

// transpose V (from vqf [tok][256], fp32) to [B*KV*64][S] with hi/lo split
__global__ __launch_bounds__(256) void vtrans_k(const float *__restrict__ vqf,
        _Float16 *__restrict__ vTh, _Float16 *__restrict__ vTl) {
    __shared__ float tile[64][65];
    const int tok0 = blockIdx.x * 64;
    const int bk = blockIdx.y;
    const int b = bk >> 2, kvh = bk & 3;
#pragma unroll
    for (int it = 0; it < 16; ++it) {
        int idx = it * 256 + threadIdx.x;
        int r = idx >> 6, c = idx & 63;
        tile[r][c] = vqf[((long)b * Sc + tok0 + r) * 256 + kvh * 64 + c];
    }
    __syncthreads();
    const int d = threadIdx.x & 63, ch = threadIdx.x >> 6;
    long orow = ((long)bk * 64 + d) * (long)Sc + tok0 + ch * 16;
    f16x8 oh[2], ol[2];
#pragma unroll
    for (int j = 0; j < 16; ++j) {
        float v = tile[ch * 16 + j][d];
        _Float16 hv = (_Float16)v;
        oh[j >> 3][j & 7] = hv;
        ol[j >> 3][j & 7] = (_Float16)((v - (float)hv) * LO_SCALE);
    }
    *(f16x8 *)(vTh + orow) = oh[0];
    *(f16x8 *)(vTh + orow + 8) = oh[1];
    *(f16x8 *)(vTl + orow) = ol[0];
    *(f16x8 *)(vTl + orow + 8) = ol[1];
}

__global__ __launch_bounds__(256) void router_p1_k(const float *__restrict__ t,
        const float *__restrict__ rw, float *probs, int *tok_e, float *tok_w, int *cnt) {
    const int tid = threadIdx.x, lane = tid & 63, wid = tid >> 6;
    const long tok = (long)blockIdx.x * 4 + wid;
    const float *row = t + tok * Dc;
    const int d0 = lane * 16;
    f32x4 xv[4];
#pragma unroll
    for (int i = 0; i < 4; ++i) xv[i] = *(const f32x4 *)(row + d0 + i * 4);
    float acc[8];
#pragma unroll
    for (int e = 0; e < 8; ++e) {
        const float *wr = rw + (long)e * Dc + d0;
        float a = 0.f;
#pragma unroll
        for (int i = 0; i < 4; ++i) {
            f32x4 wv = *(const f32x4 *)(wr + i * 4);
            a += xv[i][0] * wv[0] + xv[i][1] * wv[1] + xv[i][2] * wv[2] + xv[i][3] * wv[3];
        }
        acc[e] = a;
    }
#pragma unroll
    for (int off = 1; off < 64; off <<= 1)
#pragma unroll
        for (int e = 0; e < 8; ++e) acc[e] += __shfl_xor(acc[e], off);
    if (lane == 0) {
        float mx = acc[0];
#pragma unroll
        for (int e = 1; e < 8; ++e) mx = fmaxf(mx, acc[e]);
        float ex[8], s = 0.f;
#pragma unroll
        for (int e = 0; e < 8; ++e) { ex[e] = expf(acc[e] - mx); s += ex[e]; }
        float inv = 1.f / s;
        int i1 = -1, i2 = -1;
        float p1v = -1.f, p2v = -1.f;
#pragma unroll
        for (int e = 0; e < 8; ++e) {
            float pe = ex[e] * inv;
            probs[tok * 8 + e] = pe;
            if (pe > p1v) { i2 = i1; p2v = p1v; i1 = e; p1v = pe; }
            else if (pe > p2v) { i2 = e; p2v = pe; }
        }
        float wsum = p1v + p2v;
        tok_e[tok * 2] = i1; tok_e[tok * 2 + 1] = i2;
        tok_w[tok * 2] = p1v / wsum; tok_w[tok * 2 + 1] = p2v / wsum;
        atomicAdd(&cnt[i1], 1);
        atomicAdd(&cnt[i2], 1);
    }
}

__global__ __launch_bounds__(1024) void router_p2_k(const int *cnt, const float *probs,
        int *poff, float *aux_out) {
    __shared__ float sd[1024];
    const int tid = threadIdx.x;
    const int e = tid & 7, rs = tid >> 3;
    float s = 0.f;
    for (int r = rs; r < Tc; r += 128) s += probs[(long)r * 8 + e];
    sd[tid] = s;
    __syncthreads();
    for (int st = 64; st >= 1; st >>= 1) {
        if (rs < st) sd[tid] += sd[tid + st * 8];
        __syncthreads();
    }
    if (tid == 0) {
        float a = 0.f;
        for (int ee = 0; ee < 8; ++ee) {
            float m = sd[ee] * (1.f / Tc);
            a += m * m;
        }
        aux_out[0] = a;
        int o = 0;
        poff[0] = 0;
        for (int ee = 0; ee < 8; ++ee) { o += (cnt[ee] + 127) & ~127; poff[ee + 1] = o; }
    }
}

__global__ void router_p3_k(const int *tok_e, const float *tok_w, const int *poff,
        int *cursor, int *btok, float *bw, int *tok_slot) {
    long tok = (long)blockIdx.x * 256 + threadIdx.x;
    if (tok >= Tc) return;
#pragma unroll
    for (int j = 0; j < 2; ++j) {
        int e = tok_e[tok * 2 + j];
        int slot = atomicAdd(&cursor[e], 1);
        btok[poff[e] + slot] = (int)tok;
        bw[poff[e] + slot] = tok_w[tok * 2 + j];
        tok_slot[tok * 2 + j] = poff[e] + slot;
    }
}

__global__ void router_p4_k(const int *poff, const int *cnt, int *btok, float *bw) {
    int s = blockIdx.x * 256 + threadIdx.x;
    if (s >= poff[8]) return;
    int e = 0;
    while (s >= poff[e + 1]) ++e;
    if (s - poff[e] >= cnt[e]) { btok[s] = 0; bw[s] = 0.f; }
}

// -------------------------------------------------------------- launch ----
extern "C" void kernel_launch(void *const *d_in, const int *in_sizes, int n_in,
                              void *d_out, int out_size, void *d_ws, size_t ws_size,
                              hipStream_t stream) {
    (void)in_sizes; (void)n_in;
    const float *hidden = (const float *)d_in[0];
    const float *ln1 = (const float *)d_in[1];
    const float *ln2 = (const float *)d_in[2];
    const float *qw = (const float *)d_in[3];
    const float *qb = (const float *)d_in[4];
    const float *kw = (const float *)d_in[5];
    const float *kb = (const float *)d_in[6];
    const float *vw = (const float *)d_in[7];
    const float *vb = (const float *)d_in[8];
    const float *ow = (const float *)d_in[9];
    const float *rw = (const float *)d_in[10];
    const float *gw = (const float *)d_in[11];
    const float *uw = (const float *)d_in[12];
    const float *dwn = (const float *)d_in[13];
    const float *cosb = (const float *)d_in[14];
    const float *sinb = (const float *)d_in[15];
    float *outx = (float *)d_out;

    char *base = (char *)d_ws;
    size_t off = 0;
    auto alloc = [&](size_t bytes) -> char * {
        char *p = base + off;
        off += (bytes + 255) & ~(size_t)255;
        return p;
    };
    _Float16 *qkvwh = (_Float16 *)alloc((size_t)QKVN * Dc * 2);
    _Float16 *qkvwl = (_Float16 *)alloc((size_t)QKVN * Dc * 2);
    float *qkvb = (float *)alloc(QKVN * 4);
    _Float16 *owh = (_Float16 *)alloc((size_t)Dc * Dc * 2);
    _Float16 *owl = (_Float16 *)alloc((size_t)Dc * Dc * 2);
    __hip_bfloat16 *gateT = (__hip_bfloat16 *)alloc((size_t)Ec * Fc * Dc * 2);
    __hip_bfloat16 *upT = (__hip_bfloat16 *)alloc((size_t)Ec * Fc * Dc * 2);
    __hip_bfloat16 *downT = (__hip_bfloat16 *)alloc((size_t)Ec * Dc * Fc * 2);
    // U2..vTl span (~40 MB) is dead by down-GEMM time; scat (36 MB) aliases it
    char *U2 = alloc((size_t)Tc * Dc * 4);
    _Float16 *hh = (_Float16 *)U2;
    _Float16 *hl = hh + (size_t)Tc * Dc;
    float *tf = (float *)U2;
    char *U3 = alloc((size_t)Tc * Dc * 4);
    _Float16 *qhb = (_Float16 *)U3;
    _Float16 *qlb = qhb + (size_t)Tc * Dc;
    float *x1 = (float *)U3;
    _Float16 *khb = (_Float16 *)alloc((size_t)Tc * 256 * 2);
    _Float16 *klb = (_Float16 *)alloc((size_t)Tc * 256 * 2);
    _Float16 *vTh = (_Float16 *)alloc((size_t)Tc * 256 * 2);
    _Float16 *vTl = (_Float16 *)alloc((size_t)Tc * 256 * 2);
    float *scat = (float *)U2;   // CAP*Dc*4 = 36 MB <= U2..vTl span (~40 MB)
    _Float16 *ctxh = (_Float16 *)alloc((size_t)Tc * Dc * 2);
    _Float16 *ctxl = (_Float16 *)alloc((size_t)Tc * Dc * 2);
    __hip_bfloat16 *tbf = (__hip_bfloat16 *)alloc((size_t)Tc * Dc * 2);
    float *vqf = (float *)alloc((size_t)Tc * 256 * 4);
    float *probs = (float *)alloc((size_t)Tc * 8 * 4);
    int *tok_e = (int *)alloc((size_t)Tc * 2 * 4);
    float *tok_w = (float *)alloc((size_t)Tc * 2 * 4);
    int *tok_slot = (int *)alloc((size_t)Tc * 2 * 4);
    int *cnt = (int *)alloc(256);
    int *cursor = cnt + 8;
    int *poff = (int *)alloc(256);
    int *btok = (int *)alloc((size_t)CAP * 4);
    float *bwgt = (float *)alloc((size_t)CAP * 4);
    __hip_bfloat16 *gbuf = (__hip_bfloat16 *)alloc((size_t)CAP * Fc * 2);

    if (off > ws_size) {
        hipMemsetAsync(d_out, 0, (size_t)out_size * 4, stream);
        return;
    }

    hipMemsetAsync(cnt, 0, 64, stream);
    pack_qkvw_k<<<1024, 256, 0, stream>>>(qw, kw, vw, qkvwh, qkvwl);
    pack_bias_k<<<(QKVN + 255) / 256, 256, 0, stream>>>(qb, kb, vb, qkvb);
    split_f16_k<<<1024, 256, 0, stream>>>(ow, owh, owl, (long)Dc * Dc);
    transpose_bf16_k<<<dim3(Fc / 64, Dc / 64, Ec), 256, 0, stream>>>(gw, gateT, Dc, Fc);
    transpose_bf16_k<<<dim3(Fc / 64, Dc / 64, Ec), 256, 0, stream>>>(uw, upT, Dc, Fc);
    transpose_bf16_k<<<dim3(Dc / 64, Fc / 64, Ec), 256, 0, stream>>>(dwn, downT, Fc, Dc);
    rmsnorm_split_k<<<Tc, 256, 0, stream>>>(hidden, ln1, hh, hl);

    // QKV GEMM with fused RoPE epilogue (epi=6): writes q/k hi-lo f16 + vqf
    GemmP g{};
    g.Ah = hh; g.Al = hl; g.Bh = qkvwh; g.Bl = qkvwl;
    g.lda = Dc; g.ldb = Dc; g.bExp = 0; g.K = Dc;
    g.bias = qkvb; g.resid = cosb; g.bw = sinb;
    g.outF = vqf; g.rQh = qhb; g.rQl = qlb; g.rKh = khb; g.rKl = klb;
    g.ldc = QKVN; g.epi = 6;
    gemm_k<_Float16, true, false, false, 64><<<dim3(Tc / 128, QKVN / 64), 256, 0, stream>>>(g);

    vtrans_k<<<dim3(Sc / 64, Bc * KVc), 256, 0, stream>>>(vqf, vTh, vTl);
    attn_k<<<dim3(Sc / 64, Bc * Hc), 128, 0, stream>>>(qhb, qlb, khb, klb, vTh, vTl, ctxh, ctxl);

    GemmP go{};
    go.Ah = ctxh; go.Al = ctxl; go.Bh = owh; go.Bl = owl;
    go.lda = Dc; go.ldb = Dc; go.bExp = 0; go.K = Dc;
    go.resid = hidden; go.outF = x1; go.outF2 = outx; go.ldc = Dc; go.epi = 2;
    gemm_k<_Float16, true, false, false, 64><<<dim3(Tc / 128, Dc / 64), 256, 0, stream>>>(go);

    rmsnorm2_k<<<Tc, 256, 0, stream>>>(x1, ln2, tf, tbf);
    router_p1_k<<<Tc / 4, 256, 0, stream>>>(tf, rw, probs, tok_e, tok_w, cnt);
    router_p2_k<<<1, 1024, 0, stream>>>(cnt, probs, poff, outx + (long)Tc * Dc);
    router_p3_k<<<Tc / 256, 256, 0, stream>>>(tok_e, tok_w, poff, cursor, btok, bwgt, tok_slot);
    router_p4_k<<<CAP / 256, 256, 0, stream>>>(poff, cnt, btok, bwgt);

    // fused gate+up: he = silu(t@gate) * (t@up) -> gbuf (bf16), XCD-chunked M
    GemmP gg{};
    gg.Ah = tbf; gg.Bh = gateT; gg.Bh2 = upT;
    gg.lda = Dc; gg.ldb = Dc; gg.bExp = (long)Fc * Dc; gg.K = Dc;
    gg.poff = poff; gg.gidx = btok; gg.outBF = gbuf; gg.ldc = Fc;
    gemm_k<__hip_bfloat16, false, true, true, 128, true><<<dim3(CAP / 128, Fc / 128), 256, 0, stream>>>(gg);

    // down: BN=128, plain weighted store to per-slot scratch, XCD-chunked M
    GemmP gd{};
    gd.Ah = gbuf; gd.Bh = downT;
    gd.lda = Fc; gd.ldb = Fc; gd.bExp = (long)Dc * Fc; gd.K = Fc;
    gd.poff = poff; gd.bw = bwgt;
    gd.outF = scat; gd.ldc = Dc; gd.epi = 5;
    gemm_k<__hip_bfloat16, false, false, false, 128, true><<<dim3(CAP / 128, Dc / 128), 256, 0, stream>>>(gd);

    // combine: outx[tok] += scat[slot0] + scat[slot1]
    combine_k<<<Tc, 256, 0, stream>>>(scat, tok_slot, outx);
}

// Round 13
// 680.911 us; speedup vs baseline: 1.2365x; 1.0182x over previous
//
#include <hip/hip_runtime.h>
#include <hip/hip_bf16.h>

#define DEVI __device__ __forceinline__

typedef float f32x4 __attribute__((ext_vector_type(4)));
typedef _Float16 f16x8 __attribute__((ext_vector_type(8)));
typedef short s16x8 __attribute__((ext_vector_type(8)));
typedef unsigned int u32;

constexpr int Bc = 2, Sc = 2048, Dc = 1024, Hc = 16, KVc = 4, HDc = 64, Fc = 2816, Ec = 8;
constexpr int Tc = Bc * Sc;                 // 4096 tokens
constexpr int QKVN = Hc * HDc + 2 * KVc * HDc; // 1536
constexpr int CAP = Tc * 2 + Ec * 128;      // 9216 padded expert-token slots
constexpr float LO_SCALE = 1024.0f;
constexpr float LO_INV = 1.0f / 1024.0f;

DEVI f32x4 mfma16(f16x8 a, f16x8 b, f32x4 c) {
    return __builtin_amdgcn_mfma_f32_16x16x32_f16(a, b, c, 0, 0, 0);
}
DEVI f32x4 mfma16(s16x8 a, s16x8 b, f32x4 c) {
    return __builtin_amdgcn_mfma_f32_16x16x32_bf16(a, b, c, 0, 0, 0);
}

DEVI void gll16(const void *g, void *l) {
    __builtin_amdgcn_global_load_lds(
        (const __attribute__((address_space(1))) u32 *)g,
        (__attribute__((address_space(3))) u32 *)l, 16, 0, 0);
}

DEVI u32 pack2(_Float16 a, _Float16 b) {
    union { _Float16 h[2]; u32 u; } t;
    t.h[0] = a; t.h[1] = b;
    return t.u;
}

template <int N> DEVI void wait_vm() {
    if constexpr (N == 0) asm volatile("s_waitcnt vmcnt(0)" ::: "memory");
    else if constexpr (N == 4) asm volatile("s_waitcnt vmcnt(4)" ::: "memory");
    else if constexpr (N == 6) asm volatile("s_waitcnt vmcnt(6)" ::: "memory");
    else if constexpr (N == 8) asm volatile("s_waitcnt vmcnt(8)" ::: "memory");
    else if constexpr (N == 12) asm volatile("s_waitcnt vmcnt(12)" ::: "memory");
}

template <typename VT> struct FragT;
template <> struct FragT<_Float16> { using type = f16x8; };
template <> struct FragT<__hip_bfloat16> { using type = s16x8; };

// ---------------------------------------------------------------- GEMM ----
// C[M,N] = A[M,K] * B^T (B stored [N,K], k-contiguous). BK=32 (CK=4 chunks).
// global_load_lds (16B) staging, NBUF-deep buffering with counted-vmcnt
// pipeline (NBUF=3 gives loads ~2 compute phases of slack > HBM latency).
// XOR chunk-swizzle cs = c ^ ((r>>1)&3) on BOTH source and read.
// SPLIT: (hi, lo*1024) f16 pairs, cross terms in acc2, v = acc1+acc2/1024.
// GU: dual-B (gate/up), epilogue silu(g)*u -> bf16.  BN: 64 or 128.
// XSWZ: XCD-chunked M-ordering (A-panel slice stays L2-resident per XCD).
// Launch bounds REGISTER-AWARE (R10 lesson: forcing 3 waves/EU on the
// ~224-reg dual-accumulator GU spilled accumulators -> WRITE 48->213 MB, 2x).
// epi=6 (QKV+RoPE fusion): tile -> LDS, exchange rotate-half partner (cl^32),
// apply cos/sin, split hi/lo f16 to q/k; V stored fp32 to vqf.
struct GemmP {
    const void *Ah, *Al;
    const void *Bh, *Bl, *Bh2;
    long lda, ldb, bExp, K;
    const int *poff, *gidx;
    const float *bias, *resid, *bw;   // epi6: resid=cos table, bw=sin table
    float *outF, *outF2;              // epi6: outF=vqf
    __hip_bfloat16 *outBF;
    _Float16 *rQh, *rQl, *rKh, *rKl;  // epi6 outputs
    long ldc;
    int epi; // 0:+bias->f32  2:+resid->f32(dual)  5:scaled scatter-store  6:rope-split
};

template <typename VT, bool SPLIT, bool GATHER, bool GU, int BN, bool XSWZ = false, int NBUF = 2>
__global__ __launch_bounds__(256, SPLIT ? 3 : ((GU && BN == 128) ? 2 : 4)) void gemm_k(GemmP p) {
    constexpr int BM = 128;
    constexpr int NJ = BN / 32;
    constexpr bool HAS2 = SPLIT || GU;
    constexpr int ACH = SPLIT ? 1024 : 512;   // A-region chunks (16B)
    constexpr int BCH = BN * 4;               // chunks per B matrix
    constexpr int NB = HAS2 ? 2 : 1;
    constexpr int TOT = ACH + NB * BCH;
    constexpr int NCH = TOT / 256;            // chunks staged per thread
    constexpr int BUFVT = TOT * 8;
    constexpr int AOFF2 = 4096;               // Al (SPLIT)
    constexpr int BOFF = ACH * 8;
    constexpr int B2OFF = (ACH + BCH) * 8;
    __shared__ __align__(16) VT s[NBUF][BUFVT];
    const int tid = threadIdx.x, lane = tid & 63;
    const int wid = tid >> 6, wm = wid >> 1, wn = wid & 1;
    const int x = lane & 15, hi = lane >> 4;
    int mb = (int)blockIdx.x;
    if constexpr (XSWZ) mb = (mb & 7) * ((int)gridDim.x >> 3) + (mb >> 3);
    long m0 = (long)mb * BM, n0 = (long)blockIdx.y * BN;
    int e = 0;
    if (p.poff) {
        int tot = p.poff[Ec];
        if (m0 >= tot) return;
        while (m0 >= p.poff[e + 1]) ++e;
    }

    const VT *gs[NCH];
    int chd[NCH];
#pragma unroll
    for (int i = 0; i < NCH; ++i) {
        int ch = tid + i * 256;
        chd[i] = ch;
        if (ch < ACH) {
            int slab = ch >> 9, local = ch & 511;
            int r = local >> 2, c = local & 3;
            int cs = c ^ ((r >> 1) & 3);
            long ar = m0 + r;
            if (GATHER) ar = p.gidx[ar];
            const VT *mat = (SPLIT && slab == 1) ? (const VT *)p.Al : (const VT *)p.Ah;
            gs[i] = mat + ar * p.lda + cs * 8;
        } else {
            int idx = ch - ACH;
            int which = idx / BCH, local = idx % BCH;
            int r = local >> 2, c = local & 3;
            int cs = c ^ ((r >> 1) & 3);
            const VT *bmat = (which == 0) ? (const VT *)p.Bh
                           : (SPLIT ? (const VT *)p.Bl : (const VT *)p.Bh2);
            gs[i] = bmat + (long)e * p.bExp + (n0 + r) * p.ldb + cs * 8;
        }
    }

    f32x4 acc[4][NJ];
    f32x4 acc2[HAS2 ? 4 : 1][HAS2 ? NJ : 1];
#pragma unroll
    for (int i = 0; i < 4; ++i)
#pragma unroll
        for (int j = 0; j < NJ; ++j) {
            acc[i][j] = (f32x4){0.f, 0.f, 0.f, 0.f};
            if constexpr (HAS2) acc2[i][j] = (f32x4){0.f, 0.f, 0.f, 0.f};
        }

    using F8 = typename FragT<VT>::type;
    const int KT = (int)(p.K / 32);
    auto stageTo = [&](int kt, int b) {
#pragma unroll
        for (int i = 0; i < NCH; ++i)
            gll16(gs[i] + (long)kt * 32, &s[b][(size_t)chd[i] * 8]);
    };

    stageTo(0, 0);
    if (KT > 1) stageTo(1, 1 % NBUF);
    if (NBUF == 3 && KT > 2) stageTo(2, 2 % NBUF);

    int cur = 0;
    for (int kt = 0; kt < KT; ++kt) {
        const int rem = KT - 1 - kt;   // tiles still ahead (staged, in flight)
        if (rem >= NBUF - 1) wait_vm<(NBUF - 1) * NCH>();
        else if (NBUF == 3 && rem == 1) wait_vm<NCH>();
        else wait_vm<0>();
        __builtin_amdgcn_sched_barrier(0);
        __builtin_amdgcn_s_barrier();
        __builtin_amdgcn_sched_barrier(0);

        F8 afh[4], afl[SPLIT ? 4 : 1];
#pragma unroll
        for (int mi = 0; mi < 4; ++mi) {
            int ar = wm * 64 + mi * 16 + x;
            int ad = (ar * 4 + (hi ^ ((ar >> 1) & 3))) * 8;
            afh[mi] = *(const F8 *)&s[cur][ad];
            if constexpr (SPLIT) afl[mi] = *(const F8 *)&s[cur][AOFF2 + ad];
        }
        __builtin_amdgcn_s_setprio(1);
#pragma unroll
        for (int nj = 0; nj < NJ; ++nj) {
            int br = wn * (BN / 2) + nj * 16 + x;
            int bd = (br * 4 + (hi ^ ((br >> 1) & 3))) * 8;
            F8 bfh = *(const F8 *)&s[cur][BOFF + bd];
            F8 bf2;
            if constexpr (HAS2) bf2 = *(const F8 *)&s[cur][B2OFF + bd];
#pragma unroll
            for (int mi = 0; mi < 4; ++mi) {
                acc[mi][nj] = mfma16(afh[mi], bfh, acc[mi][nj]);
                if constexpr (SPLIT) {
                    acc2[mi][nj] = mfma16(afh[mi], bf2, acc2[mi][nj]);
                    acc2[mi][nj] = mfma16(afl[mi], bfh, acc2[mi][nj]);
                }
                if constexpr (GU) acc2[mi][nj] = mfma16(afh[mi], bf2, acc2[mi][nj]);
            }
        }
        __builtin_amdgcn_s_setprio(0);

        asm volatile("s_waitcnt lgkmcnt(0)" ::: "memory");
        __builtin_amdgcn_sched_barrier(0);
        __builtin_amdgcn_s_barrier();
        __builtin_amdgcn_sched_barrier(0);
        if (kt + NBUF < KT) stageTo(kt + NBUF, cur);
        cur = (cur + 1 == NBUF) ? 0 : cur + 1;
    }

    if (SPLIT && p.epi == 6) {
        // fused RoPE epilogue: combine+bias -> LDS, exchange rotate-half pair
        float *sEpi = (float *)&s[0][0];   // 128x64 f32 = 32KB (staging dead)
#pragma unroll
        for (int mi = 0; mi < 4; ++mi)
#pragma unroll
            for (int nj = 0; nj < NJ; ++nj)
#pragma unroll
                for (int r = 0; r < 4; ++r) {
                    int rl = wm * 64 + mi * 16 + hi * 4 + r;
                    int cl = wn * (BN / 2) + nj * 16 + x;
                    float v = fmaf(acc2[mi][nj][r], LO_INV, acc[mi][nj][r]) + p.bias[n0 + cl];
                    sEpi[rl * 64 + cl] = v;
                }
        __syncthreads();
        const bool isV = (n0 >= 1280);
        const bool isK = (n0 >= 1024) && !isV;
#pragma unroll
        for (int mi = 0; mi < 4; ++mi)
#pragma unroll
            for (int nj = 0; nj < NJ; ++nj)
#pragma unroll
                for (int r = 0; r < 4; ++r) {
                    int rl = wm * 64 + mi * 16 + hi * 4 + r;
                    int cl = wn * (BN / 2) + nj * 16 + x;
                    long row = m0 + rl;
                    float xv = sEpi[rl * 64 + cl];
                    if (isV) {
                        p.outF[row * 256 + (n0 - 1280) + cl] = xv;
                    } else {
                        int spos = (int)(row & (Sc - 1));
                        float xp = sEpi[rl * 64 + (cl ^ 32)];
                        float cs = p.resid[spos * 64 + cl];
                        float sn = p.bw[spos * 64 + cl];
                        float o = xv * cs + ((cl < 32) ? -xp : xp) * sn;
                        _Float16 hv = (_Float16)o;
                        _Float16 lo = (_Float16)((o - (float)hv) * LO_SCALE);
                        if (isK) {
                            long off = row * 256 + (n0 - 1024) + cl;
                            p.rKh[off] = hv; p.rKl[off] = lo;
                        } else {
                            long off = row * 1024 + n0 + cl;
                            p.rQh[off] = hv; p.rQl[off] = lo;
                        }
                    }
                }
        return;
    }

#pragma unroll
    for (int mi = 0; mi < 4; ++mi)
#pragma unroll
        for (int nj = 0; nj < NJ; ++nj)
#pragma unroll
            for (int r = 0; r < 4; ++r) {
                long row = m0 + wm * 64 + mi * 16 + hi * 4 + r;
                long col = n0 + wn * (BN / 2) + nj * 16 + x;
                float v = acc[mi][nj][r];
                if constexpr (GU) {
                    float u = acc2[mi][nj][r];
                    float he = v / (1.f + __expf(-v)) * u;
                    p.outBF[row * p.ldc + col] = __float2bfloat16(he);
                } else {
                    if constexpr (SPLIT) v = fmaf(acc2[mi][nj][r], LO_INV, v);
                    switch (p.epi) {
                    case 0: p.outF[row * p.ldc + col] = v + p.bias[col]; break;
                    case 2: {
                        float o = v + p.resid[row * p.ldc + col];
                        p.outF[row * p.ldc + col] = o;
                        p.outF2[row * p.ldc + col] = o;
                    } break;
                    case 5: // plain store to per-slot scratch, weight folded
                        p.outF[row * p.ldc + col] = v * p.bw[row];
                        break;
                    }
                }
            }
}

// combine: out[tok] += scat[slot0(tok)] + scat[slot1(tok)]  (coalesced f32x4)
__global__ __launch_bounds__(256) void combine_k(const float *__restrict__ scat,
        const int *__restrict__ tok_slot, float *__restrict__ out) {
    const long tok = blockIdx.x;
    const int c = threadIdx.x * 4;
    const long s0 = tok_slot[tok * 2], s1 = tok_slot[tok * 2 + 1];
    f32x4 a = *(const f32x4 *)(scat + s0 * Dc + c);
    f32x4 b = *(const f32x4 *)(scat + s1 * Dc + c);
    f32x4 o = *(const f32x4 *)(out + tok * Dc + c);
#pragma unroll
    for (int j = 0; j < 4; ++j) o[j] += a[j] + b[j];
    *(f32x4 *)(out + tok * Dc + c) = o;
}

// ----------------------------------------------------- flash attention ----
// Diagonal-paired blocks: block (pairI, bh) processes q-tiles pairI and
// 63-pairI sequentially -> uniform 65 kv-tiles per block (no straggler tail).
// Per segment: 2 waves x 16 q-rows, swapped QK^T (mfma(K,Q)), in-register
// softmax (2 shfl_xor), P to PV A-frag via packed shuffles, K/V staged via
// global_load_lds into swizzled LDS, depth-2 counted-vmcnt pipeline,
// defer-max (THR=8). Outputs ctx hi/lo f16.
__global__ __launch_bounds__(128, 2) void attn_k(
    const _Float16 *__restrict__ qh, const _Float16 *__restrict__ ql,
    const _Float16 *__restrict__ kh, const _Float16 *__restrict__ kl,
    const _Float16 *__restrict__ vTh, const _Float16 *__restrict__ vTl,
    _Float16 *__restrict__ ctxh, _Float16 *__restrict__ ctxl) {
    __shared__ __align__(16) _Float16 kbuf[2][2][32 * 64]; // [dbuf][hi/lo][kv][d]
    __shared__ __align__(16) _Float16 vbuf[2][2][64 * 32]; // [dbuf][hi/lo][d][kv]
    const int tid = threadIdx.x, lane = tid & 63, wid = tid >> 6;
    const int x = lane & 15, hi = lane >> 4;
    const int pairI = blockIdx.x;
    const int bh = blockIdx.y;
    const int b = bh >> 4, h = bh & 15, kvh = h >> 2;
    const long kRow0 = (long)b * Sc * 256;
    const long vRow0 = (long)(b * 4 + kvh) * 64 * (long)Sc;

    auto stage = [&](int kt, int bufI) {
        if (wid == 0) {          // K: [kv32][d64] CK=8, swizzle c^=(kv&7)
#pragma unroll
            for (int ss = 0; ss < 2; ++ss) {
                const _Float16 *src = ss ? kl : kh;
#pragma unroll
                for (int i = 0; i < 4; ++i) {
                    int kv = 8 * i + (lane >> 3);
                    int cd = (lane & 7) ^ (kv & 7);
                    const _Float16 *g = src + kRow0 + ((long)kt * 32 + kv) * 256 + kvh * 64 + cd * 8;
                    gll16(g, &kbuf[bufI][ss][i * 512]);
                }
            }
        } else {                 // V^T: [d64][kv32] CK=4, swizzle c^=((d>>1)&3)
#pragma unroll
            for (int ss = 0; ss < 2; ++ss) {
                const _Float16 *src = ss ? vTl : vTh;
#pragma unroll
                for (int i = 0; i < 4; ++i) {
                    int d = 16 * i + (lane >> 2);
                    int ckv = (lane & 3) ^ ((d >> 1) & 3);
                    const _Float16 *g = src + vRow0 + (long)d * Sc + (long)kt * 32 + ckv * 8;
                    gll16(g, &vbuf[bufI][ss][i * 512]);
                }
            }
        }
    };

    for (int seg = 0; seg < 2; ++seg) {
        const int qt = seg ? (63 - pairI) : pairI;
        const int q0 = qt * 32;
        const long qtokW = (long)b * Sc + q0 + wid * 16;    // wave's 16 q-rows

        f16x8 qfh[2], qfl[2];
#pragma unroll
        for (int ks = 0; ks < 2; ++ks) {
            long off = (qtokW + x) * (long)Dc + h * 64 + ks * 32 + hi * 8;
            qfh[ks] = *(const f16x8 *)(qh + off);
            qfl[ks] = *(const f16x8 *)(ql + off);
        }
        asm volatile("s_waitcnt vmcnt(0)" ::: "memory");
        __builtin_amdgcn_sched_barrier(0);

        f32x4 o1[4], o2[4];
        float mrow = -3.0e38f, lrow = 0.f;
#pragma unroll
        for (int dj = 0; dj < 4; ++dj) {
            o1[dj] = (f32x4){0.f, 0.f, 0.f, 0.f};
            o2[dj] = (f32x4){0.f, 0.f, 0.f, 0.f};
        }

        const int NT = qt + 1;

        stage(0, 0);
        stage(1, 1);

        for (int kt = 0; kt < NT; ++kt) {
            if (kt + 1 < NT) asm volatile("s_waitcnt vmcnt(8)" ::: "memory");
            else asm volatile("s_waitcnt vmcnt(0)" ::: "memory");
            __builtin_amdgcn_sched_barrier(0);
            __builtin_amdgcn_s_barrier();
            __builtin_amdgcn_sched_barrier(0);
            const int cur = kt & 1;

            f32x4 s1[2], s2[2];
#pragma unroll
            for (int kvs = 0; kvs < 2; ++kvs) {
                s1[kvs] = (f32x4){0.f, 0.f, 0.f, 0.f};
                s2[kvs] = (f32x4){0.f, 0.f, 0.f, 0.f};
            }
            __builtin_amdgcn_s_setprio(1);
#pragma unroll
            for (int ks = 0; ks < 2; ++ks)
#pragma unroll
                for (int kvs = 0; kvs < 2; ++kvs) {
                    int row = kvs * 16 + x;
                    int addr = row * 64 + (((ks * 4 + hi) ^ (row & 7)) << 3);
                    f16x8 kfh = *(const f16x8 *)&kbuf[cur][0][addr];
                    f16x8 kfl = *(const f16x8 *)&kbuf[cur][1][addr];
                    s1[kvs] = mfma16(kfh, qfh[ks], s1[kvs]);
                    s2[kvs] = mfma16(kfl, qfh[ks], s2[kvs]);
                    s2[kvs] = mfma16(kfh, qfl[ks], s2[kvs]);
                }
            __builtin_amdgcn_s_setprio(0);

            const bool diag = (kt == NT - 1);
            const int qpos = q0 + wid * 16 + x;
            float sv[2][4];
#pragma unroll
            for (int kvs = 0; kvs < 2; ++kvs)
#pragma unroll
                for (int r = 0; r < 4; ++r) {
                    float v = fmaf(s2[kvs][r], LO_INV, s1[kvs][r]) * 0.125f;
                    if (diag) {
                        int kvpos = kt * 32 + kvs * 16 + 4 * hi + r;
                        if (kvpos > qpos) v = -3.0e38f;
                    }
                    sv[kvs][r] = v;
                }
            float mx = sv[0][0];
#pragma unroll
            for (int kvs = 0; kvs < 2; ++kvs)
#pragma unroll
                for (int r = 0; r < 4; ++r) mx = fmaxf(mx, sv[kvs][r]);
            mx = fmaxf(mx, __shfl_xor(mx, 16));
            mx = fmaxf(mx, __shfl_xor(mx, 32));
            if (!__all(mx - mrow <= 8.0f)) {
                float mnew = fmaxf(mrow, mx);
                float scl = __expf(mrow - mnew);
                mrow = mnew;
                lrow *= scl;
                float sclr[4];
#pragma unroll
                for (int r = 0; r < 4; ++r) sclr[r] = __shfl(scl, 4 * hi + r);
#pragma unroll
                for (int dj = 0; dj < 4; ++dj)
#pragma unroll
                    for (int r = 0; r < 4; ++r) {
                        o1[dj][r] *= sclr[r];
                        o2[dj][r] *= sclr[r];
                    }
            }
            float pv[2][4];
            float ls = 0.f;
#pragma unroll
            for (int kvs = 0; kvs < 2; ++kvs)
#pragma unroll
                for (int r = 0; r < 4; ++r) {
                    pv[kvs][r] = __expf(sv[kvs][r] - mrow);
                    ls += pv[kvs][r];
                }
            ls += __shfl_xor(ls, 16);
            ls += __shfl_xor(ls, 32);
            lrow += ls;
            u32 Bh0[2], Bh1[2], Bl0[2], Bl1[2];
#pragma unroll
            for (int pr = 0; pr < 2; ++pr) {
                _Float16 a0 = (_Float16)pv[0][2 * pr], a1 = (_Float16)pv[0][2 * pr + 1];
                _Float16 b0 = (_Float16)pv[1][2 * pr], b1 = (_Float16)pv[1][2 * pr + 1];
                Bh0[pr] = pack2(a0, a1);
                Bh1[pr] = pack2(b0, b1);
                _Float16 la0 = (_Float16)((pv[0][2 * pr] - (float)a0) * LO_SCALE);
                _Float16 la1 = (_Float16)((pv[0][2 * pr + 1] - (float)a1) * LO_SCALE);
                _Float16 lb0 = (_Float16)((pv[1][2 * pr] - (float)b0) * LO_SCALE);
                _Float16 lb1 = (_Float16)((pv[1][2 * pr + 1] - (float)b1) * LO_SCALE);
                Bl0[pr] = pack2(la0, la1);
                Bl1[pr] = pack2(lb0, lb1);
            }
            const int srcLow = x + ((lane & 16) ? 32 : 0);
            const int srcHigh = srcLow + 16;
            const bool useB1 = lane >= 32;
            union { u32 u[4]; f16x8 v; } fh, fl;
#pragma unroll
            for (int pr = 0; pr < 2; ++pr) {
                u32 t0 = (u32)__shfl((int)Bh0[pr], srcLow);
                u32 t1 = (u32)__shfl((int)Bh1[pr], srcLow);
                fh.u[pr] = useB1 ? t1 : t0;
                u32 u0 = (u32)__shfl((int)Bh0[pr], srcHigh);
                u32 u1 = (u32)__shfl((int)Bh1[pr], srcHigh);
                fh.u[2 + pr] = useB1 ? u1 : u0;
                u32 s0 = (u32)__shfl((int)Bl0[pr], srcLow);
                u32 s1v = (u32)__shfl((int)Bl1[pr], srcLow);
                fl.u[pr] = useB1 ? s1v : s0;
                u32 w0 = (u32)__shfl((int)Bl0[pr], srcHigh);
                u32 w1 = (u32)__shfl((int)Bl1[pr], srcHigh);
                fl.u[2 + pr] = useB1 ? w1 : w0;
            }
            f16x8 pah = fh.v, pal = fl.v;

            __builtin_amdgcn_s_setprio(1);
#pragma unroll
            for (int dj = 0; dj < 4; ++dj) {
                int d = dj * 16 + x;
                int addr = d * 32 + ((hi ^ ((d >> 1) & 3)) << 3);
                f16x8 vhf = *(const f16x8 *)&vbuf[cur][0][addr];
                f16x8 vlf = *(const f16x8 *)&vbuf[cur][1][addr];
                o1[dj] = mfma16(pah, vhf, o1[dj]);
                o2[dj] = mfma16(pah, vlf, o2[dj]);
                o2[dj] = mfma16(pal, vhf, o2[dj]);
            }
            __builtin_amdgcn_s_setprio(0);

            asm volatile("s_waitcnt lgkmcnt(0)" ::: "memory");
            __builtin_amdgcn_sched_barrier(0);
            __builtin_amdgcn_s_barrier();
            __builtin_amdgcn_sched_barrier(0);
            if (kt + 2 < NT) stage(kt + 2, cur);
        }

        float linv = 1.0f / lrow;
        float lr[4];
#pragma unroll
        for (int r = 0; r < 4; ++r) lr[r] = __shfl(linv, 4 * hi + r);
#pragma unroll
        for (int dj = 0; dj < 4; ++dj)
#pragma unroll
            for (int r = 0; r < 4; ++r) {
                long tok = qtokW + 4 * hi + r;
                float ov = fmaf(o2[dj][r], LO_INV, o1[dj][r]) * lr[r];
                _Float16 hv = (_Float16)ov;
                long off = tok * Dc + h * 64 + dj * 16 + x;
                ctxh[off] = hv;
                ctxl[off] = (_Float16)((ov - (float)hv) * LO_SCALE);
            }
    }
}

// ------------------------------------------------------- small kernels ----
__global__ __launch_bounds__(256) void rmsnorm_split_k(const float *__restrict__ x,
        const float *__restrict__ w, _Float16 *__restrict__ oh, _Float16 *__restrict__ ol) {
    const long row = blockIdx.x;
    const int tid = threadIdx.x, lane = tid & 63, wid = tid >> 6;
    f32x4 v = *(const f32x4 *)(x + row * Dc + tid * 4);
    float ss = v[0] * v[0] + v[1] * v[1] + v[2] * v[2] + v[3] * v[3];
#pragma unroll
    for (int off = 1; off < 64; off <<= 1) ss += __shfl_xor(ss, off);
    __shared__ float sw[4];
    if (lane == 0) sw[wid] = ss;
    __syncthreads();
    float inv = 1.0f / sqrtf((sw[0] + sw[1] + sw[2] + sw[3]) * (1.f / Dc) + 1e-6f);
#pragma unroll
    for (int j = 0; j < 4; ++j) {
        float y = v[j] * inv * w[tid * 4 + j];
        _Float16 hv = (_Float16)y;
        oh[row * Dc + tid * 4 + j] = hv;
        ol[row * Dc + tid * 4 + j] = (_Float16)((y - (float)hv) * LO_SCALE);
    }
}

// fused RMSNorm (ln2) + router: keeps f32 row in regs (router precision),
// writes only tbf; computes 8 logits, softmax, top-2, counts.
__global__ __launch_bounds__(256) void rmsnorm_router_k(const float *__restrict__ x,
        const float *__restrict__ w, const float *__restrict__ rw,
        __hip_bfloat16 *__restrict__ tb, float *__restrict__ probs,
        int *__restrict__ tok_e, float *__restrict__ tok_w, int *__restrict__ cnt) {
    const long row = blockIdx.x;
    const int tid = threadIdx.x, lane = tid & 63, wid = tid >> 6;
    f32x4 v = *(const f32x4 *)(x + row * Dc + tid * 4);
    float ss = v[0] * v[0] + v[1] * v[1] + v[2] * v[2] + v[3] * v[3];
#pragma unroll
    for (int off = 1; off < 64; off <<= 1) ss += __shfl_xor(ss, off);
    __shared__ float sw[4];
    __shared__ float part[4][8];
    if (lane == 0) sw[wid] = ss;
    __syncthreads();
    float inv = 1.0f / sqrtf((sw[0] + sw[1] + sw[2] + sw[3]) * (1.f / Dc) + 1e-6f);
    float y[4];
#pragma unroll
    for (int j = 0; j < 4; ++j) {
        y[j] = v[j] * inv * w[tid * 4 + j];
        tb[row * Dc + tid * 4 + j] = __float2bfloat16(y[j]);
    }
    float acc[8];
#pragma unroll
    for (int e = 0; e < 8; ++e) {
        f32x4 wv = *(const f32x4 *)(rw + (long)e * Dc + tid * 4);
        acc[e] = y[0] * wv[0] + y[1] * wv[1] + y[2] * wv[2] + y[3] * wv[3];
    }
#pragma unroll
    for (int off = 1; off < 64; off <<= 1)
#pragma unroll
        for (int e = 0; e < 8; ++e) acc[e] += __shfl_xor(acc[e], off);
    if (lane == 0)
#pragma unroll
        for (int e = 0; e < 8; ++e) part[wid][e] = acc[e];
    __syncthreads();
    if (tid == 0) {
        float lg[8];
        float mx = -3.0e38f;
#pragma unroll
        for (int e = 0; e < 8; ++e) {
            lg[e] = part[0][e] + part[1][e] + part[2][e] + part[3][e];
            mx = fmaxf(mx, lg[e]);
        }
        float ex[8], s = 0.f;
#pragma unroll
        for (int e = 0; e < 8; ++e) { ex[e] = expf(lg[e] - mx); s += ex[e]; }
        float invs = 1.f / s;
        int i1 = -1, i2 = -1;
        float p1v = -1.f, p2v = -1.f;
#pragma unroll
        for (int e = 0; e < 8; ++e) {
            float pe = ex[e] * invs;
            probs[row * 8 + e] = pe;
            if (pe > p1v) { i2 = i1; p2v = p1v; i1 = e; p1v = pe; }
            else if (pe > p2v) { i2 = e; p2v = pe; }
        }
        float wsum = p1v + p2v;
        tok_e[row * 2] = i1; tok_e[row * 2 + 1] = i2;
        tok_w[row * 2] = p1v / wsum; tok_w[row * 2 + 1] = p2v / wsum;
        atomicAdd(&cnt[i1], 1);
        atomicAdd(&cnt[i2], 1);
    }
}

__global__ void pack_qkvw_k(const float *__restrict__ qw, const float *__restrict__ kw,
        const float *__restrict__ vw, _Float16 *wh, _Float16 *wl) {
    const long n = (long)QKVN * Dc;
    for (long i = (long)blockIdx.x * 256 + threadIdx.x; i < n; i += (long)gridDim.x * 256) {
        long o = i >> 10;
        int d = (int)(i & 1023);
        float v;
        if (o < 1024) v = qw[o * 1024 + d];
        else if (o < 1280) v = kw[(o - 1024) * 1024 + d];
        else v = vw[(o - 1280) * 1024 + d];
        _Float16 h = (_Float16)v;
        wh[i] = h;
        wl[i] = (_Float16)((v - (float)h) * LO_SCALE);
    }
}

__global__ void split_f16_k(const float *__restrict__ x, _Float16 *hi, _Float16 *lo, long n) {
    for (long i = (long)blockIdx.x * 256 + threadIdx.x; i < n; i += (long)gridDim.x * 256) {
        float v = x[i];
        _Float16 h = (_Float16)v;
        hi[i] = h;
        lo[i] = (_Float16)((v - (float)h) * LO_SCALE);
    }
}

__global__ void pack_bias_k(const float *qb, const float *kb, const float *vb, float *out) {
    int i = blockIdx.x * 256 + threadIdx.x;
    if (i >= QKVN) return;
    out[i] = (i < 1024) ? qb[i] : (i < 1280) ? kb[i - 1024] : vb[i - 1280];
}

__global__ __launch_bounds__(256) void transpose_bf16_k(const float *__restrict__ in,
        __hip_bfloat16 *__restrict__ out, int R, int C) {
    __shared__ float tile[64 * 65];
    const long eo = (long)blockIdx.z * R * C;
    const int r0 = blockIdx.y * 64, c0 = blockIdx.x * 64;
#pragma unroll
    for (int i = 0; i < 16; ++i) {
        int idx = threadIdx.x + i * 256;
        int r = idx >> 6, c = idx & 63;
        tile[r * 65 + c] = in[eo + (long)(r0 + r) * C + (c0 + c)];
    }
    __syncthreads();
#pragma unroll
    for (int i = 0; i < 16; ++i) {
        int idx = threadIdx.x + i * 256;
        int cc = idx >> 6, rr = idx & 63;
        out[eo + (long)(c0 + cc) * R + (r0 + rr)] = __float2bfloat16(tile[rr * 65 + cc]);
    }
}

// transpose V (from vqf [tok][256], fp32) to [B*KV*64][S] with hi/lo split
__global__ __launch_bounds__(256) void vtrans_k(const float *__restrict__ vqf,
        _Float16 *__restrict__ vTh, _Float16 *__restrict__ vTl) {
    __shared__ float tile[64][65];
    const int tok0 = blockIdx.x * 64;
    const int bk = blockIdx.y;
    const int b = bk >> 2, kvh = bk & 3;
#pragma unroll
    for (int it = 0; it < 16; ++it) {
        int idx = it * 256 + threadIdx.x;
        int r = idx >> 6, c = idx & 63;
        tile[r][c] = vqf[((long)b * Sc + tok0 + r) * 256 + kvh * 64 + c];
    }
    __syncthreads();
    const int d = threadIdx.x & 63, ch = threadIdx.x >> 6;
    long orow = ((long)bk * 64 + d) * (long)Sc + tok0 + ch * 16;
    f16x8 oh[2], ol[2];
#pragma unroll
    for (int j = 0; j < 16; ++j) {
        float v = tile[ch * 16 + j][d];
        _Float16 hv = (_Float16)v;
        oh[j >> 3][j & 7] = hv;
        ol[j >> 3][j & 7] = (_Float16)((v - (float)hv) * LO_SCALE);
    }
    *(f16x8 *)(vTh + orow) = oh[0];
    *(f16x8 *)(vTh + orow + 8) = oh[1];
    *(f16x8 *)(vTl + orow) = ol[0];
    *(f16x8 *)(vTl + orow + 8) = ol[1];
}

__global__ __launch_bounds__(1024) void router_p2_k(const int *cnt, const float *probs,
        int *poff, float *aux_out) {
    __shared__ float sd[1024];
    const int tid = threadIdx.x;
    const int e = tid & 7, rs = tid >> 3;
    float s = 0.f;
    for (int r = rs; r < Tc; r += 128) s += probs[(long)r * 8 + e];
    sd[tid] = s;
    __syncthreads();
    for (int st = 64; st >= 1; st >>= 1) {
        if (rs < st) sd[tid] += sd[tid + st * 8];
        __syncthreads();
    }
    if (tid == 0) {
        float a = 0.f;
        for (int ee = 0; ee < 8; ++ee) {
            float m = sd[ee] * (1.f / Tc);
            a += m * m;
        }
        aux_out[0] = a;
        int o = 0;
        poff[0] = 0;
        for (int ee = 0; ee < 8; ++ee) { o += (cnt[ee] + 127) & ~127; poff[ee + 1] = o; }
    }
}

__global__ void router_p3_k(const int *tok_e, const float *tok_w, const int *poff,
        int *cursor, int *btok, float *bw, int *tok_slot) {
    long tok = (long)blockIdx.x * 256 + threadIdx.x;
    if (tok >= Tc) return;
#pragma unroll
    for (int j = 0; j < 2; ++j) {
        int e = tok_e[tok * 2 + j];
        int slot = atomicAdd(&cursor[e], 1);
        btok[poff[e] + slot] = (int)tok;
        bw[poff[e] + slot] = tok_w[tok * 2 + j];
        tok_slot[tok * 2 + j] = poff[e] + slot;
    }
}

__global__ void router_p4_k(const int *poff, const int *cnt, int *btok, float *bw) {
    int s = blockIdx.x * 256 + threadIdx.x;
    if (s >= poff[8]) return;
    int e = 0;
    while (s >= poff[e + 1]) ++e;
    if (s - poff[e] >= cnt[e]) { btok[s] = 0; bw[s] = 0.f; }
}

// -------------------------------------------------------------- launch ----
extern "C" void kernel_launch(void *const *d_in, const int *in_sizes, int n_in,
                              void *d_out, int out_size, void *d_ws, size_t ws_size,
                              hipStream_t stream) {
    (void)in_sizes; (void)n_in;
    const float *hidden = (const float *)d_in[0];
    const float *ln1 = (const float *)d_in[1];
    const float *ln2 = (const float *)d_in[2];
    const float *qw = (const float *)d_in[3];
    const float *qb = (const float *)d_in[4];
    const float *kw = (const float *)d_in[5];
    const float *kb = (const float *)d_in[6];
    const float *vw = (const float *)d_in[7];
    const float *vb = (const float *)d_in[8];
    const float *ow = (const float *)d_in[9];
    const float *rw = (const float *)d_in[10];
    const float *gw = (const float *)d_in[11];
    const float *uw = (const float *)d_in[12];
    const float *dwn = (const float *)d_in[13];
    const float *cosb = (const float *)d_in[14];
    const float *sinb = (const float *)d_in[15];
    float *outx = (float *)d_out;

    char *base = (char *)d_ws;
    size_t off = 0;
    auto alloc = [&](size_t bytes) -> char * {
        char *p = base + off;
        off += (bytes + 255) & ~(size_t)255;
        return p;
    };
    _Float16 *qkvwh = (_Float16 *)alloc((size_t)QKVN * Dc * 2);
    _Float16 *qkvwl = (_Float16 *)alloc((size_t)QKVN * Dc * 2);
    float *qkvb = (float *)alloc(QKVN * 4);
    _Float16 *owh = (_Float16 *)alloc((size_t)Dc * Dc * 2);
    _Float16 *owl = (_Float16 *)alloc((size_t)Dc * Dc * 2);
    __hip_bfloat16 *gateT = (__hip_bfloat16 *)alloc((size_t)Ec * Fc * Dc * 2);
    __hip_bfloat16 *upT = (__hip_bfloat16 *)alloc((size_t)Ec * Fc * Dc * 2);
    __hip_bfloat16 *downT = (__hip_bfloat16 *)alloc((size_t)Ec * Dc * Fc * 2);
    // U2..vTl span (~40 MB) is dead by down-GEMM time; scat (36 MB) aliases it
    char *U2 = alloc((size_t)Tc * Dc * 4);
    _Float16 *hh = (_Float16 *)U2;
    _Float16 *hl = hh + (size_t)Tc * Dc;
    char *U3 = alloc((size_t)Tc * Dc * 4);
    _Float16 *qhb = (_Float16 *)U3;
    _Float16 *qlb = qhb + (size_t)Tc * Dc;
    float *x1 = (float *)U3;
    _Float16 *khb = (_Float16 *)alloc((size_t)Tc * 256 * 2);
    _Float16 *klb = (_Float16 *)alloc((size_t)Tc * 256 * 2);
    _Float16 *vTh = (_Float16 *)alloc((size_t)Tc * 256 * 2);
    _Float16 *vTl = (_Float16 *)alloc((size_t)Tc * 256 * 2);
    float *scat = (float *)U2;   // CAP*Dc*4 = 36 MB <= U2..vTl span (~40 MB)
    _Float16 *ctxh = (_Float16 *)alloc((size_t)Tc * Dc * 2);
    _Float16 *ctxl = (_Float16 *)alloc((size_t)Tc * Dc * 2);
    __hip_bfloat16 *tbf = (__hip_bfloat16 *)alloc((size_t)Tc * Dc * 2);
    float *vqf = (float *)alloc((size_t)Tc * 256 * 4);
    float *probs = (float *)alloc((size_t)Tc * 8 * 4);
    int *tok_e = (int *)alloc((size_t)Tc * 2 * 4);
    float *tok_w = (float *)alloc((size_t)Tc * 2 * 4);
    int *tok_slot = (int *)alloc((size_t)Tc * 2 * 4);
    int *cnt = (int *)alloc(256);
    int *cursor = cnt + 8;
    int *poff = (int *)alloc(256);
    int *btok = (int *)alloc((size_t)CAP * 4);
    float *bwgt = (float *)alloc((size_t)CAP * 4);
    __hip_bfloat16 *gbuf = (__hip_bfloat16 *)alloc((size_t)CAP * Fc * 2);

    if (off > ws_size) {
        hipMemsetAsync(d_out, 0, (size_t)out_size * 4, stream);
        return;
    }

    hipMemsetAsync(cnt, 0, 64, stream);
    pack_qkvw_k<<<1024, 256, 0, stream>>>(qw, kw, vw, qkvwh, qkvwl);
    pack_bias_k<<<(QKVN + 255) / 256, 256, 0, stream>>>(qb, kb, vb, qkvb);
    split_f16_k<<<1024, 256, 0, stream>>>(ow, owh, owl, (long)Dc * Dc);
    transpose_bf16_k<<<dim3(Fc / 64, Dc / 64, Ec), 256, 0, stream>>>(gw, gateT, Dc, Fc);
    transpose_bf16_k<<<dim3(Fc / 64, Dc / 64, Ec), 256, 0, stream>>>(uw, upT, Dc, Fc);
    transpose_bf16_k<<<dim3(Dc / 64, Fc / 64, Ec), 256, 0, stream>>>(dwn, downT, Fc, Dc);
    rmsnorm_split_k<<<Tc, 256, 0, stream>>>(hidden, ln1, hh, hl);

    // QKV GEMM with fused RoPE epilogue (epi=6): writes q/k hi-lo f16 + vqf
    GemmP g{};
    g.Ah = hh; g.Al = hl; g.Bh = qkvwh; g.Bl = qkvwl;
    g.lda = Dc; g.ldb = Dc; g.bExp = 0; g.K = Dc;
    g.bias = qkvb; g.resid = cosb; g.bw = sinb;
    g.outF = vqf; g.rQh = qhb; g.rQl = qlb; g.rKh = khb; g.rKl = klb;
    g.ldc = QKVN; g.epi = 6;
    gemm_k<_Float16, true, false, false, 64><<<dim3(Tc / 128, QKVN / 64), 256, 0, stream>>>(g);

    vtrans_k<<<dim3(Sc / 64, Bc * KVc), 256, 0, stream>>>(vqf, vTh, vTl);
    attn_k<<<dim3(Sc / 64, Bc * Hc), 128, 0, stream>>>(qhb, qlb, khb, klb, vTh, vTl, ctxh, ctxl);

    GemmP go{};
    go.Ah = ctxh; go.Al = ctxl; go.Bh = owh; go.Bl = owl;
    go.lda = Dc; go.ldb = Dc; go.bExp = 0; go.K = Dc;
    go.resid = hidden; go.outF = x1; go.outF2 = outx; go.ldc = Dc; go.epi = 2;
    gemm_k<_Float16, true, false, false, 64><<<dim3(Tc / 128, Dc / 64), 256, 0, stream>>>(go);

    // fused RMSNorm(ln2) + router logits/softmax/top-2
    rmsnorm_router_k<<<Tc, 256, 0, stream>>>(x1, ln2, rw, tbf, probs, tok_e, tok_w, cnt);
    router_p2_k<<<1, 1024, 0, stream>>>(cnt, probs, poff, outx + (long)Tc * Dc);
    router_p3_k<<<Tc / 256, 256, 0, stream>>>(tok_e, tok_w, poff, cursor, btok, bwgt, tok_slot);
    router_p4_k<<<CAP / 256, 256, 0, stream>>>(poff, cnt, btok, bwgt);

    // fused gate+up: silu(t@gate)*(t@up) -> gbuf, XCD-chunked M, depth-3 pipe
    GemmP gg{};
    gg.Ah = tbf; gg.Bh = gateT; gg.Bh2 = upT;
    gg.lda = Dc; gg.ldb = Dc; gg.bExp = (long)Fc * Dc; gg.K = Dc;
    gg.poff = poff; gg.gidx = btok; gg.outBF = gbuf; gg.ldc = Fc;
    gemm_k<__hip_bfloat16, false, true, true, 128, true, 3><<<dim3(CAP / 128, Fc / 128), 256, 0, stream>>>(gg);

    // down: BN=128, weighted store to per-slot scratch, XCD-chunked M, depth-3
    GemmP gd{};
    gd.Ah = gbuf; gd.Bh = downT;
    gd.lda = Fc; gd.ldb = Fc; gd.bExp = (long)Dc * Fc; gd.K = Fc;
    gd.poff = poff; gd.bw = bwgt;
    gd.outF = scat; gd.ldc = Dc; gd.epi = 5;
    gemm_k<__hip_bfloat16, false, false, false, 128, true, 3><<<dim3(CAP / 128, Dc / 128), 256, 0, stream>>>(gd);

    // combine: outx[tok] += scat[slot0] + scat[slot1]
    combine_k<<<Tc, 256, 0, stream>>>(scat, tok_slot, outx);
}

// Round 14
// 677.085 us; speedup vs baseline: 1.2435x; 1.0056x over previous
//
#include <hip/hip_runtime.h>
#include <hip/hip_bf16.h>

#define DEVI __device__ __forceinline__

typedef float f32x4 __attribute__((ext_vector_type(4)));
typedef _Float16 f16x8 __attribute__((ext_vector_type(8)));
typedef short s16x8 __attribute__((ext_vector_type(8)));
typedef unsigned int u32;

constexpr int Bc = 2, Sc = 2048, Dc = 1024, Hc = 16, KVc = 4, HDc = 64, Fc = 2816, Ec = 8;
constexpr int Tc = Bc * Sc;                 // 4096 tokens
constexpr int QKVN = Hc * HDc + 2 * KVc * HDc; // 1536
constexpr int CAP = Tc * 2 + Ec * 128;      // 9216 padded expert-token slots
constexpr float LO_SCALE = 1024.0f;
constexpr float LO_INV = 1.0f / 1024.0f;

DEVI f32x4 mfma16(f16x8 a, f16x8 b, f32x4 c) {
    return __builtin_amdgcn_mfma_f32_16x16x32_f16(a, b, c, 0, 0, 0);
}
DEVI f32x4 mfma16(s16x8 a, s16x8 b, f32x4 c) {
    return __builtin_amdgcn_mfma_f32_16x16x32_bf16(a, b, c, 0, 0, 0);
}

DEVI void gll16(const void *g, void *l) {
    __builtin_amdgcn_global_load_lds(
        (const __attribute__((address_space(1))) u32 *)g,
        (__attribute__((address_space(3))) u32 *)l, 16, 0, 0);
}

DEVI u32 pack2(_Float16 a, _Float16 b) {
    union { _Float16 h[2]; u32 u; } t;
    t.h[0] = a; t.h[1] = b;
    return t.u;
}

template <int N> DEVI void wait_vm() {
    if constexpr (N == 0) asm volatile("s_waitcnt vmcnt(0)" ::: "memory");
    else if constexpr (N == 4) asm volatile("s_waitcnt vmcnt(4)" ::: "memory");
    else if constexpr (N == 6) asm volatile("s_waitcnt vmcnt(6)" ::: "memory");
    else if constexpr (N == 8) asm volatile("s_waitcnt vmcnt(8)" ::: "memory");
    else if constexpr (N == 12) asm volatile("s_waitcnt vmcnt(12)" ::: "memory");
}

template <typename VT> struct FragT;
template <> struct FragT<_Float16> { using type = f16x8; };
template <> struct FragT<__hip_bfloat16> { using type = s16x8; };

// ---------------------------------------------------------------- GEMM ----
// C[M,N] = A[M,K] * B^T (B stored [N,K], k-contiguous). BK=32 (CK=4 chunks).
// global_load_lds (16B) staging, double-buffered, depth-2 counted-vmcnt
// pipeline (depth-3 measured null in R13). XOR chunk-swizzle cs = c^((r>>1)&3)
// on BOTH source and read.
// SPLIT: (hi, lo*1024) f16 pairs, cross terms in acc2, v = acc1+acc2/1024.
// GU: dual-B (gate/up), epilogue silu(g)*u -> bf16.  BN: 64 or 128.
// XSWZ: XCD-chunked M-ordering (A-panel slice stays L2-resident per XCD).
// Launch bounds REGISTER-AWARE (R10 lesson: forcing 3 waves/EU on the
// ~224-reg dual-accumulator GU spilled accumulators -> WRITE 48->213 MB, 2x).
// epi=6 (QKV+RoPE+V-transpose fusion): tile -> LDS (stride 65), Q/K threads
// read rotate-half partner (cl^32) + cos/sin + hi/lo split; V blocks write
// the tile TRANSPOSED (hi/lo split) straight to vT.
struct GemmP {
    const void *Ah, *Al;
    const void *Bh, *Bl, *Bh2;
    long lda, ldb, bExp, K;
    const int *poff, *gidx;
    const float *bias, *resid, *bw;   // epi6: resid=cos table, bw=sin table
    float *outF, *outF2;
    __hip_bfloat16 *outBF;
    _Float16 *rQh, *rQl, *rKh, *rKl;  // epi6 outputs
    _Float16 *rVh, *rVl;              // epi6 transposed V outputs
    long ldc;
    int epi; // 0:+bias->f32  2:+resid->f32(dual)  5:scaled scatter-store  6:rope-split
};

template <typename VT, bool SPLIT, bool GATHER, bool GU, int BN, bool XSWZ = false>
__global__ __launch_bounds__(256, SPLIT ? 3 : ((GU && BN == 128) ? 2 : 4)) void gemm_k(GemmP p) {
    constexpr int BM = 128;
    constexpr int NJ = BN / 32;
    constexpr bool HAS2 = SPLIT || GU;
    constexpr int ACH = SPLIT ? 1024 : 512;   // A-region chunks (16B)
    constexpr int BCH = BN * 4;               // chunks per B matrix
    constexpr int NB = HAS2 ? 2 : 1;
    constexpr int TOT = ACH + NB * BCH;
    constexpr int NCH = TOT / 256;            // chunks staged per thread
    constexpr int BUFVT = TOT * 8;
    constexpr int AOFF2 = 4096;               // Al (SPLIT)
    constexpr int BOFF = ACH * 8;
    constexpr int B2OFF = (ACH + BCH) * 8;
    __shared__ __align__(16) VT s[2][BUFVT];
    const int tid = threadIdx.x, lane = tid & 63;
    const int wid = tid >> 6, wm = wid >> 1, wn = wid & 1;
    const int x = lane & 15, hi = lane >> 4;
    int mb = (int)blockIdx.x;
    if constexpr (XSWZ) mb = (mb & 7) * ((int)gridDim.x >> 3) + (mb >> 3);
    long m0 = (long)mb * BM, n0 = (long)blockIdx.y * BN;
    int e = 0;
    if (p.poff) {
        int tot = p.poff[Ec];
        if (m0 >= tot) return;
        while (m0 >= p.poff[e + 1]) ++e;
    }

    const VT *gs[NCH];
    int chd[NCH];
#pragma unroll
    for (int i = 0; i < NCH; ++i) {
        int ch = tid + i * 256;
        chd[i] = ch;
        if (ch < ACH) {
            int slab = ch >> 9, local = ch & 511;
            int r = local >> 2, c = local & 3;
            int cs = c ^ ((r >> 1) & 3);
            long ar = m0 + r;
            if (GATHER) ar = p.gidx[ar];
            const VT *mat = (SPLIT && slab == 1) ? (const VT *)p.Al : (const VT *)p.Ah;
            gs[i] = mat + ar * p.lda + cs * 8;
        } else {
            int idx = ch - ACH;
            int which = idx / BCH, local = idx % BCH;
            int r = local >> 2, c = local & 3;
            int cs = c ^ ((r >> 1) & 3);
            const VT *bmat = (which == 0) ? (const VT *)p.Bh
                           : (SPLIT ? (const VT *)p.Bl : (const VT *)p.Bh2);
            gs[i] = bmat + (long)e * p.bExp + (n0 + r) * p.ldb + cs * 8;
        }
    }

    f32x4 acc[4][NJ];
    f32x4 acc2[HAS2 ? 4 : 1][HAS2 ? NJ : 1];
#pragma unroll
    for (int i = 0; i < 4; ++i)
#pragma unroll
        for (int j = 0; j < NJ; ++j) {
            acc[i][j] = (f32x4){0.f, 0.f, 0.f, 0.f};
            if constexpr (HAS2) acc2[i][j] = (f32x4){0.f, 0.f, 0.f, 0.f};
        }

    using F8 = typename FragT<VT>::type;
    const int KT = (int)(p.K / 32);
    auto stageTo = [&](int kt, int b) {
#pragma unroll
        for (int i = 0; i < NCH; ++i)
            gll16(gs[i] + (long)kt * 32, &s[b][(size_t)chd[i] * 8]);
    };

    stageTo(0, 0);
    if (KT > 1) stageTo(1, 1);

    for (int kt = 0; kt < KT; ++kt) {
        if (kt + 1 < KT) wait_vm<NCH>();
        else wait_vm<0>();
        __builtin_amdgcn_sched_barrier(0);
        __builtin_amdgcn_s_barrier();
        __builtin_amdgcn_sched_barrier(0);
        const int cur = kt & 1;

        F8 afh[4], afl[SPLIT ? 4 : 1];
#pragma unroll
        for (int mi = 0; mi < 4; ++mi) {
            int ar = wm * 64 + mi * 16 + x;
            int ad = (ar * 4 + (hi ^ ((ar >> 1) & 3))) * 8;
            afh[mi] = *(const F8 *)&s[cur][ad];
            if constexpr (SPLIT) afl[mi] = *(const F8 *)&s[cur][AOFF2 + ad];
        }
        __builtin_amdgcn_s_setprio(1);
#pragma unroll
        for (int nj = 0; nj < NJ; ++nj) {
            int br = wn * (BN / 2) + nj * 16 + x;
            int bd = (br * 4 + (hi ^ ((br >> 1) & 3))) * 8;
            F8 bfh = *(const F8 *)&s[cur][BOFF + bd];
            F8 bf2;
            if constexpr (HAS2) bf2 = *(const F8 *)&s[cur][B2OFF + bd];
#pragma unroll
            for (int mi = 0; mi < 4; ++mi) {
                acc[mi][nj] = mfma16(afh[mi], bfh, acc[mi][nj]);
                if constexpr (SPLIT) {
                    acc2[mi][nj] = mfma16(afh[mi], bf2, acc2[mi][nj]);
                    acc2[mi][nj] = mfma16(afl[mi], bfh, acc2[mi][nj]);
                }
                if constexpr (GU) acc2[mi][nj] = mfma16(afh[mi], bf2, acc2[mi][nj]);
            }
        }
        __builtin_amdgcn_s_setprio(0);

        asm volatile("s_waitcnt lgkmcnt(0)" ::: "memory");
        __builtin_amdgcn_sched_barrier(0);
        __builtin_amdgcn_s_barrier();
        __builtin_amdgcn_sched_barrier(0);
        if (kt + 2 < KT) stageTo(kt + 2, cur);
    }

    if (SPLIT && p.epi == 6) {
        // fused RoPE epilogue: combine+bias -> LDS (stride 65)
        float *sEpi = (float *)&s[0][0];   // 128x65 f32 = 33.3KB <= 48KB
#pragma unroll
        for (int mi = 0; mi < 4; ++mi)
#pragma unroll
            for (int nj = 0; nj < NJ; ++nj)
#pragma unroll
                for (int r = 0; r < 4; ++r) {
                    int rl = wm * 64 + mi * 16 + hi * 4 + r;
                    int cl = wn * (BN / 2) + nj * 16 + x;
                    float v = fmaf(acc2[mi][nj][r], LO_INV, acc[mi][nj][r]) + p.bias[n0 + cl];
                    sEpi[rl * 65 + cl] = v;
                }
        __syncthreads();
        const bool isV = (n0 >= 1280);
        if (isV) {
            // transposed V store: vT[(b*4+kvh)*64 + d][tok], hi/lo split
            const int bIdx = (int)(m0 >> 11);
            const int tok0 = (int)(m0 & (Sc - 1));
            const int kvh = (int)((n0 - 1280) >> 6);
            const long vbase = ((long)(bIdx * 4 + kvh) * 64) * (long)Sc;
#pragma unroll
            for (int it = 0; it < 4; ++it) {
                int idx = tid + it * 256;
                int d = idx >> 4, tch = idx & 15;
                f16x8 oh, ol;
#pragma unroll
                for (int j = 0; j < 8; ++j) {
                    float v = sEpi[(tch * 8 + j) * 65 + d];
                    _Float16 hv = (_Float16)v;
                    oh[j] = hv;
                    ol[j] = (_Float16)((v - (float)hv) * LO_SCALE);
                }
                long orow = vbase + (long)d * Sc + tok0 + tch * 8;
                *(f16x8 *)(p.rVh + orow) = oh;
                *(f16x8 *)(p.rVl + orow) = ol;
            }
        } else {
            const bool isK = (n0 >= 1024);
#pragma unroll
            for (int mi = 0; mi < 4; ++mi)
#pragma unroll
                for (int nj = 0; nj < NJ; ++nj)
#pragma unroll
                    for (int r = 0; r < 4; ++r) {
                        int rl = wm * 64 + mi * 16 + hi * 4 + r;
                        int cl = wn * (BN / 2) + nj * 16 + x;
                        long row = m0 + rl;
                        float xv = sEpi[rl * 65 + cl];
                        int spos = (int)(row & (Sc - 1));
                        float xp = sEpi[rl * 65 + (cl ^ 32)];
                        float cs = p.resid[spos * 64 + cl];
                        float sn = p.bw[spos * 64 + cl];
                        float o = xv * cs + ((cl < 32) ? -xp : xp) * sn;
                        _Float16 hv = (_Float16)o;
                        _Float16 lo = (_Float16)((o - (float)hv) * LO_SCALE);
                        if (isK) {
                            long off = row * 256 + (n0 - 1024) + cl;
                            p.rKh[off] = hv; p.rKl[off] = lo;
                        } else {
                            long off = row * 1024 + n0 + cl;
                            p.rQh[off] = hv; p.rQl[off] = lo;
                        }
                    }
        }
        return;
    }

#pragma unroll
    for (int mi = 0; mi < 4; ++mi)
#pragma unroll
        for (int nj = 0; nj < NJ; ++nj)
#pragma unroll
            for (int r = 0; r < 4; ++r) {
                long row = m0 + wm * 64 + mi * 16 + hi * 4 + r;
                long col = n0 + wn * (BN / 2) + nj * 16 + x;
                float v = acc[mi][nj][r];
                if constexpr (GU) {
                    float u = acc2[mi][nj][r];
                    float he = v / (1.f + __expf(-v)) * u;
                    p.outBF[row * p.ldc + col] = __float2bfloat16(he);
                } else {
                    if constexpr (SPLIT) v = fmaf(acc2[mi][nj][r], LO_INV, v);
                    switch (p.epi) {
                    case 0: p.outF[row * p.ldc + col] = v + p.bias[col]; break;
                    case 2: {
                        float o = v + p.resid[row * p.ldc + col];
                        p.outF[row * p.ldc + col] = o;
                        p.outF2[row * p.ldc + col] = o;
                    } break;
                    case 5: // plain store to per-slot scratch, weight folded
                        p.outF[row * p.ldc + col] = v * p.bw[row];
                        break;
                    }
                }
            }
}

// combine: out[tok] += scat[slot0(tok)] + scat[slot1(tok)]  (coalesced f32x4)
__global__ __launch_bounds__(256) void combine_k(const float *__restrict__ scat,
        const int *__restrict__ tok_slot, float *__restrict__ out) {
    const long tok = blockIdx.x;
    const int c = threadIdx.x * 4;
    const long s0 = tok_slot[tok * 2], s1 = tok_slot[tok * 2 + 1];
    f32x4 a = *(const f32x4 *)(scat + s0 * Dc + c);
    f32x4 b = *(const f32x4 *)(scat + s1 * Dc + c);
    f32x4 o = *(const f32x4 *)(out + tok * Dc + c);
#pragma unroll
    for (int j = 0; j < 4; ++j) o[j] += a[j] + b[j];
    *(f32x4 *)(out + tok * Dc + c) = o;
}

// ----------------------------------------------------- flash attention ----
// Diagonal-paired blocks: block (pairI, bh) processes q-tiles pairI and
// 63-pairI sequentially -> uniform 65 kv-tiles per block (no straggler tail).
// Per segment: 2 waves x 16 q-rows, swapped QK^T (mfma(K,Q)), in-register
// softmax (2 shfl_xor), P to PV A-frag via packed shuffles, K/V staged via
// global_load_lds into swizzled LDS, depth-2 counted-vmcnt pipeline,
// defer-max (THR=8). Outputs ctx hi/lo f16.
__global__ __launch_bounds__(128, 2) void attn_k(
    const _Float16 *__restrict__ qh, const _Float16 *__restrict__ ql,
    const _Float16 *__restrict__ kh, const _Float16 *__restrict__ kl,
    const _Float16 *__restrict__ vTh, const _Float16 *__restrict__ vTl,
    _Float16 *__restrict__ ctxh, _Float16 *__restrict__ ctxl) {
    __shared__ __align__(16) _Float16 kbuf[2][2][32 * 64]; // [dbuf][hi/lo][kv][d]
    __shared__ __align__(16) _Float16 vbuf[2][2][64 * 32]; // [dbuf][hi/lo][d][kv]
    const int tid = threadIdx.x, lane = tid & 63, wid = tid >> 6;
    const int x = lane & 15, hi = lane >> 4;
    const int pairI = blockIdx.x;
    const int bh = blockIdx.y;
    const int b = bh >> 4, h = bh & 15, kvh = h >> 2;
    const long kRow0 = (long)b * Sc * 256;
    const long vRow0 = (long)(b * 4 + kvh) * 64 * (long)Sc;

    auto stage = [&](int kt, int bufI) {
        if (wid == 0) {          // K: [kv32][d64] CK=8, swizzle c^=(kv&7)
#pragma unroll
            for (int ss = 0; ss < 2; ++ss) {
                const _Float16 *src = ss ? kl : kh;
#pragma unroll
                for (int i = 0; i < 4; ++i) {
                    int kv = 8 * i + (lane >> 3);
                    int cd = (lane & 7) ^ (kv & 7);
                    const _Float16 *g = src + kRow0 + ((long)kt * 32 + kv) * 256 + kvh * 64 + cd * 8;
                    gll16(g, &kbuf[bufI][ss][i * 512]);
                }
            }
        } else {                 // V^T: [d64][kv32] CK=4, swizzle c^=((d>>1)&3)
#pragma unroll
            for (int ss = 0; ss < 2; ++ss) {
                const _Float16 *src = ss ? vTl : vTh;
#pragma unroll
                for (int i = 0; i < 4; ++i) {
                    int d = 16 * i + (lane >> 2);
                    int ckv = (lane & 3) ^ ((d >> 1) & 3);
                    const _Float16 *g = src + vRow0 + (long)d * Sc + (long)kt * 32 + ckv * 8;
                    gll16(g, &vbuf[bufI][ss][i * 512]);
                }
            }
        }
    };

    for (int seg = 0; seg < 2; ++seg) {
        const int qt = seg ? (63 - pairI) : pairI;
        const int q0 = qt * 32;
        const long qtokW = (long)b * Sc + q0 + wid * 16;    // wave's 16 q-rows

        f16x8 qfh[2], qfl[2];
#pragma unroll
        for (int ks = 0; ks < 2; ++ks) {
            long off = (qtokW + x) * (long)Dc + h * 64 + ks * 32 + hi * 8;
            qfh[ks] = *(const f16x8 *)(qh + off);
            qfl[ks] = *(const f16x8 *)(ql + off);
        }
        asm volatile("s_waitcnt vmcnt(0)" ::: "memory");
        __builtin_amdgcn_sched_barrier(0);

        f32x4 o1[4], o2[4];
        float mrow = -3.0e38f, lrow = 0.f;
#pragma unroll
        for (int dj = 0; dj < 4; ++dj) {
            o1[dj] = (f32x4){0.f, 0.f, 0.f, 0.f};
            o2[dj] = (f32x4){0.f, 0.f, 0.f, 0.f};
        }

        const int NT = qt + 1;

        stage(0, 0);
        stage(1, 1);

        for (int kt = 0; kt < NT; ++kt) {
            if (kt + 1 < NT) asm volatile("s_waitcnt vmcnt(8)" ::: "memory");
            else asm volatile("s_waitcnt vmcnt(0)" ::: "memory");
            __builtin_amdgcn_sched_barrier(0);
            __builtin_amdgcn_s_barrier();
            __builtin_amdgcn_sched_barrier(0);
            const int cur = kt & 1;

            f32x4 s1[2], s2[2];
#pragma unroll
            for (int kvs = 0; kvs < 2; ++kvs) {
                s1[kvs] = (f32x4){0.f, 0.f, 0.f, 0.f};
                s2[kvs] = (f32x4){0.f, 0.f, 0.f, 0.f};
            }
            __builtin_amdgcn_s_setprio(1);
#pragma unroll
            for (int ks = 0; ks < 2; ++ks)
#pragma unroll
                for (int kvs = 0; kvs < 2; ++kvs) {
                    int row = kvs * 16 + x;
                    int addr = row * 64 + (((ks * 4 + hi) ^ (row & 7)) << 3);
                    f16x8 kfh = *(const f16x8 *)&kbuf[cur][0][addr];
                    f16x8 kfl = *(const f16x8 *)&kbuf[cur][1][addr];
                    s1[kvs] = mfma16(kfh, qfh[ks], s1[kvs]);
                    s2[kvs] = mfma16(kfl, qfh[ks], s2[kvs]);
                    s2[kvs] = mfma16(kfh, qfl[ks], s2[kvs]);
                }
            __builtin_amdgcn_s_setprio(0);

            const bool diag = (kt == NT - 1);
            const int qpos = q0 + wid * 16 + x;
            float sv[2][4];
#pragma unroll
            for (int kvs = 0; kvs < 2; ++kvs)
#pragma unroll
                for (int r = 0; r < 4; ++r) {
                    float v = fmaf(s2[kvs][r], LO_INV, s1[kvs][r]) * 0.125f;
                    if (diag) {
                        int kvpos = kt * 32 + kvs * 16 + 4 * hi + r;
                        if (kvpos > qpos) v = -3.0e38f;
                    }
                    sv[kvs][r] = v;
                }
            float mx = sv[0][0];
#pragma unroll
            for (int kvs = 0; kvs < 2; ++kvs)
#pragma unroll
                for (int r = 0; r < 4; ++r) mx = fmaxf(mx, sv[kvs][r]);
            mx = fmaxf(mx, __shfl_xor(mx, 16));
            mx = fmaxf(mx, __shfl_xor(mx, 32));
            if (!__all(mx - mrow <= 8.0f)) {
                float mnew = fmaxf(mrow, mx);
                float scl = __expf(mrow - mnew);
                mrow = mnew;
                lrow *= scl;
                float sclr[4];
#pragma unroll
                for (int r = 0; r < 4; ++r) sclr[r] = __shfl(scl, 4 * hi + r);
#pragma unroll
                for (int dj = 0; dj < 4; ++dj)
#pragma unroll
                    for (int r = 0; r < 4; ++r) {
                        o1[dj][r] *= sclr[r];
                        o2[dj][r] *= sclr[r];
                    }
            }
            float pv[2][4];
            float ls = 0.f;
#pragma unroll
            for (int kvs = 0; kvs < 2; ++kvs)
#pragma unroll
                for (int r = 0; r < 4; ++r) {
                    pv[kvs][r] = __expf(sv[kvs][r] - mrow);
                    ls += pv[kvs][r];
                }
            ls += __shfl_xor(ls, 16);
            ls += __shfl_xor(ls, 32);
            lrow += ls;
            u32 Bh0[2], Bh1[2], Bl0[2], Bl1[2];
#pragma unroll
            for (int pr = 0; pr < 2; ++pr) {
                _Float16 a0 = (_Float16)pv[0][2 * pr], a1 = (_Float16)pv[0][2 * pr + 1];
                _Float16 b0 = (_Float16)pv[1][2 * pr], b1 = (_Float16)pv[1][2 * pr + 1];
                Bh0[pr] = pack2(a0, a1);
                Bh1[pr] = pack2(b0, b1);
                _Float16 la0 = (_Float16)((pv[0][2 * pr] - (float)a0) * LO_SCALE);
                _Float16 la1 = (_Float16)((pv[0][2 * pr + 1] - (float)a1) * LO_SCALE);
                _Float16 lb0 = (_Float16)((pv[1][2 * pr] - (float)b0) * LO_SCALE);
                _Float16 lb1 = (_Float16)((pv[1][2 * pr + 1] - (float)b1) * LO_SCALE);
                Bl0[pr] = pack2(la0, la1);
                Bl1[pr] = pack2(lb0, lb1);
            }
            const int srcLow = x + ((lane & 16) ? 32 : 0);
            const int srcHigh = srcLow + 16;
            const bool useB1 = lane >= 32;
            union { u32 u[4]; f16x8 v; } fh, fl;
#pragma unroll
            for (int pr = 0; pr < 2; ++pr) {
                u32 t0 = (u32)__shfl((int)Bh0[pr], srcLow);
                u32 t1 = (u32)__shfl((int)Bh1[pr], srcLow);
                fh.u[pr] = useB1 ? t1 : t0;
                u32 u0 = (u32)__shfl((int)Bh0[pr], srcHigh);
                u32 u1 = (u32)__shfl((int)Bh1[pr], srcHigh);
                fh.u[2 + pr] = useB1 ? u1 : u0;
                u32 s0 = (u32)__shfl((int)Bl0[pr], srcLow);
                u32 s1v = (u32)__shfl((int)Bl1[pr], srcLow);
                fl.u[pr] = useB1 ? s1v : s0;
                u32 w0 = (u32)__shfl((int)Bl0[pr], srcHigh);
                u32 w1 = (u32)__shfl((int)Bl1[pr], srcHigh);
                fl.u[2 + pr] = useB1 ? w1 : w0;
            }
            f16x8 pah = fh.v, pal = fl.v;

            __builtin_amdgcn_s_setprio(1);
#pragma unroll
            for (int dj = 0; dj < 4; ++dj) {
                int d = dj * 16 + x;
                int addr = d * 32 + ((hi ^ ((d >> 1) & 3)) << 3);
                f16x8 vhf = *(const f16x8 *)&vbuf[cur][0][addr];
                f16x8 vlf = *(const f16x8 *)&vbuf[cur][1][addr];
                o1[dj] = mfma16(pah, vhf, o1[dj]);
                o2[dj] = mfma16(pah, vlf, o2[dj]);
                o2[dj] = mfma16(pal, vhf, o2[dj]);
            }
            __builtin_amdgcn_s_setprio(0);

            asm volatile("s_waitcnt lgkmcnt(0)" ::: "memory");
            __builtin_amdgcn_sched_barrier(0);
            __builtin_amdgcn_s_barrier();
            __builtin_amdgcn_sched_barrier(0);
            if (kt + 2 < NT) stage(kt + 2, cur);
        }

        float linv = 1.0f / lrow;
        float lr[4];
#pragma unroll
        for (int r = 0; r < 4; ++r) lr[r] = __shfl(linv, 4 * hi + r);
#pragma unroll
        for (int dj = 0; dj < 4; ++dj)
#pragma unroll
            for (int r = 0; r < 4; ++r) {
                long tok = qtokW + 4 * hi + r;
                float ov = fmaf(o2[dj][r], LO_INV, o1[dj][r]) * lr[r];
                _Float16 hv = (_Float16)ov;
                long off = tok * Dc + h * 64 + dj * 16 + x;
                ctxh[off] = hv;
                ctxl[off] = (_Float16)((ov - (float)hv) * LO_SCALE);
            }
    }
}

// ------------------------------------------------------- small kernels ----
__global__ __launch_bounds__(256) void rmsnorm_split_k(const float *__restrict__ x,
        const float *__restrict__ w, _Float16 *__restrict__ oh, _Float16 *__restrict__ ol) {
    const long row = blockIdx.x;
    const int tid = threadIdx.x, lane = tid & 63, wid = tid >> 6;
    f32x4 v = *(const f32x4 *)(x + row * Dc + tid * 4);
    float ss = v[0] * v[0] + v[1] * v[1] + v[2] * v[2] + v[3] * v[3];
#pragma unroll
    for (int off = 1; off < 64; off <<= 1) ss += __shfl_xor(ss, off);
    __shared__ float sw[4];
    if (lane == 0) sw[wid] = ss;
    __syncthreads();
    float inv = 1.0f / sqrtf((sw[0] + sw[1] + sw[2] + sw[3]) * (1.f / Dc) + 1e-6f);
#pragma unroll
    for (int j = 0; j < 4; ++j) {
        float y = v[j] * inv * w[tid * 4 + j];
        _Float16 hv = (_Float16)y;
        oh[row * Dc + tid * 4 + j] = hv;
        ol[row * Dc + tid * 4 + j] = (_Float16)((y - (float)hv) * LO_SCALE);
    }
}

// fused RMSNorm (ln2) + router: keeps f32 row in regs (router precision),
// writes only tbf; computes 8 logits, softmax, top-2, counts.
__global__ __launch_bounds__(256) void rmsnorm_router_k(const float *__restrict__ x,
        const float *__restrict__ w, const float *__restrict__ rw,
        __hip_bfloat16 *__restrict__ tb, float *__restrict__ probs,
        int *__restrict__ tok_e, float *__restrict__ tok_w, int *__restrict__ cnt) {
    const long row = blockIdx.x;
    const int tid = threadIdx.x, lane = tid & 63, wid = tid >> 6;
    f32x4 v = *(const f32x4 *)(x + row * Dc + tid * 4);
    float ss = v[0] * v[0] + v[1] * v[1] + v[2] * v[2] + v[3] * v[3];
#pragma unroll
    for (int off = 1; off < 64; off <<= 1) ss += __shfl_xor(ss, off);
    __shared__ float sw[4];
    __shared__ float part[4][8];
    if (lane == 0) sw[wid] = ss;
    __syncthreads();
    float inv = 1.0f / sqrtf((sw[0] + sw[1] + sw[2] + sw[3]) * (1.f / Dc) + 1e-6f);
    float y[4];
#pragma unroll
    for (int j = 0; j < 4; ++j) {
        y[j] = v[j] * inv * w[tid * 4 + j];
        tb[row * Dc + tid * 4 + j] = __float2bfloat16(y[j]);
    }
    float acc[8];
#pragma unroll
    for (int e = 0; e < 8; ++e) {
        f32x4 wv = *(const f32x4 *)(rw + (long)e * Dc + tid * 4);
        acc[e] = y[0] * wv[0] + y[1] * wv[1] + y[2] * wv[2] + y[3] * wv[3];
    }
#pragma unroll
    for (int off = 1; off < 64; off <<= 1)
#pragma unroll
        for (int e = 0; e < 8; ++e) acc[e] += __shfl_xor(acc[e], off);
    if (lane == 0)
#pragma unroll
        for (int e = 0; e < 8; ++e) part[wid][e] = acc[e];
    __syncthreads();
    if (tid == 0) {
        float lg[8];
        float mx = -3.0e38f;
#pragma unroll
        for (int e = 0; e < 8; ++e) {
            lg[e] = part[0][e] + part[1][e] + part[2][e] + part[3][e];
            mx = fmaxf(mx, lg[e]);
        }
        float ex[8], s = 0.f;
#pragma unroll
        for (int e = 0; e < 8; ++e) { ex[e] = expf(lg[e] - mx); s += ex[e]; }
        float invs = 1.f / s;
        int i1 = -1, i2 = -1;
        float p1v = -1.f, p2v = -1.f;
#pragma unroll
        for (int e = 0; e < 8; ++e) {
            float pe = ex[e] * invs;
            probs[row * 8 + e] = pe;
            if (pe > p1v) { i2 = i1; p2v = p1v; i1 = e; p1v = pe; }
            else if (pe > p2v) { i2 = e; p2v = pe; }
        }
        float wsum = p1v + p2v;
        tok_e[row * 2] = i1; tok_e[row * 2 + 1] = i2;
        tok_w[row * 2] = p1v / wsum; tok_w[row * 2 + 1] = p2v / wsum;
        atomicAdd(&cnt[i1], 1);
        atomicAdd(&cnt[i2], 1);
    }
}

__global__ void pack_qkvw_k(const float *__restrict__ qw, const float *__restrict__ kw,
        const float *__restrict__ vw, _Float16 *wh, _Float16 *wl) {
    const long n = (long)QKVN * Dc;
    for (long i = (long)blockIdx.x * 256 + threadIdx.x; i < n; i += (long)gridDim.x * 256) {
        long o = i >> 10;
        int d = (int)(i & 1023);
        float v;
        if (o < 1024) v = qw[o * 1024 + d];
        else if (o < 1280) v = kw[(o - 1024) * 1024 + d];
        else v = vw[(o - 1280) * 1024 + d];
        _Float16 h = (_Float16)v;
        wh[i] = h;
        wl[i] = (_Float16)((v - (float)h) * LO_SCALE);
    }
}

__global__ void split_f16_k(const float *__restrict__ x, _Float16 *hi, _Float16 *lo, long n) {
    for (long i = (long)blockIdx.x * 256 + threadIdx.x; i < n; i += (long)gridDim.x * 256) {
        float v = x[i];
        _Float16 h = (_Float16)v;
        hi[i] = h;
        lo[i] = (_Float16)((v - (float)h) * LO_SCALE);
    }
}

__global__ void pack_bias_k(const float *qb, const float *kb, const float *vb, float *out) {
    int i = blockIdx.x * 256 + threadIdx.x;
    if (i >= QKVN) return;
    out[i] = (i < 1024) ? qb[i] : (i < 1280) ? kb[i - 1024] : vb[i - 1280];
}

__global__ __launch_bounds__(256) void transpose_bf16_k(const float *__restrict__ in,
        __hip_bfloat16 *__restrict__ out, int R, int C) {
    __shared__ float tile[64 * 65];
    const long eo = (long)blockIdx.z * R * C;
    const int r0 = blockIdx.y * 64, c0 = blockIdx.x * 64;
#pragma unroll
    for (int i = 0; i < 16; ++i) {
        int idx = threadIdx.x + i * 256;
        int r = idx >> 6, c = idx & 63;
        tile[r * 65 + c] = in[eo + (long)(r0 + r) * C + (c0 + c)];
    }
    __syncthreads();
#pragma unroll
    for (int i = 0; i < 16; ++i) {
        int idx = threadIdx.x + i * 256;
        int cc = idx >> 6, rr = idx & 63;
        out[eo + (long)(c0 + cc) * R + (r0 + rr)] = __float2bfloat16(tile[rr * 65 + cc]);
    }
}

__global__ __launch_bounds__(1024) void router_p2_k(const int *cnt, const float *probs,
        int *poff, float *aux_out) {
    __shared__ float sd[1024];
    const int tid = threadIdx.x;
    const int e = tid & 7, rs = tid >> 3;
    float s = 0.f;
    for (int r = rs; r < Tc; r += 128) s += probs[(long)r * 8 + e];
    sd[tid] = s;
    __syncthreads();
    for (int st = 64; st >= 1; st >>= 1) {
        if (rs < st) sd[tid] += sd[tid + st * 8];
        __syncthreads();
    }
    if (tid == 0) {
        float a = 0.f;
        for (int ee = 0; ee < 8; ++ee) {
            float m = sd[ee] * (1.f / Tc);
            a += m * m;
        }
        aux_out[0] = a;
        int o = 0;
        poff[0] = 0;
        for (int ee = 0; ee < 8; ++ee) { o += (cnt[ee] + 127) & ~127; poff[ee + 1] = o; }
    }
}

__global__ void router_p3_k(const int *tok_e, const float *tok_w, const int *poff,
        int *cursor, int *btok, float *bw, int *tok_slot) {
    long tok = (long)blockIdx.x * 256 + threadIdx.x;
    if (tok >= Tc) return;
#pragma unroll
    for (int j = 0; j < 2; ++j) {
        int e = tok_e[tok * 2 + j];
        int slot = atomicAdd(&cursor[e], 1);
        btok[poff[e] + slot] = (int)tok;
        bw[poff[e] + slot] = tok_w[tok * 2 + j];
        tok_slot[tok * 2 + j] = poff[e] + slot;
    }
}

__global__ void router_p4_k(const int *poff, const int *cnt, int *btok, float *bw) {
    int s = blockIdx.x * 256 + threadIdx.x;
    if (s >= poff[8]) return;
    int e = 0;
    while (s >= poff[e + 1]) ++e;
    if (s - poff[e] >= cnt[e]) { btok[s] = 0; bw[s] = 0.f; }
}

// -------------------------------------------------------------- launch ----
extern "C" void kernel_launch(void *const *d_in, const int *in_sizes, int n_in,
                              void *d_out, int out_size, void *d_ws, size_t ws_size,
                              hipStream_t stream) {
    (void)in_sizes; (void)n_in;
    const float *hidden = (const float *)d_in[0];
    const float *ln1 = (const float *)d_in[1];
    const float *ln2 = (const float *)d_in[2];
    const float *qw = (const float *)d_in[3];
    const float *qb = (const float *)d_in[4];
    const float *kw = (const float *)d_in[5];
    const float *kb = (const float *)d_in[6];
    const float *vw = (const float *)d_in[7];
    const float *vb = (const float *)d_in[8];
    const float *ow = (const float *)d_in[9];
    const float *rw = (const float *)d_in[10];
    const float *gw = (const float *)d_in[11];
    const float *uw = (const float *)d_in[12];
    const float *dwn = (const float *)d_in[13];
    const float *cosb = (const float *)d_in[14];
    const float *sinb = (const float *)d_in[15];
    float *outx = (float *)d_out;

    char *base = (char *)d_ws;
    size_t off = 0;
    auto alloc = [&](size_t bytes) -> char * {
        char *p = base + off;
        off += (bytes + 255) & ~(size_t)255;
        return p;
    };
    _Float16 *qkvwh = (_Float16 *)alloc((size_t)QKVN * Dc * 2);
    _Float16 *qkvwl = (_Float16 *)alloc((size_t)QKVN * Dc * 2);
    float *qkvb = (float *)alloc(QKVN * 4);
    _Float16 *owh = (_Float16 *)alloc((size_t)Dc * Dc * 2);
    _Float16 *owl = (_Float16 *)alloc((size_t)Dc * Dc * 2);
    __hip_bfloat16 *gateT = (__hip_bfloat16 *)alloc((size_t)Ec * Fc * Dc * 2);
    __hip_bfloat16 *upT = (__hip_bfloat16 *)alloc((size_t)Ec * Fc * Dc * 2);
    __hip_bfloat16 *downT = (__hip_bfloat16 *)alloc((size_t)Ec * Dc * Fc * 2);
    // U2..vTl span (~40 MB) is dead by down-GEMM time; scat (36 MB) aliases it
    char *U2 = alloc((size_t)Tc * Dc * 4);
    _Float16 *hh = (_Float16 *)U2;
    _Float16 *hl = hh + (size_t)Tc * Dc;
    char *U3 = alloc((size_t)Tc * Dc * 4);
    _Float16 *qhb = (_Float16 *)U3;
    _Float16 *qlb = qhb + (size_t)Tc * Dc;
    float *x1 = (float *)U3;
    _Float16 *khb = (_Float16 *)alloc((size_t)Tc * 256 * 2);
    _Float16 *klb = (_Float16 *)alloc((size_t)Tc * 256 * 2);
    _Float16 *vTh = (_Float16 *)alloc((size_t)Tc * 256 * 2);
    _Float16 *vTl = (_Float16 *)alloc((size_t)Tc * 256 * 2);
    float *scat = (float *)U2;   // CAP*Dc*4 = 36 MB <= U2..vTl span (~40 MB)
    _Float16 *ctxh = (_Float16 *)alloc((size_t)Tc * Dc * 2);
    _Float16 *ctxl = (_Float16 *)alloc((size_t)Tc * Dc * 2);
    __hip_bfloat16 *tbf = (__hip_bfloat16 *)alloc((size_t)Tc * Dc * 2);
    float *probs = (float *)alloc((size_t)Tc * 8 * 4);
    int *tok_e = (int *)alloc((size_t)Tc * 2 * 4);
    float *tok_w = (float *)alloc((size_t)Tc * 2 * 4);
    int *tok_slot = (int *)alloc((size_t)Tc * 2 * 4);
    int *cnt = (int *)alloc(256);
    int *cursor = cnt + 8;
    int *poff = (int *)alloc(256);
    int *btok = (int *)alloc((size_t)CAP * 4);
    float *bwgt = (float *)alloc((size_t)CAP * 4);
    __hip_bfloat16 *gbuf = (__hip_bfloat16 *)alloc((size_t)CAP * Fc * 2);

    if (off > ws_size) {
        hipMemsetAsync(d_out, 0, (size_t)out_size * 4, stream);
        return;
    }

    hipMemsetAsync(cnt, 0, 64, stream);
    pack_qkvw_k<<<1024, 256, 0, stream>>>(qw, kw, vw, qkvwh, qkvwl);
    pack_bias_k<<<(QKVN + 255) / 256, 256, 0, stream>>>(qb, kb, vb, qkvb);
    split_f16_k<<<1024, 256, 0, stream>>>(ow, owh, owl, (long)Dc * Dc);
    transpose_bf16_k<<<dim3(Fc / 64, Dc / 64, Ec), 256, 0, stream>>>(gw, gateT, Dc, Fc);
    transpose_bf16_k<<<dim3(Fc / 64, Dc / 64, Ec), 256, 0, stream>>>(uw, upT, Dc, Fc);
    transpose_bf16_k<<<dim3(Dc / 64, Fc / 64, Ec), 256, 0, stream>>>(dwn, downT, Fc, Dc);
    rmsnorm_split_k<<<Tc, 256, 0, stream>>>(hidden, ln1, hh, hl);

    // QKV GEMM with fused RoPE + V-transpose epilogue (epi=6)
    GemmP g{};
    g.Ah = hh; g.Al = hl; g.Bh = qkvwh; g.Bl = qkvwl;
    g.lda = Dc; g.ldb = Dc; g.bExp = 0; g.K = Dc;
    g.bias = qkvb; g.resid = cosb; g.bw = sinb;
    g.rQh = qhb; g.rQl = qlb; g.rKh = khb; g.rKl = klb; g.rVh = vTh; g.rVl = vTl;
    g.ldc = QKVN; g.epi = 6;
    gemm_k<_Float16, true, false, false, 64><<<dim3(Tc / 128, QKVN / 64), 256, 0, stream>>>(g);

    attn_k<<<dim3(Sc / 64, Bc * Hc), 128, 0, stream>>>(qhb, qlb, khb, klb, vTh, vTl, ctxh, ctxl);

    GemmP go{};
    go.Ah = ctxh; go.Al = ctxl; go.Bh = owh; go.Bl = owl;
    go.lda = Dc; go.ldb = Dc; go.bExp = 0; go.K = Dc;
    go.resid = hidden; go.outF = x1; go.outF2 = outx; go.ldc = Dc; go.epi = 2;
    gemm_k<_Float16, true, false, false, 64><<<dim3(Tc / 128, Dc / 64), 256, 0, stream>>>(go);

    // fused RMSNorm(ln2) + router logits/softmax/top-2
    rmsnorm_router_k<<<Tc, 256, 0, stream>>>(x1, ln2, rw, tbf, probs, tok_e, tok_w, cnt);
    router_p2_k<<<1, 1024, 0, stream>>>(cnt, probs, poff, outx + (long)Tc * Dc);
    router_p3_k<<<Tc / 256, 256, 0, stream>>>(tok_e, tok_w, poff, cursor, btok, bwgt, tok_slot);
    router_p4_k<<<CAP / 256, 256, 0, stream>>>(poff, cnt, btok, bwgt);

    // fused gate+up: silu(t@gate)*(t@up) -> gbuf, XCD-chunked M, depth-2
    GemmP gg{};
    gg.Ah = tbf; gg.Bh = gateT; gg.Bh2 = upT;
    gg.lda = Dc; gg.ldb = Dc; gg.bExp = (long)Fc * Dc; gg.K = Dc;
    gg.poff = poff; gg.gidx = btok; gg.outBF = gbuf; gg.ldc = Fc;
    gemm_k<__hip_bfloat16, false, true, true, 128, true><<<dim3(CAP / 128, Fc / 128), 256, 0, stream>>>(gg);

    // down: BN=128, weighted store to per-slot scratch, XCD-chunked M, depth-2
    GemmP gd{};
    gd.Ah = gbuf; gd.Bh = downT;
    gd.lda = Fc; gd.ldb = Fc; gd.bExp = (long)Dc * Fc; gd.K = Fc;
    gd.poff = poff; gd.bw = bwgt;
    gd.outF = scat; gd.ldc = Dc; gd.epi = 5;
    gemm_k<__hip_bfloat16, false, false, false, 128, true><<<dim3(CAP / 128, Dc / 128), 256, 0, stream>>>(gd);

    // combine: outx[tok] += scat[slot0] + scat[slot1]
    combine_k<<<Tc, 256, 0, stream>>>(scat, tok_slot, outx);
}

// Round 15
// 674.220 us; speedup vs baseline: 1.2487x; 1.0042x over previous
//
#include <hip/hip_runtime.h>
#include <hip/hip_bf16.h>

#define DEVI __device__ __forceinline__

typedef float f32x4 __attribute__((ext_vector_type(4)));
typedef _Float16 f16x8 __attribute__((ext_vector_type(8)));
typedef short s16x8 __attribute__((ext_vector_type(8)));
typedef unsigned int u32;

constexpr int Bc = 2, Sc = 2048, Dc = 1024, Hc = 16, KVc = 4, HDc = 64, Fc = 2816, Ec = 8;
constexpr int Tc = Bc * Sc;                 // 4096 tokens
constexpr int QKVN = Hc * HDc + 2 * KVc * HDc; // 1536
constexpr int CAP = Tc * 2 + Ec * 128;      // 9216 padded expert-token slots
constexpr float LO_SCALE = 1024.0f;
constexpr float LO_INV = 1.0f / 1024.0f;

DEVI f32x4 mfma16(f16x8 a, f16x8 b, f32x4 c) {
    return __builtin_amdgcn_mfma_f32_16x16x32_f16(a, b, c, 0, 0, 0);
}
DEVI f32x4 mfma16(s16x8 a, s16x8 b, f32x4 c) {
    return __builtin_amdgcn_mfma_f32_16x16x32_bf16(a, b, c, 0, 0, 0);
}

DEVI void gll16(const void *g, void *l) {
    __builtin_amdgcn_global_load_lds(
        (const __attribute__((address_space(1))) u32 *)g,
        (__attribute__((address_space(3))) u32 *)l, 16, 0, 0);
}

DEVI u32 pack2(_Float16 a, _Float16 b) {
    union { _Float16 h[2]; u32 u; } t;
    t.h[0] = a; t.h[1] = b;
    return t.u;
}

template <int N> DEVI void wait_vm() {
    if constexpr (N == 0) asm volatile("s_waitcnt vmcnt(0)" ::: "memory");
    else if constexpr (N == 4) asm volatile("s_waitcnt vmcnt(4)" ::: "memory");
    else if constexpr (N == 6) asm volatile("s_waitcnt vmcnt(6)" ::: "memory");
    else if constexpr (N == 8) asm volatile("s_waitcnt vmcnt(8)" ::: "memory");
    else if constexpr (N == 12) asm volatile("s_waitcnt vmcnt(12)" ::: "memory");
}

template <typename VT> struct FragT;
template <> struct FragT<_Float16> { using type = f16x8; };
template <> struct FragT<__hip_bfloat16> { using type = s16x8; };

// ---------------------------------------------------------------- GEMM ----
// C[M,N] = A[M,K] * B^T (B stored [N,K], k-contiguous). BK=32 (CK=4 chunks).
// global_load_lds (16B) staging. XOR chunk-swizzle cs = c^((r>>1)&3) on BOTH
// source and read.
// NBUF=2: classic double-buffer, 2 barriers/K-tile (stage after 2nd barrier).
// NBUF=3: SINGLE-barrier triple-buffer — stage(kt+2) issued right after the
//   top barrier into the buffer all waves finished reading at iter kt-1;
//   overwrite of any buffer is guarded by the next top barrier (2 iters
//   later). 1 barrier/K-tile + loads get ~2 compute phases of slack.
//   (R13's depth-3 with stage-late + 2 barriers was measured null — the
//   schedule, not the buffer count, is the lever.)
// SPLIT: (hi, lo*1024) f16 pairs, cross terms in acc2, v = acc1+acc2/1024.
// GU: dual-B (gate/up), epilogue silu(g)*u -> bf16.  BN: 64 or 128.
// XSWZ: XCD-chunked M-ordering (A-panel slice stays L2-resident per XCD).
// Launch bounds REGISTER-AWARE (R10: forcing 3 waves/EU on ~224-reg dual-acc
// GU spilled accumulators -> WRITE 48->213 MB, 2x duration).
// epi=6 (QKV+RoPE+V-transpose fusion).
struct GemmP {
    const void *Ah, *Al;
    const void *Bh, *Bl, *Bh2;
    long lda, ldb, bExp, K;
    const int *poff, *gidx;
    const float *bias, *resid, *bw;   // epi6: resid=cos table, bw=sin table
    float *outF, *outF2;
    __hip_bfloat16 *outBF;
    _Float16 *rQh, *rQl, *rKh, *rKl;  // epi6 outputs
    _Float16 *rVh, *rVl;              // epi6 transposed V outputs
    long ldc;
    int epi; // 0:+bias->f32  2:+resid->f32(dual)  5:scaled scatter-store  6:rope-split
};

template <typename VT, bool SPLIT, bool GATHER, bool GU, int BN, bool XSWZ = false, int NBUF = 2>
__global__ __launch_bounds__(256, SPLIT ? 3 : ((GU && BN == 128) ? 2 : ((NBUF == 3) ? 3 : 4))) void gemm_k(GemmP p) {
    constexpr int BM = 128;
    constexpr int NJ = BN / 32;
    constexpr bool HAS2 = SPLIT || GU;
    constexpr int ACH = SPLIT ? 1024 : 512;   // A-region chunks (16B)
    constexpr int BCH = BN * 4;               // chunks per B matrix
    constexpr int NB = HAS2 ? 2 : 1;
    constexpr int TOT = ACH + NB * BCH;
    constexpr int NCH = TOT / 256;            // chunks staged per thread
    constexpr int BUFVT = TOT * 8;
    constexpr int AOFF2 = 4096;               // Al (SPLIT)
    constexpr int BOFF = ACH * 8;
    constexpr int B2OFF = (ACH + BCH) * 8;
    __shared__ __align__(16) VT s[NBUF][BUFVT];
    const int tid = threadIdx.x, lane = tid & 63;
    const int wid = tid >> 6, wm = wid >> 1, wn = wid & 1;
    const int x = lane & 15, hi = lane >> 4;
    int mb = (int)blockIdx.x;
    if constexpr (XSWZ) mb = (mb & 7) * ((int)gridDim.x >> 3) + (mb >> 3);
    long m0 = (long)mb * BM, n0 = (long)blockIdx.y * BN;
    int e = 0;
    if (p.poff) {
        int tot = p.poff[Ec];
        if (m0 >= tot) return;
        while (m0 >= p.poff[e + 1]) ++e;
    }

    const VT *gs[NCH];
    int chd[NCH];
#pragma unroll
    for (int i = 0; i < NCH; ++i) {
        int ch = tid + i * 256;
        chd[i] = ch;
        if (ch < ACH) {
            int slab = ch >> 9, local = ch & 511;
            int r = local >> 2, c = local & 3;
            int cs = c ^ ((r >> 1) & 3);
            long ar = m0 + r;
            if (GATHER) ar = p.gidx[ar];
            const VT *mat = (SPLIT && slab == 1) ? (const VT *)p.Al : (const VT *)p.Ah;
            gs[i] = mat + ar * p.lda + cs * 8;
        } else {
            int idx = ch - ACH;
            int which = idx / BCH, local = idx % BCH;
            int r = local >> 2, c = local & 3;
            int cs = c ^ ((r >> 1) & 3);
            const VT *bmat = (which == 0) ? (const VT *)p.Bh
                           : (SPLIT ? (const VT *)p.Bl : (const VT *)p.Bh2);
            gs[i] = bmat + (long)e * p.bExp + (n0 + r) * p.ldb + cs * 8;
        }
    }

    f32x4 acc[4][NJ];
    f32x4 acc2[HAS2 ? 4 : 1][HAS2 ? NJ : 1];
#pragma unroll
    for (int i = 0; i < 4; ++i)
#pragma unroll
        for (int j = 0; j < NJ; ++j) {
            acc[i][j] = (f32x4){0.f, 0.f, 0.f, 0.f};
            if constexpr (HAS2) acc2[i][j] = (f32x4){0.f, 0.f, 0.f, 0.f};
        }

    using F8 = typename FragT<VT>::type;
    const int KT = (int)(p.K / 32);
    auto stageTo = [&](int kt, int b) {
#pragma unroll
        for (int i = 0; i < NCH; ++i)
            gll16(gs[i] + (long)kt * 32, &s[b][(size_t)chd[i] * 8]);
    };

    auto compute = [&](int cur) {
        F8 afh[4], afl[SPLIT ? 4 : 1];
#pragma unroll
        for (int mi = 0; mi < 4; ++mi) {
            int ar = wm * 64 + mi * 16 + x;
            int ad = (ar * 4 + (hi ^ ((ar >> 1) & 3))) * 8;
            afh[mi] = *(const F8 *)&s[cur][ad];
            if constexpr (SPLIT) afl[mi] = *(const F8 *)&s[cur][AOFF2 + ad];
        }
        __builtin_amdgcn_s_setprio(1);
#pragma unroll
        for (int nj = 0; nj < NJ; ++nj) {
            int br = wn * (BN / 2) + nj * 16 + x;
            int bd = (br * 4 + (hi ^ ((br >> 1) & 3))) * 8;
            F8 bfh = *(const F8 *)&s[cur][BOFF + bd];
            F8 bf2;
            if constexpr (HAS2) bf2 = *(const F8 *)&s[cur][B2OFF + bd];
#pragma unroll
            for (int mi = 0; mi < 4; ++mi) {
                acc[mi][nj] = mfma16(afh[mi], bfh, acc[mi][nj]);
                if constexpr (SPLIT) {
                    acc2[mi][nj] = mfma16(afh[mi], bf2, acc2[mi][nj]);
                    acc2[mi][nj] = mfma16(afl[mi], bfh, acc2[mi][nj]);
                }
                if constexpr (GU) acc2[mi][nj] = mfma16(afh[mi], bf2, acc2[mi][nj]);
            }
        }
        __builtin_amdgcn_s_setprio(0);
    };

    if constexpr (NBUF == 3) {
        // single-barrier triple-buffer schedule
        stageTo(0, 0);
        if (KT > 1) stageTo(1, 1);
        int cur = 0;
        for (int kt = 0; kt < KT; ++kt) {
            if (kt + 1 < KT) wait_vm<NCH>();
            else wait_vm<0>();
            __builtin_amdgcn_sched_barrier(0);
            __builtin_amdgcn_s_barrier();
            __builtin_amdgcn_sched_barrier(0);
            if (kt + 2 < KT) stageTo(kt + 2, (cur + 2) % 3);
            compute(cur);
            cur = (cur + 1 == 3) ? 0 : cur + 1;
        }
        asm volatile("s_waitcnt lgkmcnt(0)" ::: "memory");
        __builtin_amdgcn_s_barrier();
    } else {
        stageTo(0, 0);
        if (KT > 1) stageTo(1, 1);
        for (int kt = 0; kt < KT; ++kt) {
            if (kt + 1 < KT) wait_vm<NCH>();
            else wait_vm<0>();
            __builtin_amdgcn_sched_barrier(0);
            __builtin_amdgcn_s_barrier();
            __builtin_amdgcn_sched_barrier(0);
            const int cur = kt & 1;
            compute(cur);
            asm volatile("s_waitcnt lgkmcnt(0)" ::: "memory");
            __builtin_amdgcn_sched_barrier(0);
            __builtin_amdgcn_s_barrier();
            __builtin_amdgcn_sched_barrier(0);
            if (kt + 2 < KT) stageTo(kt + 2, cur);
        }
    }

    if (SPLIT && p.epi == 6) {
        // fused RoPE epilogue: combine+bias -> LDS (stride 65)
        float *sEpi = (float *)&s[0][0];   // 128x65 f32 = 33.3KB <= 64KB
#pragma unroll
        for (int mi = 0; mi < 4; ++mi)
#pragma unroll
            for (int nj = 0; nj < NJ; ++nj)
#pragma unroll
                for (int r = 0; r < 4; ++r) {
                    int rl = wm * 64 + mi * 16 + hi * 4 + r;
                    int cl = wn * (BN / 2) + nj * 16 + x;
                    float v = fmaf(acc2[mi][nj][r], LO_INV, acc[mi][nj][r]) + p.bias[n0 + cl];
                    sEpi[rl * 65 + cl] = v;
                }
        __syncthreads();
        const bool isV = (n0 >= 1280);
        if (isV) {
            // transposed V store: vT[(b*4+kvh)*64 + d][tok], hi/lo split
            const int bIdx = (int)(m0 >> 11);
            const int tok0 = (int)(m0 & (Sc - 1));
            const int kvh = (int)((n0 - 1280) >> 6);
            const long vbase = ((long)(bIdx * 4 + kvh) * 64) * (long)Sc;
#pragma unroll
            for (int it = 0; it < 4; ++it) {
                int idx = tid + it * 256;
                int d = idx >> 4, tch = idx & 15;
                f16x8 oh, ol;
#pragma unroll
                for (int j = 0; j < 8; ++j) {
                    float v = sEpi[(tch * 8 + j) * 65 + d];
                    _Float16 hv = (_Float16)v;
                    oh[j] = hv;
                    ol[j] = (_Float16)((v - (float)hv) * LO_SCALE);
                }
                long orow = vbase + (long)d * Sc + tok0 + tch * 8;
                *(f16x8 *)(p.rVh + orow) = oh;
                *(f16x8 *)(p.rVl + orow) = ol;
            }
        } else {
            const bool isK = (n0 >= 1024);
#pragma unroll
            for (int mi = 0; mi < 4; ++mi)
#pragma unroll
                for (int nj = 0; nj < NJ; ++nj)
#pragma unroll
                    for (int r = 0; r < 4; ++r) {
                        int rl = wm * 64 + mi * 16 + hi * 4 + r;
                        int cl = wn * (BN / 2) + nj * 16 + x;
                        long row = m0 + rl;
                        float xv = sEpi[rl * 65 + cl];
                        int spos = (int)(row & (Sc - 1));
                        float xp = sEpi[rl * 65 + (cl ^ 32)];
                        float cs = p.resid[spos * 64 + cl];
                        float sn = p.bw[spos * 64 + cl];
                        float o = xv * cs + ((cl < 32) ? -xp : xp) * sn;
                        _Float16 hv = (_Float16)o;
                        _Float16 lo = (_Float16)((o - (float)hv) * LO_SCALE);
                        if (isK) {
                            long off = row * 256 + (n0 - 1024) + cl;
                            p.rKh[off] = hv; p.rKl[off] = lo;
                        } else {
                            long off = row * 1024 + n0 + cl;
                            p.rQh[off] = hv; p.rQl[off] = lo;
                        }
                    }
        }
        return;
    }

#pragma unroll
    for (int mi = 0; mi < 4; ++mi)
#pragma unroll
        for (int nj = 0; nj < NJ; ++nj)
#pragma unroll
            for (int r = 0; r < 4; ++r) {
                long row = m0 + wm * 64 + mi * 16 + hi * 4 + r;
                long col = n0 + wn * (BN / 2) + nj * 16 + x;
                float v = acc[mi][nj][r];
                if constexpr (GU) {
                    float u = acc2[mi][nj][r];
                    float he = v / (1.f + __expf(-v)) * u;
                    p.outBF[row * p.ldc + col] = __float2bfloat16(he);
                } else {
                    if constexpr (SPLIT) v = fmaf(acc2[mi][nj][r], LO_INV, v);
                    switch (p.epi) {
                    case 0: p.outF[row * p.ldc + col] = v + p.bias[col]; break;
                    case 2: {
                        float o = v + p.resid[row * p.ldc + col];
                        p.outF[row * p.ldc + col] = o;
                        p.outF2[row * p.ldc + col] = o;
                    } break;
                    case 5: // plain store to per-slot scratch, weight folded
                        p.outF[row * p.ldc + col] = v * p.bw[row];
                        break;
                    }
                }
            }
}

// combine: out[tok] += scat[slot0(tok)] + scat[slot1(tok)]  (coalesced f32x4)
__global__ __launch_bounds__(256) void combine_k(const float *__restrict__ scat,
        const int *__restrict__ tok_slot, float *__restrict__ out) {
    const long tok = blockIdx.x;
    const int c = threadIdx.x * 4;
    const long s0 = tok_slot[tok * 2], s1 = tok_slot[tok * 2 + 1];
    f32x4 a = *(const f32x4 *)(scat + s0 * Dc + c);
    f32x4 b = *(const f32x4 *)(scat + s1 * Dc + c);
    f32x4 o = *(const f32x4 *)(out + tok * Dc + c);
#pragma unroll
    for (int j = 0; j < 4; ++j) o[j] += a[j] + b[j];
    *(f32x4 *)(out + tok * Dc + c) = o;
}

// ----------------------------------------------------- flash attention ----
// Diagonal-paired blocks: block (pairI, bh) processes q-tiles pairI and
// 63-pairI sequentially -> uniform 65 kv-tiles per block (no straggler tail).
// Per segment: 2 waves x 16 q-rows, swapped QK^T (mfma(K,Q)), in-register
// softmax (2 shfl_xor), P to PV A-frag via packed shuffles, K/V staged via
// global_load_lds into swizzled LDS, depth-2 counted-vmcnt pipeline,
// defer-max (THR=8). Outputs ctx hi/lo f16.
__global__ __launch_bounds__(128, 2) void attn_k(
    const _Float16 *__restrict__ qh, const _Float16 *__restrict__ ql,
    const _Float16 *__restrict__ kh, const _Float16 *__restrict__ kl,
    const _Float16 *__restrict__ vTh, const _Float16 *__restrict__ vTl,
    _Float16 *__restrict__ ctxh, _Float16 *__restrict__ ctxl) {
    __shared__ __align__(16) _Float16 kbuf[2][2][32 * 64]; // [dbuf][hi/lo][kv][d]
    __shared__ __align__(16) _Float16 vbuf[2][2][64 * 32]; // [dbuf][hi/lo][d][kv]
    const int tid = threadIdx.x, lane = tid & 63, wid = tid >> 6;
    const int x = lane & 15, hi = lane >> 4;
    const int pairI = blockIdx.x;
    const int bh = blockIdx.y;
    const int b = bh >> 4, h = bh & 15, kvh = h >> 2;
    const long kRow0 = (long)b * Sc * 256;
    const long vRow0 = (long)(b * 4 + kvh) * 64 * (long)Sc;

    auto stage = [&](int kt, int bufI) {
        if (wid == 0) {          // K: [kv32][d64] CK=8, swizzle c^=(kv&7)
#pragma unroll
            for (int ss = 0; ss < 2; ++ss) {
                const _Float16 *src = ss ? kl : kh;
#pragma unroll
                for (int i = 0; i < 4; ++i) {
                    int kv = 8 * i + (lane >> 3);
                    int cd = (lane & 7) ^ (kv & 7);
                    const _Float16 *g = src + kRow0 + ((long)kt * 32 + kv) * 256 + kvh * 64 + cd * 8;
                    gll16(g, &kbuf[bufI][ss][i * 512]);
                }
            }
        } else {                 // V^T: [d64][kv32] CK=4, swizzle c^=((d>>1)&3)
#pragma unroll
            for (int ss = 0; ss < 2; ++ss) {
                const _Float16 *src = ss ? vTl : vTh;
#pragma unroll
                for (int i = 0; i < 4; ++i) {
                    int d = 16 * i + (lane >> 2);
                    int ckv = (lane & 3) ^ ((d >> 1) & 3);
                    const _Float16 *g = src + vRow0 + (long)d * Sc + (long)kt * 32 + ckv * 8;
                    gll16(g, &vbuf[bufI][ss][i * 512]);
                }
            }
        }
    };

    for (int seg = 0; seg < 2; ++seg) {
        const int qt = seg ? (63 - pairI) : pairI;
        const int q0 = qt * 32;
        const long qtokW = (long)b * Sc + q0 + wid * 16;    // wave's 16 q-rows

        f16x8 qfh[2], qfl[2];
#pragma unroll
        for (int ks = 0; ks < 2; ++ks) {
            long off = (qtokW + x) * (long)Dc + h * 64 + ks * 32 + hi * 8;
            qfh[ks] = *(const f16x8 *)(qh + off);
            qfl[ks] = *(const f16x8 *)(ql + off);
        }
        asm volatile("s_waitcnt vmcnt(0)" ::: "memory");
        __builtin_amdgcn_sched_barrier(0);

        f32x4 o1[4], o2[4];
        float mrow = -3.0e38f, lrow = 0.f;
#pragma unroll
        for (int dj = 0; dj < 4; ++dj) {
            o1[dj] = (f32x4){0.f, 0.f, 0.f, 0.f};
            o2[dj] = (f32x4){0.f, 0.f, 0.f, 0.f};
        }

        const int NT = qt + 1;

        stage(0, 0);
        stage(1, 1);

        for (int kt = 0; kt < NT; ++kt) {
            if (kt + 1 < NT) asm volatile("s_waitcnt vmcnt(8)" ::: "memory");
            else asm volatile("s_waitcnt vmcnt(0)" ::: "memory");
            __builtin_amdgcn_sched_barrier(0);
            __builtin_amdgcn_s_barrier();
            __builtin_amdgcn_sched_barrier(0);
            const int cur = kt & 1;

            f32x4 s1[2], s2[2];
#pragma unroll
            for (int kvs = 0; kvs < 2; ++kvs) {
                s1[kvs] = (f32x4){0.f, 0.f, 0.f, 0.f};
                s2[kvs] = (f32x4){0.f, 0.f, 0.f, 0.f};
            }
            __builtin_amdgcn_s_setprio(1);
#pragma unroll
            for (int ks = 0; ks < 2; ++ks)
#pragma unroll
                for (int kvs = 0; kvs < 2; ++kvs) {
                    int row = kvs * 16 + x;
                    int addr = row * 64 + (((ks * 4 + hi) ^ (row & 7)) << 3);
                    f16x8 kfh = *(const f16x8 *)&kbuf[cur][0][addr];
                    f16x8 kfl = *(const f16x8 *)&kbuf[cur][1][addr];
                    s1[kvs] = mfma16(kfh, qfh[ks], s1[kvs]);
                    s2[kvs] = mfma16(kfl, qfh[ks], s2[kvs]);
                    s2[kvs] = mfma16(kfh, qfl[ks], s2[kvs]);
                }
            __builtin_amdgcn_s_setprio(0);

            const bool diag = (kt == NT - 1);
            const int qpos = q0 + wid * 16 + x;
            float sv[2][4];
#pragma unroll
            for (int kvs = 0; kvs < 2; ++kvs)
#pragma unroll
                for (int r = 0; r < 4; ++r) {
                    float v = fmaf(s2[kvs][r], LO_INV, s1[kvs][r]) * 0.125f;
                    if (diag) {
                        int kvpos = kt * 32 + kvs * 16 + 4 * hi + r;
                        if (kvpos > qpos) v = -3.0e38f;
                    }
                    sv[kvs][r] = v;
                }
            float mx = sv[0][0];
#pragma unroll
            for (int kvs = 0; kvs < 2; ++kvs)
#pragma unroll
                for (int r = 0; r < 4; ++r) mx = fmaxf(mx, sv[kvs][r]);
            mx = fmaxf(mx, __shfl_xor(mx, 16));
            mx = fmaxf(mx, __shfl_xor(mx, 32));
            if (!__all(mx - mrow <= 8.0f)) {
                float mnew = fmaxf(mrow, mx);
                float scl = __expf(mrow - mnew);
                mrow = mnew;
                lrow *= scl;
                float sclr[4];
#pragma unroll
                for (int r = 0; r < 4; ++r) sclr[r] = __shfl(scl, 4 * hi + r);
#pragma unroll
                for (int dj = 0; dj < 4; ++dj)
#pragma unroll
                    for (int r = 0; r < 4; ++r) {
                        o1[dj][r] *= sclr[r];
                        o2[dj][r] *= sclr[r];
                    }
            }
            float pv[2][4];
            float ls = 0.f;
#pragma unroll
            for (int kvs = 0; kvs < 2; ++kvs)
#pragma unroll
                for (int r = 0; r < 4; ++r) {
                    pv[kvs][r] = __expf(sv[kvs][r] - mrow);
                    ls += pv[kvs][r];
                }
            ls += __shfl_xor(ls, 16);
            ls += __shfl_xor(ls, 32);
            lrow += ls;
            u32 Bh0[2], Bh1[2], Bl0[2], Bl1[2];
#pragma unroll
            for (int pr = 0; pr < 2; ++pr) {
                _Float16 a0 = (_Float16)pv[0][2 * pr], a1 = (_Float16)pv[0][2 * pr + 1];
                _Float16 b0 = (_Float16)pv[1][2 * pr], b1 = (_Float16)pv[1][2 * pr + 1];
                Bh0[pr] = pack2(a0, a1);
                Bh1[pr] = pack2(b0, b1);
                _Float16 la0 = (_Float16)((pv[0][2 * pr] - (float)a0) * LO_SCALE);
                _Float16 la1 = (_Float16)((pv[0][2 * pr + 1] - (float)a1) * LO_SCALE);
                _Float16 lb0 = (_Float16)((pv[1][2 * pr] - (float)b0) * LO_SCALE);
                _Float16 lb1 = (_Float16)((pv[1][2 * pr + 1] - (float)b1) * LO_SCALE);
                Bl0[pr] = pack2(la0, la1);
                Bl1[pr] = pack2(lb0, lb1);
            }
            const int srcLow = x + ((lane & 16) ? 32 : 0);
            const int srcHigh = srcLow + 16;
            const bool useB1 = lane >= 32;
            union { u32 u[4]; f16x8 v; } fh, fl;
#pragma unroll
            for (int pr = 0; pr < 2; ++pr) {
                u32 t0 = (u32)__shfl((int)Bh0[pr], srcLow);
                u32 t1 = (u32)__shfl((int)Bh1[pr], srcLow);
                fh.u[pr] = useB1 ? t1 : t0;
                u32 u0 = (u32)__shfl((int)Bh0[pr], srcHigh);
                u32 u1 = (u32)__shfl((int)Bh1[pr], srcHigh);
                fh.u[2 + pr] = useB1 ? u1 : u0;
                u32 s0 = (u32)__shfl((int)Bl0[pr], srcLow);
                u32 s1v = (u32)__shfl((int)Bl1[pr], srcLow);
                fl.u[pr] = useB1 ? s1v : s0;
                u32 w0 = (u32)__shfl((int)Bl0[pr], srcHigh);
                u32 w1 = (u32)__shfl((int)Bl1[pr], srcHigh);
                fl.u[2 + pr] = useB1 ? w1 : w0;
            }
            f16x8 pah = fh.v, pal = fl.v;

            __builtin_amdgcn_s_setprio(1);
#pragma unroll
            for (int dj = 0; dj < 4; ++dj) {
                int d = dj * 16 + x;
                int addr = d * 32 + ((hi ^ ((d >> 1) & 3)) << 3);
                f16x8 vhf = *(const f16x8 *)&vbuf[cur][0][addr];
                f16x8 vlf = *(const f16x8 *)&vbuf[cur][1][addr];
                o1[dj] = mfma16(pah, vhf, o1[dj]);
                o2[dj] = mfma16(pah, vlf, o2[dj]);
                o2[dj] = mfma16(pal, vhf, o2[dj]);
            }
            __builtin_amdgcn_s_setprio(0);

            asm volatile("s_waitcnt lgkmcnt(0)" ::: "memory");
            __builtin_amdgcn_sched_barrier(0);
            __builtin_amdgcn_s_barrier();
            __builtin_amdgcn_sched_barrier(0);
            if (kt + 2 < NT) stage(kt + 2, cur);
        }

        float linv = 1.0f / lrow;
        float lr[4];
#pragma unroll
        for (int r = 0; r < 4; ++r) lr[r] = __shfl(linv, 4 * hi + r);
#pragma unroll
        for (int dj = 0; dj < 4; ++dj)
#pragma unroll
            for (int r = 0; r < 4; ++r) {
                long tok = qtokW + 4 * hi + r;
                float ov = fmaf(o2[dj][r], LO_INV, o1[dj][r]) * lr[r];
                _Float16 hv = (_Float16)ov;
                long off = tok * Dc + h * 64 + dj * 16 + x;
                ctxh[off] = hv;
                ctxl[off] = (_Float16)((ov - (float)hv) * LO_SCALE);
            }
    }
}

// ------------------------------------------------------- small kernels ----
__global__ __launch_bounds__(256) void rmsnorm_split_k(const float *__restrict__ x,
        const float *__restrict__ w, _Float16 *__restrict__ oh, _Float16 *__restrict__ ol) {
    const long row = blockIdx.x;
    const int tid = threadIdx.x, lane = tid & 63, wid = tid >> 6;
    f32x4 v = *(const f32x4 *)(x + row * Dc + tid * 4);
    float ss = v[0] * v[0] + v[1] * v[1] + v[2] * v[2] + v[3] * v[3];
#pragma unroll
    for (int off = 1; off < 64; off <<= 1) ss += __shfl_xor(ss, off);
    __shared__ float sw[4];
    if (lane == 0) sw[wid] = ss;
    __syncthreads();
    float inv = 1.0f / sqrtf((sw[0] + sw[1] + sw[2] + sw[3]) * (1.f / Dc) + 1e-6f);
#pragma unroll
    for (int j = 0; j < 4; ++j) {
        float y = v[j] * inv * w[tid * 4 + j];
        _Float16 hv = (_Float16)y;
        oh[row * Dc + tid * 4 + j] = hv;
        ol[row * Dc + tid * 4 + j] = (_Float16)((y - (float)hv) * LO_SCALE);
    }
}

// fused RMSNorm (ln2) + router: keeps f32 row in regs (router precision),
// writes only tbf; computes 8 logits, softmax, top-2, counts.
__global__ __launch_bounds__(256) void rmsnorm_router_k(const float *__restrict__ x,
        const float *__restrict__ w, const float *__restrict__ rw,
        __hip_bfloat16 *__restrict__ tb, float *__restrict__ probs,
        int *__restrict__ tok_e, float *__restrict__ tok_w, int *__restrict__ cnt) {
    const long row = blockIdx.x;
    const int tid = threadIdx.x, lane = tid & 63, wid = tid >> 6;
    f32x4 v = *(const f32x4 *)(x + row * Dc + tid * 4);
    float ss = v[0] * v[0] + v[1] * v[1] + v[2] * v[2] + v[3] * v[3];
#pragma unroll
    for (int off = 1; off < 64; off <<= 1) ss += __shfl_xor(ss, off);
    __shared__ float sw[4];
    __shared__ float part[4][8];
    if (lane == 0) sw[wid] = ss;
    __syncthreads();
    float inv = 1.0f / sqrtf((sw[0] + sw[1] + sw[2] + sw[3]) * (1.f / Dc) + 1e-6f);
    float y[4];
#pragma unroll
    for (int j = 0; j < 4; ++j) {
        y[j] = v[j] * inv * w[tid * 4 + j];
        tb[row * Dc + tid * 4 + j] = __float2bfloat16(y[j]);
    }
    float acc[8];
#pragma unroll
    for (int e = 0; e < 8; ++e) {
        f32x4 wv = *(const f32x4 *)(rw + (long)e * Dc + tid * 4);
        acc[e] = y[0] * wv[0] + y[1] * wv[1] + y[2] * wv[2] + y[3] * wv[3];
    }
#pragma unroll
    for (int off = 1; off < 64; off <<= 1)
#pragma unroll
        for (int e = 0; e < 8; ++e) acc[e] += __shfl_xor(acc[e], off);
    if (lane == 0)
#pragma unroll
        for (int e = 0; e < 8; ++e) part[wid][e] = acc[e];
    __syncthreads();
    if (tid == 0) {
        float lg[8];
        float mx = -3.0e38f;
#pragma unroll
        for (int e = 0; e < 8; ++e) {
            lg[e] = part[0][e] + part[1][e] + part[2][e] + part[3][e];
            mx = fmaxf(mx, lg[e]);
        }
        float ex[8], s = 0.f;
#pragma unroll
        for (int e = 0; e < 8; ++e) { ex[e] = expf(lg[e] - mx); s += ex[e]; }
        float invs = 1.f / s;
        int i1 = -1, i2 = -1;
        float p1v = -1.f, p2v = -1.f;
#pragma unroll
        for (int e = 0; e < 8; ++e) {
            float pe = ex[e] * invs;
            probs[row * 8 + e] = pe;
            if (pe > p1v) { i2 = i1; p2v = p1v; i1 = e; p1v = pe; }
            else if (pe > p2v) { i2 = e; p2v = pe; }
        }
        float wsum = p1v + p2v;
        tok_e[row * 2] = i1; tok_e[row * 2 + 1] = i2;
        tok_w[row * 2] = p1v / wsum; tok_w[row * 2 + 1] = p2v / wsum;
        atomicAdd(&cnt[i1], 1);
        atomicAdd(&cnt[i2], 1);
    }
}

__global__ void pack_qkvw_k(const float *__restrict__ qw, const float *__restrict__ kw,
        const float *__restrict__ vw, _Float16 *wh, _Float16 *wl) {
    const long n = (long)QKVN * Dc;
    for (long i = (long)blockIdx.x * 256 + threadIdx.x; i < n; i += (long)gridDim.x * 256) {
        long o = i >> 10;
        int d = (int)(i & 1023);
        float v;
        if (o < 1024) v = qw[o * 1024 + d];
        else if (o < 1280) v = kw[(o - 1024) * 1024 + d];
        else v = vw[(o - 1280) * 1024 + d];
        _Float16 h = (_Float16)v;
        wh[i] = h;
        wl[i] = (_Float16)((v - (float)h) * LO_SCALE);
    }
}

__global__ void split_f16_k(const float *__restrict__ x, _Float16 *hi, _Float16 *lo, long n) {
    for (long i = (long)blockIdx.x * 256 + threadIdx.x; i < n; i += (long)gridDim.x * 256) {
        float v = x[i];
        _Float16 h = (_Float16)v;
        hi[i] = h;
        lo[i] = (_Float16)((v - (float)h) * LO_SCALE);
    }
}

__global__ void pack_bias_k(const float *qb, const float *kb, const float *vb, float *out) {
    int i = blockIdx.x * 256 + threadIdx.x;
    if (i >= QKVN) return;
    out[i] = (i < 1024) ? qb[i] : (i < 1280) ? kb[i - 1024] : vb[i - 1280];
}

__global__ __launch_bounds__(256) void transpose_bf16_k(const float *__restrict__ in,
        __hip_bfloat16 *__restrict__ out, int R, int C) {
    __shared__ float tile[64 * 65];
    const long eo = (long)blockIdx.z * R * C;
    const int r0 = blockIdx.y * 64, c0 = blockIdx.x * 64;
#pragma unroll
    for (int i = 0; i < 16; ++i) {
        int idx = threadIdx.x + i * 256;
        int r = idx >> 6, c = idx & 63;
        tile[r * 65 + c] = in[eo + (long)(r0 + r) * C + (c0 + c)];
    }
    __syncthreads();
#pragma unroll
    for (int i = 0; i < 16; ++i) {
        int idx = threadIdx.x + i * 256;
        int cc = idx >> 6, rr = idx & 63;
        out[eo + (long)(c0 + cc) * R + (r0 + rr)] = __float2bfloat16(tile[rr * 65 + cc]);
    }
}

__global__ __launch_bounds__(1024) void router_p2_k(const int *cnt, const float *probs,
        int *poff, float *aux_out) {
    __shared__ float sd[1024];
    const int tid = threadIdx.x;
    const int e = tid & 7, rs = tid >> 3;
    float s = 0.f;
    for (int r = rs; r < Tc; r += 128) s += probs[(long)r * 8 + e];
    sd[tid] = s;
    __syncthreads();
    for (int st = 64; st >= 1; st >>= 1) {
        if (rs < st) sd[tid] += sd[tid + st * 8];
        __syncthreads();
    }
    if (tid == 0) {
        float a = 0.f;
        for (int ee = 0; ee < 8; ++ee) {
            float m = sd[ee] * (1.f / Tc);
            a += m * m;
        }
        aux_out[0] = a;
        int o = 0;
        poff[0] = 0;
        for (int ee = 0; ee < 8; ++ee) { o += (cnt[ee] + 127) & ~127; poff[ee + 1] = o; }
    }
}

__global__ void router_p3_k(const int *tok_e, const float *tok_w, const int *poff,
        int *cursor, int *btok, float *bw, int *tok_slot) {
    long tok = (long)blockIdx.x * 256 + threadIdx.x;
    if (tok >= Tc) return;
#pragma unroll
    for (int j = 0; j < 2; ++j) {
        int e = tok_e[tok * 2 + j];
        int slot = atomicAdd(&cursor[e], 1);
        btok[poff[e] + slot] = (int)tok;
        bw[poff[e] + slot] = tok_w[tok * 2 + j];
        tok_slot[tok * 2 + j] = poff[e] + slot;
    }
}

__global__ void router_p4_k(const int *poff, const int *cnt, int *btok, float *bw) {
    int s = blockIdx.x * 256 + threadIdx.x;
    if (s >= poff[8]) return;
    int e = 0;
    while (s >= poff[e + 1]) ++e;
    if (s - poff[e] >= cnt[e]) { btok[s] = 0; bw[s] = 0.f; }
}

// -------------------------------------------------------------- launch ----
extern "C" void kernel_launch(void *const *d_in, const int *in_sizes, int n_in,
                              void *d_out, int out_size, void *d_ws, size_t ws_size,
                              hipStream_t stream) {
    (void)in_sizes; (void)n_in;
    const float *hidden = (const float *)d_in[0];
    const float *ln1 = (const float *)d_in[1];
    const float *ln2 = (const float *)d_in[2];
    const float *qw = (const float *)d_in[3];
    const float *qb = (const float *)d_in[4];
    const float *kw = (const float *)d_in[5];
    const float *kb = (const float *)d_in[6];
    const float *vw = (const float *)d_in[7];
    const float *vb = (const float *)d_in[8];
    const float *ow = (const float *)d_in[9];
    const float *rw = (const float *)d_in[10];
    const float *gw = (const float *)d_in[11];
    const float *uw = (const float *)d_in[12];
    const float *dwn = (const float *)d_in[13];
    const float *cosb = (const float *)d_in[14];
    const float *sinb = (const float *)d_in[15];
    float *outx = (float *)d_out;

    char *base = (char *)d_ws;
    size_t off = 0;
    auto alloc = [&](size_t bytes) -> char * {
        char *p = base + off;
        off += (bytes + 255) & ~(size_t)255;
        return p;
    };
    _Float16 *qkvwh = (_Float16 *)alloc((size_t)QKVN * Dc * 2);
    _Float16 *qkvwl = (_Float16 *)alloc((size_t)QKVN * Dc * 2);
    float *qkvb = (float *)alloc(QKVN * 4);
    _Float16 *owh = (_Float16 *)alloc((size_t)Dc * Dc * 2);
    _Float16 *owl = (_Float16 *)alloc((size_t)Dc * Dc * 2);
    __hip_bfloat16 *gateT = (__hip_bfloat16 *)alloc((size_t)Ec * Fc * Dc * 2);
    __hip_bfloat16 *upT = (__hip_bfloat16 *)alloc((size_t)Ec * Fc * Dc * 2);
    __hip_bfloat16 *downT = (__hip_bfloat16 *)alloc((size_t)Ec * Dc * Fc * 2);
    // U2..vTl span (~40 MB) is dead by down-GEMM time; scat (36 MB) aliases it
    char *U2 = alloc((size_t)Tc * Dc * 4);
    _Float16 *hh = (_Float16 *)U2;
    _Float16 *hl = hh + (size_t)Tc * Dc;
    char *U3 = alloc((size_t)Tc * Dc * 4);
    _Float16 *qhb = (_Float16 *)U3;
    _Float16 *qlb = qhb + (size_t)Tc * Dc;
    float *x1 = (float *)U3;
    _Float16 *khb = (_Float16 *)alloc((size_t)Tc * 256 * 2);
    _Float16 *klb = (_Float16 *)alloc((size_t)Tc * 256 * 2);
    _Float16 *vTh = (_Float16 *)alloc((size_t)Tc * 256 * 2);
    _Float16 *vTl = (_Float16 *)alloc((size_t)Tc * 256 * 2);
    float *scat = (float *)U2;   // CAP*Dc*4 = 36 MB <= U2..vTl span (~40 MB)
    _Float16 *ctxh = (_Float16 *)alloc((size_t)Tc * Dc * 2);
    _Float16 *ctxl = (_Float16 *)alloc((size_t)Tc * Dc * 2);
    __hip_bfloat16 *tbf = (__hip_bfloat16 *)alloc((size_t)Tc * Dc * 2);
    float *probs = (float *)alloc((size_t)Tc * 8 * 4);
    int *tok_e = (int *)alloc((size_t)Tc * 2 * 4);
    float *tok_w = (float *)alloc((size_t)Tc * 2 * 4);
    int *tok_slot = (int *)alloc((size_t)Tc * 2 * 4);
    int *cnt = (int *)alloc(256);
    int *cursor = cnt + 8;
    int *poff = (int *)alloc(256);
    int *btok = (int *)alloc((size_t)CAP * 4);
    float *bwgt = (float *)alloc((size_t)CAP * 4);
    __hip_bfloat16 *gbuf = (__hip_bfloat16 *)alloc((size_t)CAP * Fc * 2);

    if (off > ws_size) {
        hipMemsetAsync(d_out, 0, (size_t)out_size * 4, stream);
        return;
    }

    hipMemsetAsync(cnt, 0, 64, stream);
    pack_qkvw_k<<<1024, 256, 0, stream>>>(qw, kw, vw, qkvwh, qkvwl);
    pack_bias_k<<<(QKVN + 255) / 256, 256, 0, stream>>>(qb, kb, vb, qkvb);
    split_f16_k<<<1024, 256, 0, stream>>>(ow, owh, owl, (long)Dc * Dc);
    transpose_bf16_k<<<dim3(Fc / 64, Dc / 64, Ec), 256, 0, stream>>>(gw, gateT, Dc, Fc);
    transpose_bf16_k<<<dim3(Fc / 64, Dc / 64, Ec), 256, 0, stream>>>(uw, upT, Dc, Fc);
    transpose_bf16_k<<<dim3(Dc / 64, Fc / 64, Ec), 256, 0, stream>>>(dwn, downT, Fc, Dc);
    rmsnorm_split_k<<<Tc, 256, 0, stream>>>(hidden, ln1, hh, hl);

    // QKV GEMM with fused RoPE + V-transpose epilogue (epi=6)
    GemmP g{};
    g.Ah = hh; g.Al = hl; g.Bh = qkvwh; g.Bl = qkvwl;
    g.lda = Dc; g.ldb = Dc; g.bExp = 0; g.K = Dc;
    g.bias = qkvb; g.resid = cosb; g.bw = sinb;
    g.rQh = qhb; g.rQl = qlb; g.rKh = khb; g.rKl = klb; g.rVh = vTh; g.rVl = vTl;
    g.ldc = QKVN; g.epi = 6;
    gemm_k<_Float16, true, false, false, 64><<<dim3(Tc / 128, QKVN / 64), 256, 0, stream>>>(g);

    attn_k<<<dim3(Sc / 64, Bc * Hc), 128, 0, stream>>>(qhb, qlb, khb, klb, vTh, vTl, ctxh, ctxl);

    GemmP go{};
    go.Ah = ctxh; go.Al = ctxl; go.Bh = owh; go.Bl = owl;
    go.lda = Dc; go.ldb = Dc; go.bExp = 0; go.K = Dc;
    go.resid = hidden; go.outF = x1; go.outF2 = outx; go.ldc = Dc; go.epi = 2;
    gemm_k<_Float16, true, false, false, 64><<<dim3(Tc / 128, Dc / 64), 256, 0, stream>>>(go);

    // fused RMSNorm(ln2) + router logits/softmax/top-2
    rmsnorm_router_k<<<Tc, 256, 0, stream>>>(x1, ln2, rw, tbf, probs, tok_e, tok_w, cnt);
    router_p2_k<<<1, 1024, 0, stream>>>(cnt, probs, poff, outx + (long)Tc * Dc);
    router_p3_k<<<Tc / 256, 256, 0, stream>>>(tok_e, tok_w, poff, cursor, btok, bwgt, tok_slot);
    router_p4_k<<<CAP / 256, 256, 0, stream>>>(poff, cnt, btok, bwgt);

    // fused gate+up: silu(t@gate)*(t@up) -> gbuf, XCD-chunked M,
    // single-barrier triple-buffer pipeline (NBUF=3)
    GemmP gg{};
    gg.Ah = tbf; gg.Bh = gateT; gg.Bh2 = upT;
    gg.lda = Dc; gg.ldb = Dc; gg.bExp = (long)Fc * Dc; gg.K = Dc;
    gg.poff = poff; gg.gidx = btok; gg.outBF = gbuf; gg.ldc = Fc;
    gemm_k<__hip_bfloat16, false, true, true, 128, true, 3><<<dim3(CAP / 128, Fc / 128), 256, 0, stream>>>(gg);

    // down: BN=128, weighted store to per-slot scratch, XCD-chunked M, NBUF=3
    GemmP gd{};
    gd.Ah = gbuf; gd.Bh = downT;
    gd.lda = Fc; gd.ldb = Fc; gd.bExp = (long)Dc * Fc; gd.K = Fc;
    gd.poff = poff; gd.bw = bwgt;
    gd.outF = scat; gd.ldc = Dc; gd.epi = 5;
    gemm_k<__hip_bfloat16, false, false, false, 128, true, 3><<<dim3(CAP / 128, Dc / 128), 256, 0, stream>>>(gd);

    // combine: outx[tok] += scat[slot0] + scat[slot1]
    combine_k<<<Tc, 256, 0, stream>>>(scat, tok_slot, outx);
}